// Round 1
// baseline (2745.610 us; speedup 1.0000x reference)
//
#include <hip/hip_runtime.h>
#include <cmath>

// ---------------------------------------------------------------------------
// NeuralMemory: fp32 baseline implementation.
// Key simplification: per-chunk vmap'd grads == (1/NC) * sum over all rows,
// so the whole memory-update is flat GEMMs over (B*(M+S)) x D activations.
// ---------------------------------------------------------------------------

namespace {

constexpr int Bb   = 2;
constexpr int Ss   = 2048;
constexpr int Dd   = 512;
constexpr int Mm   = 64;
constexpr int NCc  = 16;
constexpr int NHh  = 8;
constexpr int HD   = Dd / NHh;   // 64
constexpr int WINw = 256;
constexpr int Nn   = Mm + Ss;    // 2112
constexpr int Rr   = Bb * Nn;    // 4224 rows total
constexpr int NBD  = Rr * Dd;    // 2,162,688 floats per activation buffer
constexpr float MAXLR = 0.1f;

__device__ __forceinline__ float sigf(float x)  { return 1.0f / (1.0f + expf(-x)); }
__device__ __forceinline__ float siluf(float x) { return x * sigf(x); }
__device__ __forceinline__ float dsiluf(float x){ float s = sigf(x); return s * (1.0f + x * (1.0f - s)); }

// ---- build xm = concat(meta broadcast, x) along seq dim -------------------
__global__ void k_build_xm(const float* __restrict__ x, const float* __restrict__ meta,
                           float* __restrict__ xm) {
    int i = blockIdx.x * 256 + threadIdx.x;      // float4 index over Rr*128
    const int nv = Rr * (Dd / 4);
    if (i >= nv) return;
    int c = i & 127;
    int r = i >> 7;
    int b = r / Nn, t = r - b * Nn;
    float4 v;
    if (t < Mm) v = ((const float4*)meta)[t * 128 + c];
    else        v = ((const float4*)x)[(size_t)(b * Ss + (t - Mm)) * 128 + c];
    ((float4*)xm)[i] = v;
}

// ---- per-row scalar gates: lr = 0.1*sig(x.w), fg = sig, mo = sig ----------
__global__ void k_gates(const float* __restrict__ xm,
                        const float* __restrict__ lw, const float* __restrict__ lb,
                        const float* __restrict__ fw, const float* __restrict__ fb,
                        const float* __restrict__ mw, const float* __restrict__ mb,
                        float* __restrict__ lr_t, float* __restrict__ fg_t, float* __restrict__ mo_t) {
    int r = blockIdx.x * 4 + (threadIdx.x >> 6);
    int lane = threadIdx.x & 63;
    if (r >= Rr) return;
    const float* row = xm + (size_t)r * Dd;
    float s0 = 0.f, s1 = 0.f, s2 = 0.f;
    for (int j = lane; j < Dd; j += 64) {
        float v = row[j];
        s0 += v * lw[j]; s1 += v * fw[j]; s2 += v * mw[j];
    }
    #pragma unroll
    for (int off = 32; off; off >>= 1) {
        s0 += __shfl_down(s0, off, 64);
        s1 += __shfl_down(s1, off, 64);
        s2 += __shfl_down(s2, off, 64);
    }
    if (lane == 0) {
        lr_t[r] = MAXLR * sigf(s0 + lb[0]);
        fg_t[r] = sigf(s1 + fb[0]);
        mo_t[r] = sigf(s2 + mb[0]);
    }
}

// scal[0]=alpha_bar (fg mean), scal[1]=theta_bar (lr mean), scal[2]=eta_bar (mo mean)
__global__ void k_gate_means(const float* __restrict__ lr_t, const float* __restrict__ fg_t,
                             const float* __restrict__ mo_t, float* __restrict__ scal) {
    __shared__ float red[256];
    const float* ptrs[3] = { fg_t, lr_t, mo_t };
    for (int w = 0; w < 3; ++w) {
        float acc = 0.f;
        for (int i = threadIdx.x; i < Rr; i += 256) acc += ptrs[w][i];
        red[threadIdx.x] = acc; __syncthreads();
        for (int off = 128; off; off >>= 1) {
            if (threadIdx.x < off) red[threadIdx.x] += red[threadIdx.x + off];
            __syncthreads();
        }
        if (threadIdx.x == 0) scal[w] = red[0] / (float)Rr;
        __syncthreads();
    }
}

// ---- generic fp32 GEMM, 128x128 tile, BK=8, 256 threads, 8x8/thread ------
// TA=0: A is (M,K) row-major. TA=1: A is (K,M) (i.e. computes A^T B).
// TB=0: B is (K,N).           TB=1: B is (N,K) (i.e. computes A B^T).
// SPLITK: gridDim.z splits K evenly; each z writes raw sums to C + z*M*N.
// Requires M%128==0, N%128==0, K%8==0 (true for all uses here).
template<int TA, int TB, bool SPLITK>
__global__ __launch_bounds__(256) void k_gemm(
        const float* __restrict__ A, const float* __restrict__ Bm,
        float* __restrict__ C, const float* __restrict__ bias,
        int Md, int Nd, int Kd, float alpha, int accum) {
    __shared__ float As[8][128];
    __shared__ float Bs[8][128];
    const int tid = threadIdx.x;
    const int m0 = blockIdx.x * 128;
    const int n0 = blockIdx.y * 128;
    int k_begin = 0, k_end = Kd;
    if (SPLITK) {
        int kc = Kd / gridDim.z;
        k_begin = blockIdx.z * kc;
        k_end = k_begin + kc;
        C += (size_t)blockIdx.z * Md * Nd;
    }
    float acc[8][8];
    #pragma unroll
    for (int i = 0; i < 8; ++i)
        #pragma unroll
        for (int j = 0; j < 8; ++j) acc[i][j] = 0.f;

    const int ty = tid >> 4, tx = tid & 15;

    for (int k0 = k_begin; k0 < k_end; k0 += 8) {
        if (TA == 0) {
            int m = tid >> 1, kq = (tid & 1) * 4;
            float4 va = *(const float4*)(A + (size_t)(m0 + m) * Kd + k0 + kq);
            As[kq + 0][m] = va.x; As[kq + 1][m] = va.y;
            As[kq + 2][m] = va.z; As[kq + 3][m] = va.w;
        } else {
            int k = tid >> 5, mq = (tid & 31) * 4;
            float4 va = *(const float4*)(A + (size_t)(k0 + k) * Md + m0 + mq);
            *(float4*)&As[k][mq] = va;
        }
        if (TB == 0) {
            int k = tid >> 5, nq = (tid & 31) * 4;
            float4 vb = *(const float4*)(Bm + (size_t)(k0 + k) * Nd + n0 + nq);
            *(float4*)&Bs[k][nq] = vb;
        } else {
            int n = tid >> 1, kq = (tid & 1) * 4;
            float4 vb = *(const float4*)(Bm + (size_t)(n0 + n) * Kd + k0 + kq);
            Bs[kq + 0][n] = vb.x; Bs[kq + 1][n] = vb.y;
            Bs[kq + 2][n] = vb.z; Bs[kq + 3][n] = vb.w;
        }
        __syncthreads();
        #pragma unroll
        for (int k = 0; k < 8; ++k) {
            float a[8], bq[8];
            *(float4*)&a[0]  = *(const float4*)&As[k][ty * 4];
            *(float4*)&a[4]  = *(const float4*)&As[k][64 + ty * 4];
            *(float4*)&bq[0] = *(const float4*)&Bs[k][tx * 4];
            *(float4*)&bq[4] = *(const float4*)&Bs[k][64 + tx * 4];
            #pragma unroll
            for (int i = 0; i < 8; ++i)
                #pragma unroll
                for (int j = 0; j < 8; ++j)
                    acc[i][j] += a[i] * bq[j];
        }
        __syncthreads();
    }

    #pragma unroll
    for (int i = 0; i < 8; ++i) {
        int m = m0 + ((i < 4) ? (ty * 4 + i) : (64 + ty * 4 + (i - 4)));
        #pragma unroll
        for (int jq = 0; jq < 2; ++jq) {
            int n = n0 + ((jq == 0) ? (tx * 4) : (64 + tx * 4));
            float4 v;
            v.x = acc[i][jq * 4 + 0]; v.y = acc[i][jq * 4 + 1];
            v.z = acc[i][jq * 4 + 2]; v.w = acc[i][jq * 4 + 3];
            float* cp = C + (size_t)m * Nd + n;
            if (!SPLITK) {
                v.x *= alpha; v.y *= alpha; v.z *= alpha; v.w *= alpha;
                if (bias) { v.x += bias[n]; v.y += bias[n + 1]; v.z += bias[n + 2]; v.w += bias[n + 3]; }
                if (accum) { float4 o = *(float4*)cp; v.x += o.x; v.y += o.y; v.z += o.z; v.w += o.w; }
            }
            *(float4*)cp = v;
        }
    }
}

__global__ void k_reduce_splitk(const float* __restrict__ part, float* __restrict__ out,
                                int n, int z, float alpha) {
    int i = blockIdx.x * 256 + threadIdx.x;
    if (i >= n) return;
    float s = 0.f;
    for (int zz = 0; zz < z; ++zz) s += part[(size_t)zz * n + i];
    out[i] = alpha * s;
}

// ---- causal depthwise conv (K=4) + SiLU (+ optional row L2-normalize) ----
template<bool NORM>
__global__ __launch_bounds__(256) void k_conv_silu(const float* __restrict__ y,
                                                   const float* __restrict__ cw,
                                                   float* __restrict__ out) {
    int r = blockIdx.x;
    int b = r / Nn, t = r - b * Nn;
    const size_t rowbase = (size_t)r * Dd;
    float s[2];
    #pragma unroll
    for (int u = 0; u < 2; ++u) {
        int d = threadIdx.x + u * 256;
        float acc = 0.f;
        #pragma unroll
        for (int k = 0; k < 4; ++k) {
            int tt = t - 3 + k;
            if (tt >= 0) acc += y[(size_t)(b * Nn + tt) * Dd + d] * cw[d * 4 + k];
        }
        s[u] = siluf(acc);
    }
    if (NORM) {
        __shared__ float red[256];
        red[threadIdx.x] = s[0] * s[0] + s[1] * s[1];
        __syncthreads();
        for (int off = 128; off; off >>= 1) {
            if (threadIdx.x < off) red[threadIdx.x] += red[threadIdx.x + off];
            __syncthreads();
        }
        float denom = fmaxf(sqrtf(red[0]), 1e-12f);
        out[rowbase + threadIdx.x]       = s[0] / denom;
        out[rowbase + threadIdx.x + 256] = s[1] / denom;
    } else {
        out[rowbase + threadIdx.x]       = s[0];
        out[rowbase + threadIdx.x + 256] = s[1];
    }
}

// ---- elementwise helpers --------------------------------------------------
__global__ void k_silu(const float* __restrict__ in, float* __restrict__ out, int n) {
    int i = blockIdx.x * 256 + threadIdx.x;
    if (i < n) out[i] = siluf(in[i]);
}
__global__ void k_res_silu(const float* __restrict__ hp, const float* __restrict__ a,
                           float* __restrict__ out, int n) {
    int i = blockIdx.x * 256 + threadIdx.x;
    if (i < n) out[i] = hp[i] + siluf(a[i]);
}
// g = (2/D) * lr[row] * (g - v)
__global__ void k_dpred(float* __restrict__ g, const float* __restrict__ v,
                        const float* __restrict__ lr_t, int n) {
    int i = blockIdx.x * 256 + threadIdx.x;
    if (i < n) g[i] = (2.0f / (float)Dd) * lr_t[i >> 9] * (g[i] - v[i]);
}
__global__ void k_dsilu(const float* __restrict__ dh, const float* __restrict__ a,
                        float* __restrict__ out, int n) {
    int i = blockIdx.x * 256 + threadIdx.x;
    if (i < n) out[i] = dh[i] * dsiluf(a[i]);
}

// ---- column sums for bias grads ------------------------------------------
__global__ void k_colsum(const float* __restrict__ g, float* __restrict__ part) {
    int col = blockIdx.x * 256 + threadIdx.x;      // grid.x = 2 -> 512 cols
    int chunk = blockIdx.y;                         // 16 chunks of 264 rows
    int r0 = chunk * (Rr / 16);
    float s = 0.f;
    for (int r = r0; r < r0 + Rr / 16; ++r) s += g[(size_t)r * Dd + col];
    part[chunk * Dd + col] = s;
}
__global__ void k_colsum_reduce(const float* __restrict__ part, float* __restrict__ out, float alpha) {
    int col = blockIdx.x * 256 + threadIdx.x;
    if (col >= Dd) return;
    float s = 0.f;
    for (int c = 0; c < 16; ++c) s += part[c * Dd + col];
    out[col] = alpha * s;
}

// ---- parameter update: new = p*(1-abar) + ebar*mom - tbar*g --------------
__global__ void k_update(const float* __restrict__ p, const float* __restrict__ mom,
                         const float* __restrict__ g, const float* __restrict__ scal,
                         float* __restrict__ out, int n) {
    int i = blockIdx.x * 256 + threadIdx.x;
    if (i < n) out[i] = p[i] * (1.0f - scal[0]) + scal[2] * mom[i] - scal[1] * g[i];
}

// ---- sliding-window attention (flash-style, one wave per query) ----------
__global__ __launch_bounds__(256) void k_swa(const float* __restrict__ qs,
                                             const float* __restrict__ ks,
                                             const float* __restrict__ vs,
                                             float* __restrict__ out) {
    int wid = blockIdx.x * 4 + (threadIdx.x >> 6);
    int lane = threadIdx.x & 63;
    if (wid >= Bb * NHh * Nn) return;
    int i  = wid % Nn;
    int bh = wid / Nn;
    int h  = bh % NHh, b = bh / NHh;
    const size_t base = (size_t)(b * Nn) * Dd + h * HD;
    float qv = qs[base + (size_t)i * Dd + lane];
    int j0 = i - (WINw - 1); if (j0 < 0) j0 = 0;
    float mrun = -1e30f, lrun = 0.f, accv = 0.f;
    for (int j = j0; j <= i; ++j) {
        float p = qv * ks[base + (size_t)j * Dd + lane];
        #pragma unroll
        for (int off = 32; off; off >>= 1) p += __shfl_xor(p, off, 64);
        float sc = p * 0.125f;                 // 1/sqrt(64)
        float mnew = fmaxf(mrun, sc);
        float corr = expf(mrun - mnew);
        float pe = expf(sc - mnew);
        lrun = lrun * corr + pe;
        accv = accv * corr + pe * vs[base + (size_t)j * Dd + lane];
        mrun = mnew;
    }
    out[base + (size_t)i * Dd + lane] = accv / lrun;
}

// ---- slice rows t >= M into d_out ----------------------------------------
__global__ void k_slice(const float* __restrict__ full, float* __restrict__ out) {
    int i = blockIdx.x * 256 + threadIdx.x;     // float4 over B*S*128
    const int nv = Bb * Ss * 128;
    if (i >= nv) return;
    int c = i & 127;
    int r = i >> 7;
    int b = r / Ss, t = r - b * Ss;
    ((float4*)out)[i] = ((const float4*)full)[(size_t)(b * Nn + Mm + t) * 128 + c];
}

} // namespace

extern "C" void kernel_launch(void* const* d_in, const int* in_sizes, int n_in,
                              void* d_out, int out_size, void* d_ws, size_t ws_size,
                              hipStream_t stream) {
    const float* x       = (const float*)d_in[0];
    const float* meta    = (const float*)d_in[1];
    const float* mWin    = (const float*)d_in[2];
    const float* mbin    = (const float*)d_in[3];
    const float* mWh     = (const float*)d_in[4];
    const float* mbh     = (const float*)d_in[5];
    const float* mWout   = (const float*)d_in[6];
    const float* mbout   = (const float*)d_in[7];
    const float* momWin  = (const float*)d_in[8];
    const float* mombin  = (const float*)d_in[9];
    const float* momWh   = (const float*)d_in[10];
    const float* mombh   = (const float*)d_in[11];
    const float* momWout = (const float*)d_in[12];
    const float* mombout = (const float*)d_in[13];
    const float* q_w = (const float*)d_in[14]; const float* q_b = (const float*)d_in[15]; const float* q_c = (const float*)d_in[16];
    const float* k_w = (const float*)d_in[17]; const float* k_b = (const float*)d_in[18]; const float* k_c = (const float*)d_in[19];
    const float* v_w = (const float*)d_in[20]; const float* v_b = (const float*)d_in[21]; const float* v_c = (const float*)d_in[22];
    const float* lr_w = (const float*)d_in[23]; const float* lr_b = (const float*)d_in[24];
    const float* fg_w = (const float*)d_in[25]; const float* fg_b = (const float*)d_in[26];
    const float* mo_w = (const float*)d_in[27]; const float* mo_b = (const float*)d_in[28];
    const float* swa_wq = (const float*)d_in[29]; const float* swa_wk = (const float*)d_in[30];
    const float* swa_wv = (const float*)d_in[31]; const float* swa_wo = (const float*)d_in[32];
    const float* swa_bq = (const float*)d_in[33]; const float* swa_bk = (const float*)d_in[34];
    const float* swa_bv = (const float*)d_in[35]; const float* swa_bo = (const float*)d_in[36];

    // ---- workspace carve-up (~138 MB of fp32) ----
    float* ws = (float*)d_ws;
    size_t off = 0;
    auto alloc = [&](size_t n) { float* p = ws + off; off += n; return p; };
    float* xm = alloc(NBD); float* t0 = alloc(NBD);
    float* qb = alloc(NBD); float* kb = alloc(NBD); float* vb = alloc(NBD);
    float* z0 = alloc(NBD); float* h0 = alloc(NBD); float* a0 = alloc(NBD);
    float* h1 = alloc(NBD); float* a1 = alloc(NBD); float* h2 = alloc(NBD);
    float* g1 = alloc(NBD); float* g2 = alloc(NBD); float* g3 = alloc(NBD);
    float* lr_t = alloc(Rr); float* fg_t = alloc(Rr); float* mo_t = alloc(Rr);
    float* scal = alloc(8);
    float* gWin = alloc(512 * 512); float* gWh0 = alloc(512 * 512);
    float* gWh1 = alloc(512 * 512); float* gWout = alloc(512 * 512);
    float* gbin = alloc(512); float* gbh0 = alloc(512); float* gbh1 = alloc(512); float* gbout = alloc(512);
    float* nWin = alloc(512 * 512); float* nWh0 = alloc(512 * 512);
    float* nWh1 = alloc(512 * 512); float* nWout = alloc(512 * 512);
    float* nbin = alloc(512); float* nbh0 = alloc(512); float* nbh1 = alloc(512); float* nbout = alloc(512);
    float* parts = alloc(8 * 512 * 512);
    float* cpart = alloc(16 * 512);
    (void)ws_size; (void)in_sizes; (void)n_in; (void)out_size;

    const int EWG = (NBD + 255) / 256;                 // elementwise grid
    auto GEMM_NN = [&](const float* A, const float* Bm, float* C, const float* bias, int accum) {
        k_gemm<0, 0, false><<<dim3(Rr / 128, 4), 256, 0, stream>>>(A, Bm, C, bias, Rr, 512, 512, 1.0f, accum);
    };
    auto GEMM_NT = [&](const float* A, const float* Bm, float* C, int accum) {
        k_gemm<0, 1, false><<<dim3(Rr / 128, 4), 256, 0, stream>>>(A, Bm, C, nullptr, Rr, 512, 512, 1.0f, accum);
    };
    auto GRADW = [&](const float* Aact, const float* Bg, float* Gout) {
        k_gemm<1, 0, true><<<dim3(4, 4, 8), 256, 0, stream>>>(Aact, Bg, parts, nullptr, 512, 512, Rr, 1.0f, 0);
        k_reduce_splitk<<<(262144 + 255) / 256, 256, 0, stream>>>(parts, Gout, 262144, 8, 1.0f / NCc);
    };
    auto COLSUM = [&](const float* Gm, float* bout) {
        k_colsum<<<dim3(2, 16), 256, 0, stream>>>(Gm, cpart);
        k_colsum_reduce<<<2, 256, 0, stream>>>(cpart, bout, 1.0f / NCc);
    };
    auto UPD = [&](const float* p, const float* mom, const float* g, float* outp, int n) {
        k_update<<<(n + 255) / 256, 256, 0, stream>>>(p, mom, g, scal, outp, n);
    };

    // ---- Phase A: xm, gates, q/k/v projections -> conv -> silu (-> l2n) ----
    k_build_xm<<<(Rr * 128 + 255) / 256, 256, 0, stream>>>(x, meta, xm);
    k_gates<<<Rr / 4, 256, 0, stream>>>(xm, lr_w, lr_b, fg_w, fg_b, mo_w, mo_b, lr_t, fg_t, mo_t);
    k_gate_means<<<1, 256, 0, stream>>>(lr_t, fg_t, mo_t, scal);

    GEMM_NN(xm, q_w, t0, q_b, 0);
    k_conv_silu<true><<<Rr, 256, 0, stream>>>(t0, q_c, qb);
    GEMM_NN(xm, k_w, t0, k_b, 0);
    k_conv_silu<true><<<Rr, 256, 0, stream>>>(t0, k_c, kb);
    GEMM_NN(xm, v_w, t0, v_b, 0);
    k_conv_silu<false><<<Rr, 256, 0, stream>>>(t0, v_c, vb);

    // ---- Phase B: memory-MLP forward on k ----
    GEMM_NN(kb, mWin, z0, mbin, 0);
    k_silu<<<EWG, 256, 0, stream>>>(z0, h0, NBD);
    GEMM_NN(h0, mWh, a0, mbh, 0);
    k_res_silu<<<EWG, 256, 0, stream>>>(h0, a0, h1, NBD);
    GEMM_NN(h1, mWh + 512 * 512, a1, mbh + 512, 0);
    k_res_silu<<<EWG, 256, 0, stream>>>(h1, a1, h2, NBD);
    GEMM_NN(h2, mWout, g1, mbout, 0);
    k_dpred<<<EWG, 256, 0, stream>>>(g1, vb, lr_t, NBD);   // g1 = dpred

    // ---- Phase C: backward ----
    GRADW(h2, g1, gWout);  COLSUM(g1, gbout);
    GEMM_NT(g1, mWout, g2, 0);                              // g2 = dh2
    k_dsilu<<<EWG, 256, 0, stream>>>(g2, a1, g3, NBD);      // g3 = da1
    GRADW(h1, g3, gWh1);   COLSUM(g3, gbh1);
    GEMM_NT(g3, mWh + 512 * 512, g2, 1);                    // g2 = dh1
    k_dsilu<<<EWG, 256, 0, stream>>>(g2, a0, g3, NBD);      // g3 = da0
    GRADW(h0, g3, gWh0);   COLSUM(g3, gbh0);
    GEMM_NT(g3, mWh, g2, 1);                                // g2 = dh0
    k_dsilu<<<EWG, 256, 0, stream>>>(g2, z0, g3, NBD);      // g3 = dz0
    GRADW(kb, g3, gWin);   COLSUM(g3, gbin);

    // ---- Phase D: parameter update ----
    UPD(mWin, momWin, gWin, nWin, 262144);
    UPD(mbin, mombin, gbin, nbin, 512);
    UPD(mWh, momWh, gWh0, nWh0, 262144);
    UPD(mWh + 262144, momWh + 262144, gWh1, nWh1, 262144);
    UPD(mbh, mombh, gbh0, nbh0, 512);
    UPD(mbh + 512, mombh + 512, gbh1, nbh1, 512);
    UPD(mWout, momWout, gWout, nWout, 262144);
    UPD(mbout, mombout, gbout, nbout, 512);

    // ---- Phase E: retrieval MLP on q with new params, retrieved -> t0 ----
    GEMM_NN(qb, nWin, z0, nbin, 0);
    k_silu<<<EWG, 256, 0, stream>>>(z0, h0, NBD);
    GEMM_NN(h0, nWh0, a0, nbh0, 0);
    k_res_silu<<<EWG, 256, 0, stream>>>(h0, a0, h1, NBD);
    GEMM_NN(h1, nWh1, a1, nbh1, 0);
    k_res_silu<<<EWG, 256, 0, stream>>>(h1, a1, h2, NBD);
    GEMM_NN(h2, nWout, g1, nbout, 0);
    k_silu<<<EWG, 256, 0, stream>>>(g1, t0, NBD);           // retrieved

    // ---- Phase F: sliding-window attention + out proj + slice ----
    GEMM_NN(t0, swa_wq, g1, swa_bq, 0);
    GEMM_NN(t0, swa_wk, g2, swa_bk, 0);
    GEMM_NN(t0, swa_wv, g3, swa_bv, 0);
    k_swa<<<(Bb * NHh * Nn) / 4, 256, 0, stream>>>(g1, g2, g3, kb);
    GEMM_NN(kb, swa_wo, vb, swa_bo, 0);
    k_slice<<<(Bb * Ss * 128 + 255) / 256, 256, 0, stream>>>(vb, (float*)d_out);
}

// Round 2
// 1491.695 us; speedup vs baseline: 1.8406x; 1.8406x over previous
//
#include <hip/hip_runtime.h>
#include <cmath>

// ---------------------------------------------------------------------------
// NeuralMemory R2: flash-tiled SWA + prefetched 128x64 fp32 GEMM + fused
// elementwise epilogues. Grad trick: vmap'd per-chunk grads == (1/NC)*sum
// over all rows, so everything is flat GEMMs over (B*(M+S)) x D.
// ---------------------------------------------------------------------------

namespace {

constexpr int Bb   = 2;
constexpr int Ss   = 2048;
constexpr int Dd   = 512;
constexpr int Mm   = 64;
constexpr int NCc  = 16;
constexpr int NHh  = 8;
constexpr int HD   = Dd / NHh;   // 64
constexpr int WINw = 256;
constexpr int Nn   = Mm + Ss;    // 2112
constexpr int Rr   = Bb * Nn;    // 4224
constexpr int NBD  = Rr * Dd;    // 2,162,688 floats
constexpr float MAXLR = 0.1f;

__device__ __forceinline__ float sigf(float x)  { return 1.0f / (1.0f + __expf(-x)); }
__device__ __forceinline__ float siluf(float x) { return x * sigf(x); }
__device__ __forceinline__ float dsiluf(float x){ float s = sigf(x); return s * (1.0f + x * (1.0f - s)); }

__global__ void k_build_xm(const float* __restrict__ x, const float* __restrict__ meta,
                           float* __restrict__ xm) {
    int i = blockIdx.x * 256 + threadIdx.x;
    const int nv = Rr * 128;
    if (i >= nv) return;
    int c = i & 127;
    int r = i >> 7;
    int b = r / Nn, t = r - b * Nn;
    float4 v;
    if (t < Mm) v = ((const float4*)meta)[t * 128 + c];
    else        v = ((const float4*)x)[(size_t)(b * Ss + (t - Mm)) * 128 + c];
    ((float4*)xm)[i] = v;
}

__global__ void k_gates(const float* __restrict__ xm,
                        const float* __restrict__ lw, const float* __restrict__ lb,
                        const float* __restrict__ fw, const float* __restrict__ fb,
                        const float* __restrict__ mw, const float* __restrict__ mb,
                        float* __restrict__ lr_t, float* __restrict__ fg_t, float* __restrict__ mo_t) {
    int r = blockIdx.x * 4 + (threadIdx.x >> 6);
    int lane = threadIdx.x & 63;
    if (r >= Rr) return;
    const float* row = xm + (size_t)r * Dd;
    float s0 = 0.f, s1 = 0.f, s2 = 0.f;
    for (int j = lane; j < Dd; j += 64) {
        float v = row[j];
        s0 += v * lw[j]; s1 += v * fw[j]; s2 += v * mw[j];
    }
    #pragma unroll
    for (int off = 32; off; off >>= 1) {
        s0 += __shfl_down(s0, off, 64);
        s1 += __shfl_down(s1, off, 64);
        s2 += __shfl_down(s2, off, 64);
    }
    if (lane == 0) {
        lr_t[r] = MAXLR * sigf(s0 + lb[0]);
        fg_t[r] = sigf(s1 + fb[0]);
        mo_t[r] = sigf(s2 + mb[0]);
    }
}

__global__ void k_gate_means(const float* __restrict__ lr_t, const float* __restrict__ fg_t,
                             const float* __restrict__ mo_t, float* __restrict__ scal) {
    __shared__ float red[256];
    const float* ptrs[3] = { fg_t, lr_t, mo_t };
    for (int w = 0; w < 3; ++w) {
        float acc = 0.f;
        for (int i = threadIdx.x; i < Rr; i += 256) acc += ptrs[w][i];
        red[threadIdx.x] = acc; __syncthreads();
        for (int off = 128; off; off >>= 1) {
            if (threadIdx.x < off) red[threadIdx.x] += red[threadIdx.x + off];
            __syncthreads();
        }
        if (threadIdx.x == 0) scal[w] = red[0] / (float)Rr;
        __syncthreads();
    }
}

// ---- GEMM 128x64 tile, BK=8, 256 thr, 8x4/thread, register prefetch ------
// TA=0: A (M,K) row-major; TA=1: A (K,M) -> computes A^T B.
// TB=0: B (K,N); TB=1: B (N,K) -> computes A B^T.
// EPI: 0 none(+bias,+accum) 1 silu 2 extra+silu 3 dpred 4 dsilu-dual
//      5 silu-dual 6 res-silu-dual 7 bias+slice-to-out
struct Tri { const float* B; const float* bias; float* C; };
struct TriSet { Tri t[3]; };

template<int TA, int TB, bool SPLITK, int EPI, bool MULTI>
__global__ __launch_bounds__(256) void k_gemm(
        const float* __restrict__ A, const float* Bm,
        float* C, const float* bias,
        const float* __restrict__ extra1, const float* __restrict__ lrp,
        float* __restrict__ out2, TriSet ts,
        int Md, int Nd, int Kd, int accum) {
    __shared__ float As[8][128];
    __shared__ float Bs[8][64];
    const int tid = threadIdx.x;
    const int m0 = blockIdx.x * 128;
    const int n0 = blockIdx.y * 64;
    if (MULTI) {
        Bm = ts.t[blockIdx.z].B; bias = ts.t[blockIdx.z].bias; C = ts.t[blockIdx.z].C;
    }
    int k_begin = 0, k_end = Kd;
    if (SPLITK) {
        int kc = Kd / gridDim.z;
        k_begin = blockIdx.z * kc;
        k_end = k_begin + kc;
        C += (size_t)blockIdx.z * Md * Nd;
    }
    float acc[8][4];
    #pragma unroll
    for (int i = 0; i < 8; ++i)
        #pragma unroll
        for (int j = 0; j < 4; ++j) acc[i][j] = 0.f;

    const int ty = tid >> 4, tx = tid & 15;

    auto loadA = [&](int k0) -> float4 {
        if (TA == 0) { int m = tid >> 1, kq = (tid & 1) * 4;
            return *(const float4*)(A + (size_t)(m0 + m) * Kd + k0 + kq); }
        else { int k = tid >> 5, mq = (tid & 31) * 4;
            return *(const float4*)(A + (size_t)(k0 + k) * Md + m0 + mq); }
    };
    auto loadB = [&](int k0) -> float2 {
        if (TB == 0) { int k = tid >> 5, n2 = (tid & 31) * 2;
            return *(const float2*)(Bm + (size_t)(k0 + k) * Nd + n0 + n2); }
        else { int n = tid >> 2, kq = (tid & 3) * 2;
            return *(const float2*)(Bm + (size_t)(n0 + n) * Kd + k0 + kq); }
    };
    auto storeA = [&](float4 v) {
        if (TA == 0) { int m = tid >> 1, kq = (tid & 1) * 4;
            As[kq + 0][m] = v.x; As[kq + 1][m] = v.y; As[kq + 2][m] = v.z; As[kq + 3][m] = v.w; }
        else { int k = tid >> 5, mq = (tid & 31) * 4; *(float4*)&As[k][mq] = v; }
    };
    auto storeB = [&](float2 v) {
        if (TB == 0) { int k = tid >> 5, n2 = (tid & 31) * 2;
            Bs[k][n2] = v.x; Bs[k][n2 + 1] = v.y; }
        else { int n = tid >> 2, kq = (tid & 3) * 2;
            Bs[kq + 0][n] = v.x; Bs[kq + 1][n] = v.y; }
    };

    float4 pA = loadA(k_begin);
    float2 pB = loadB(k_begin);
    for (int k0 = k_begin; k0 < k_end; k0 += 8) {
        storeA(pA); storeB(pB);
        __syncthreads();
        if (k0 + 8 < k_end) { pA = loadA(k0 + 8); pB = loadB(k0 + 8); }
        #pragma unroll
        for (int k = 0; k < 8; ++k) {
            float a[8], bq[4];
            *(float4*)&a[0]  = *(const float4*)&As[k][ty * 4];
            *(float4*)&a[4]  = *(const float4*)&As[k][64 + ty * 4];
            *(float4*)&bq[0] = *(const float4*)&Bs[k][tx * 4];
            #pragma unroll
            for (int i = 0; i < 8; ++i)
                #pragma unroll
                for (int j = 0; j < 4; ++j)
                    acc[i][j] += a[i] * bq[j];
        }
        __syncthreads();
    }

    #pragma unroll
    for (int i = 0; i < 8; ++i) {
        int mr = (i < 4) ? (ty * 4 + i) : (64 + ty * 4 + (i - 4));
        int m = m0 + mr;
        int n = n0 + tx * 4;
        float v[4] = { acc[i][0], acc[i][1], acc[i][2], acc[i][3] };
        size_t idx = (size_t)m * Nd + n;
        if (SPLITK) {
            *(float4*)(C + idx) = *(float4*)v;
            continue;
        }
        if (EPI != 4 && bias) {
            #pragma unroll
            for (int j = 0; j < 4; ++j) v[j] += bias[n + j];
        }
        if (EPI == 0) {
            if (accum) { float4 o = *(float4*)(C + idx);
                v[0] += o.x; v[1] += o.y; v[2] += o.z; v[3] += o.w; }
            *(float4*)(C + idx) = *(float4*)v;
        } else if (EPI == 1) {
            #pragma unroll
            for (int j = 0; j < 4; ++j) v[j] = siluf(v[j]);
            *(float4*)(C + idx) = *(float4*)v;
        } else if (EPI == 2) {
            #pragma unroll
            for (int j = 0; j < 4; ++j) v[j] = extra1[idx + j] + siluf(v[j]);
            *(float4*)(C + idx) = *(float4*)v;
        } else if (EPI == 3) {
            float sc = (2.0f / (float)Dd) * lrp[m];
            #pragma unroll
            for (int j = 0; j < 4; ++j) v[j] = sc * (v[j] - extra1[idx + j]);
            *(float4*)(C + idx) = *(float4*)v;
        } else if (EPI == 4) {
            if (accum) { float4 o = *(float4*)(C + idx);
                v[0] += o.x; v[1] += o.y; v[2] += o.z; v[3] += o.w; }
            *(float4*)(C + idx) = *(float4*)v;
            float w[4];
            #pragma unroll
            for (int j = 0; j < 4; ++j) w[j] = v[j] * dsiluf(extra1[idx + j]);
            *(float4*)(out2 + idx) = *(float4*)w;
        } else if (EPI == 5) {
            *(float4*)(C + idx) = *(float4*)v;
            float w[4];
            #pragma unroll
            for (int j = 0; j < 4; ++j) w[j] = siluf(v[j]);
            *(float4*)(out2 + idx) = *(float4*)w;
        } else if (EPI == 6) {
            *(float4*)(C + idx) = *(float4*)v;
            float w[4];
            #pragma unroll
            for (int j = 0; j < 4; ++j) w[j] = extra1[idx + j] + siluf(v[j]);
            *(float4*)(out2 + idx) = *(float4*)w;
        } else if (EPI == 7) {
            int b = m / Nn, t = m - b * Nn;
            if (t >= Mm)
                *(float4*)(C + (size_t)(b * Ss + (t - Mm)) * Nd + n) = *(float4*)v;
        }
    }
}

__global__ void k_reduce_splitk(const float* __restrict__ part, float* __restrict__ out,
                                int n, int z, float alpha) {
    int i = blockIdx.x * 256 + threadIdx.x;
    if (i >= n) return;
    float s = 0.f;
    for (int zz = 0; zz < z; ++zz) s += part[(size_t)zz * n + i];
    out[i] = alpha * s;
}

__global__ __launch_bounds__(256) void k_conv3(
        const float* __restrict__ yq, const float* __restrict__ yk, const float* __restrict__ yv,
        const float* __restrict__ cq, const float* __restrict__ ck, const float* __restrict__ cv,
        float* __restrict__ oq, float* __restrict__ ok, float* __restrict__ ov) {
    int which = blockIdx.y;
    const float* y  = which == 0 ? yq : which == 1 ? yk : yv;
    const float* cw = which == 0 ? cq : which == 1 ? ck : cv;
    float* out      = which == 0 ? oq : which == 1 ? ok : ov;
    bool norm = which < 2;
    int r = blockIdx.x;
    int b = r / Nn, t = r - b * Nn;
    const size_t rowbase = (size_t)r * Dd;
    float s[2];
    #pragma unroll
    for (int u = 0; u < 2; ++u) {
        int d = threadIdx.x + u * 256;
        float acc = 0.f;
        #pragma unroll
        for (int k = 0; k < 4; ++k) {
            int tt = t - 3 + k;
            if (tt >= 0) acc += y[(size_t)(b * Nn + tt) * Dd + d] * cw[d * 4 + k];
        }
        s[u] = siluf(acc);
    }
    if (norm) {
        __shared__ float red[256];
        red[threadIdx.x] = s[0] * s[0] + s[1] * s[1];
        __syncthreads();
        for (int off = 128; off; off >>= 1) {
            if (threadIdx.x < off) red[threadIdx.x] += red[threadIdx.x + off];
            __syncthreads();
        }
        float denom = fmaxf(sqrtf(red[0]), 1e-12f);
        out[rowbase + threadIdx.x]       = s[0] / denom;
        out[rowbase + threadIdx.x + 256] = s[1] / denom;
    } else {
        out[rowbase + threadIdx.x]       = s[0];
        out[rowbase + threadIdx.x + 256] = s[1];
    }
}

__global__ void k_colsum(const float* __restrict__ g, float* __restrict__ part) {
    int col = blockIdx.x * 256 + threadIdx.x;
    int chunk = blockIdx.y;                      // 64 chunks of 66 rows
    int r0 = chunk * (Rr / 64);
    float s = 0.f;
    for (int r = r0; r < r0 + Rr / 64; ++r) s += g[(size_t)r * Dd + col];
    part[chunk * Dd + col] = s;
}
__global__ void k_colsum_reduce(const float* __restrict__ part, float* __restrict__ out, float alpha) {
    int col = blockIdx.x * 256 + threadIdx.x;
    if (col >= Dd) return;
    float s = 0.f;
    for (int c = 0; c < 64; ++c) s += part[c * Dd + col];
    out[col] = alpha * s;
}

struct UpdSet { const float* p[4]; const float* mom[4]; const float* g[4]; float* o[4]; };
__global__ void k_update4(UpdSet u, const float* __restrict__ scal, int seg_elems) {
    int blocks_per = (seg_elems + 255) / 256;
    int seg = blockIdx.x / blocks_per;
    int i = (blockIdx.x - seg * blocks_per) * 256 + threadIdx.x;
    if (i >= seg_elems) return;
    u.o[seg][i] = u.p[seg][i] * (1.0f - scal[0]) + scal[2] * u.mom[seg][i] - scal[1] * u.g[seg][i];
}

// ---- flash-tiled sliding-window attention --------------------------------
__global__ __launch_bounds__(256) void k_swa(const float* __restrict__ qs,
                                             const float* __restrict__ ks,
                                             const float* __restrict__ vs,
                                             float* __restrict__ out) {
    __shared__ float Ks[32][64];
    __shared__ float Vs[32][64];
    const int tid = threadIdx.x;
    const int q0 = blockIdx.x * 64;
    const int bh = blockIdx.y;
    const int h = bh & 7, b = bh >> 3;
    const int ql = tid >> 2, g = tid & 3;
    const int i = q0 + ql;
    const size_t srow = (size_t)(b * Nn) * Dd + h * HD;

    float qreg[16], o[16];
    #pragma unroll
    for (int d4 = 0; d4 < 4; ++d4)
        *(float4*)&qreg[d4 * 4] = *(const float4*)(qs + srow + (size_t)i * Dd + g * 16 + d4 * 4);
    #pragma unroll
    for (int d = 0; d < 16; ++d) o[d] = 0.f;
    float mrun = -1e30f, lrun = 0.f;

    int wstart = q0 - (WINw - 1);
    int jt0 = wstart <= 0 ? 0 : (wstart & ~31);
    for (int jt = jt0; jt <= q0 + 63; jt += 32) {
        __syncthreads();
        #pragma unroll
        for (int u = 0; u < 2; ++u) {
            int idx = tid + u * 256;
            int row = idx >> 4, c4 = (idx & 15) * 4;
            *(float4*)&Ks[row][c4] = *(const float4*)(ks + srow + (size_t)(jt + row) * Dd + c4);
            *(float4*)&Vs[row][c4] = *(const float4*)(vs + srow + (size_t)(jt + row) * Dd + c4);
        }
        __syncthreads();

        float sreg[32];
        #pragma unroll
        for (int j = 0; j < 32; ++j) {
            float p = 0.f;
            #pragma unroll
            for (int d4 = 0; d4 < 4; ++d4) {
                float4 kv = *(const float4*)&Ks[j][g * 16 + d4 * 4];
                p += qreg[d4 * 4 + 0] * kv.x + qreg[d4 * 4 + 1] * kv.y
                   + qreg[d4 * 4 + 2] * kv.z + qreg[d4 * 4 + 3] * kv.w;
            }
            p += __shfl_xor(p, 1);
            p += __shfl_xor(p, 2);
            int jg = jt + j;
            bool ok = (jg <= i) && (i - jg < WINw);
            sreg[j] = ok ? p * 0.125f : -1e30f;
        }
        float mt = -1e30f;
        #pragma unroll
        for (int j = 0; j < 32; ++j) mt = fmaxf(mt, sreg[j]);
        float mnew = fmaxf(mrun, mt);
        float corr = __expf(mrun - mnew);
        lrun *= corr;
        #pragma unroll
        for (int d = 0; d < 16; ++d) o[d] *= corr;
        #pragma unroll
        for (int j = 0; j < 32; ++j) {
            float pj = (sreg[j] > -1e29f) ? __expf(sreg[j] - mnew) : 0.f;
            lrun += pj;
            #pragma unroll
            for (int d4 = 0; d4 < 4; ++d4) {
                float4 vv = *(const float4*)&Vs[j][g * 16 + d4 * 4];
                o[d4 * 4 + 0] += pj * vv.x; o[d4 * 4 + 1] += pj * vv.y;
                o[d4 * 4 + 2] += pj * vv.z; o[d4 * 4 + 3] += pj * vv.w;
            }
        }
        mrun = mnew;
    }
    float invl = 1.0f / lrun;
    #pragma unroll
    for (int d4 = 0; d4 < 4; ++d4) {
        float4 v;
        v.x = o[d4 * 4 + 0] * invl; v.y = o[d4 * 4 + 1] * invl;
        v.z = o[d4 * 4 + 2] * invl; v.w = o[d4 * 4 + 3] * invl;
        *(float4*)(out + srow + (size_t)i * Dd + g * 16 + d4 * 4) = v;
    }
}

} // namespace

extern "C" void kernel_launch(void* const* d_in, const int* in_sizes, int n_in,
                              void* d_out, int out_size, void* d_ws, size_t ws_size,
                              hipStream_t stream) {
    const float* x       = (const float*)d_in[0];
    const float* meta    = (const float*)d_in[1];
    const float* mWin    = (const float*)d_in[2];
    const float* mbin    = (const float*)d_in[3];
    const float* mWh     = (const float*)d_in[4];
    const float* mbh     = (const float*)d_in[5];
    const float* mWout   = (const float*)d_in[6];
    const float* mbout   = (const float*)d_in[7];
    const float* momWin  = (const float*)d_in[8];
    const float* mombin  = (const float*)d_in[9];
    const float* momWh   = (const float*)d_in[10];
    const float* mombh   = (const float*)d_in[11];
    const float* momWout = (const float*)d_in[12];
    const float* mombout = (const float*)d_in[13];
    const float* q_w = (const float*)d_in[14]; const float* q_b = (const float*)d_in[15]; const float* q_c = (const float*)d_in[16];
    const float* k_w = (const float*)d_in[17]; const float* k_b = (const float*)d_in[18]; const float* k_c = (const float*)d_in[19];
    const float* v_w = (const float*)d_in[20]; const float* v_b = (const float*)d_in[21]; const float* v_c = (const float*)d_in[22];
    const float* lr_w = (const float*)d_in[23]; const float* lr_b = (const float*)d_in[24];
    const float* fg_w = (const float*)d_in[25]; const float* fg_b = (const float*)d_in[26];
    const float* mo_w = (const float*)d_in[27]; const float* mo_b = (const float*)d_in[28];
    const float* swa_wq = (const float*)d_in[29]; const float* swa_wk = (const float*)d_in[30];
    const float* swa_wv = (const float*)d_in[31]; const float* swa_wo = (const float*)d_in[32];
    const float* swa_bq = (const float*)d_in[33]; const float* swa_bk = (const float*)d_in[34];
    const float* swa_bv = (const float*)d_in[35]; const float* swa_bo = (const float*)d_in[36];

    float* ws = (float*)d_ws;
    size_t off = 0;
    auto alloc = [&](size_t n) { float* p = ws + off; off += n; return p; };
    float* xm = alloc(NBD); float* t0 = alloc(NBD);
    float* qb = alloc(NBD); float* kb = alloc(NBD); float* vb = alloc(NBD);
    float* z0 = alloc(NBD); float* h0 = alloc(NBD); float* a0 = alloc(NBD);
    float* h1 = alloc(NBD); float* a1 = alloc(NBD); float* h2 = alloc(NBD);
    float* g1 = alloc(NBD); float* g2 = alloc(NBD); float* g3 = alloc(NBD);
    float* lr_t = alloc(Rr); float* fg_t = alloc(Rr); float* mo_t = alloc(Rr);
    float* scal = alloc(8);
    float* gWin = alloc(262144); float* gWh0 = alloc(262144);
    float* gWh1 = alloc(262144); float* gWout = alloc(262144);
    float* gbin = alloc(512); float* gbh0 = alloc(512); float* gbh1 = alloc(512); float* gbout = alloc(512);
    float* nWin = alloc(262144); float* nWh0 = alloc(262144);
    float* nWh1 = alloc(262144); float* nWout = alloc(262144);
    float* nbin = alloc(512); float* nbh0 = alloc(512); float* nbh1 = alloc(512); float* nbout = alloc(512);
    float* parts = alloc(8 * 262144);
    float* cpart = alloc(64 * 512);
    (void)ws_size; (void)in_sizes; (void)n_in; (void)out_size;

    const dim3 GG(Rr / 128, Dd / 64);          // 33 x 8 = 264 blocks
    TriSet none{};

    auto GRADW = [&](const float* Aact, const float* Bg, float* Gout) {
        k_gemm<1, 0, true, 0, false><<<dim3(4, 8, 8), 256, 0, stream>>>(
            Aact, Bg, parts, nullptr, nullptr, nullptr, nullptr, none, Dd, Dd, Rr, 0);
        k_reduce_splitk<<<(262144 + 255) / 256, 256, 0, stream>>>(parts, Gout, 262144, 8, 1.0f / NCc);
    };
    auto COLSUM = [&](const float* Gm, float* bo) {
        k_colsum<<<dim3(2, 64), 256, 0, stream>>>(Gm, cpart);
        k_colsum_reduce<<<2, 256, 0, stream>>>(cpart, bo, 1.0f / NCc);
    };

    // ---- Phase A ----
    k_build_xm<<<(Rr * 128 + 255) / 256, 256, 0, stream>>>(x, meta, xm);
    k_gates<<<Rr / 4, 256, 0, stream>>>(xm, lr_w, lr_b, fg_w, fg_b, mo_w, mo_b, lr_t, fg_t, mo_t);
    k_gate_means<<<1, 256, 0, stream>>>(lr_t, fg_t, mo_t, scal);

    TriSet qkvA{{ {q_w, q_b, g3}, {k_w, k_b, g2}, {v_w, v_b, g1} }};
    k_gemm<0, 0, false, 0, true><<<dim3(Rr / 128, 8, 3), 256, 0, stream>>>(
        xm, nullptr, nullptr, nullptr, nullptr, nullptr, nullptr, qkvA, Rr, Dd, Dd, 0);
    k_conv3<<<dim3(Rr, 3), 256, 0, stream>>>(g3, g2, g1, q_c, k_c, v_c, qb, kb, vb);

    // ---- Phase B: memory-MLP forward (pre-acts kept for bwd) ----
    k_gemm<0, 0, false, 5, false><<<GG, 256, 0, stream>>>(
        kb, mWin, z0, mbin, nullptr, nullptr, h0, none, Rr, Dd, Dd, 0);
    k_gemm<0, 0, false, 6, false><<<GG, 256, 0, stream>>>(
        h0, mWh, a0, mbh, h0, nullptr, h1, none, Rr, Dd, Dd, 0);
    k_gemm<0, 0, false, 6, false><<<GG, 256, 0, stream>>>(
        h1, mWh + 262144, a1, mbh + 512, h1, nullptr, h2, none, Rr, Dd, Dd, 0);
    k_gemm<0, 0, false, 3, false><<<GG, 256, 0, stream>>>(
        h2, mWout, g1, mbout, vb, lr_t, nullptr, none, Rr, Dd, Dd, 0);   // g1 = dpred

    // ---- Phase C: backward ----
    GRADW(h2, g1, gWout);  COLSUM(g1, gbout);
    k_gemm<0, 1, false, 4, false><<<GG, 256, 0, stream>>>(
        g1, mWout, g2, nullptr, a1, nullptr, g3, none, Rr, Dd, Dd, 0);   // g2=dh2, g3=da1
    GRADW(h1, g3, gWh1);   COLSUM(g3, gbh1);
    k_gemm<0, 1, false, 4, false><<<GG, 256, 0, stream>>>(
        g3, mWh + 262144, g2, nullptr, a0, nullptr, t0, none, Rr, Dd, Dd, 1); // g2=dh1, t0=da0
    GRADW(h0, t0, gWh0);   COLSUM(t0, gbh0);
    k_gemm<0, 1, false, 4, false><<<GG, 256, 0, stream>>>(
        t0, mWh, g2, nullptr, z0, nullptr, g3, none, Rr, Dd, Dd, 1);     // g2=dh0, g3=dz0
    GRADW(kb, g3, gWin);   COLSUM(g3, gbin);

    // ---- Phase D ----
    UpdSet uw{{mWin, mWh, mWh + 262144, mWout},
              {momWin, momWh, momWh + 262144, momWout},
              {gWin, gWh0, gWh1, gWout},
              {nWin, nWh0, nWh1, nWout}};
    k_update4<<<4 * 1024, 256, 0, stream>>>(uw, scal, 262144);
    UpdSet ub{{mbin, mbh, mbh + 512, mbout},
              {mombin, mombh, mombh + 512, mombout},
              {gbin, gbh0, gbh1, gbout},
              {nbin, nbh0, nbh1, nbout}};
    k_update4<<<4 * 2, 256, 0, stream>>>(ub, scal, 512);

    // ---- Phase E: retrieval MLP on q with new params ----
    k_gemm<0, 0, false, 1, false><<<GG, 256, 0, stream>>>(
        qb, nWin, z0, nbin, nullptr, nullptr, nullptr, none, Rr, Dd, Dd, 0);
    k_gemm<0, 0, false, 2, false><<<GG, 256, 0, stream>>>(
        z0, nWh0, h0, nbh0, z0, nullptr, nullptr, none, Rr, Dd, Dd, 0);
    k_gemm<0, 0, false, 2, false><<<GG, 256, 0, stream>>>(
        h0, nWh1, h1, nbh1, h0, nullptr, nullptr, none, Rr, Dd, Dd, 0);
    k_gemm<0, 0, false, 1, false><<<GG, 256, 0, stream>>>(
        h1, nWout, t0, nbout, nullptr, nullptr, nullptr, none, Rr, Dd, Dd, 0); // retrieved

    // ---- Phase F ----
    TriSet qkvF{{ {swa_wq, swa_bq, g1}, {swa_wk, swa_bk, g2}, {swa_wv, swa_bv, g3} }};
    k_gemm<0, 0, false, 0, true><<<dim3(Rr / 128, 8, 3), 256, 0, stream>>>(
        t0, nullptr, nullptr, nullptr, nullptr, nullptr, nullptr, qkvF, Rr, Dd, Dd, 0);
    k_swa<<<dim3(Nn / 64, Bb * NHh), 256, 0, stream>>>(g1, g2, g3, kb);
    k_gemm<0, 0, false, 7, false><<<GG, 256, 0, stream>>>(
        kb, swa_wo, (float*)d_out, swa_bo, nullptr, nullptr, nullptr, none, Rr, Dd, Dd, 0);
}

// Round 3
// 1017.963 us; speedup vs baseline: 2.6972x; 1.4654x over previous
//
#include <hip/hip_runtime.h>
#include <cmath>

// ---------------------------------------------------------------------------
// NeuralMemory R3: bf16 MFMA GEMMs (16x16x32), bf16x2 split (3-MFMA) on the
// output-critical path, plain bf16 on the theta-damped gradient path.
// Activations stored as bf16 hi/lo pairs; weights converted+transposed once.
// ---------------------------------------------------------------------------

namespace {

constexpr int Bb   = 2;
constexpr int Ss   = 2048;
constexpr int Dd   = 512;
constexpr int Mm   = 64;
constexpr int NCc  = 16;
constexpr int NHh  = 8;
constexpr int HD   = 64;
constexpr int WINw = 256;
constexpr int Nn   = Mm + Ss;    // 2112
constexpr int Rr   = Bb * Nn;    // 4224
constexpr int NBD  = Rr * Dd;
constexpr float MAXLR = 0.1f;

typedef __attribute__((ext_vector_type(8))) short short8;
typedef __attribute__((ext_vector_type(4))) float f32x4;

__device__ __forceinline__ float sigf(float x)  { return 1.0f / (1.0f + __expf(-x)); }
__device__ __forceinline__ float siluf(float x) { return x * sigf(x); }
__device__ __forceinline__ float dsiluf(float x){ float s = sigf(x); return s * (1.0f + x * (1.0f - s)); }
__device__ __forceinline__ unsigned short f2bf(float f) {
    unsigned int u = __float_as_uint(f);
    u = (u + 0x7FFFu + ((u >> 16) & 1u)) >> 16;
    return (unsigned short)u;
}
__device__ __forceinline__ float bf2f(unsigned short h) {
    return __uint_as_float(((unsigned int)h) << 16);
}

// ---- build xm (hi/lo bf16) ------------------------------------------------
__global__ void k_build_xm(const float* __restrict__ x, const float* __restrict__ meta,
                           unsigned short* __restrict__ xh, unsigned short* __restrict__ xl) {
    int i = blockIdx.x * 256 + threadIdx.x;      // float4 units
    if (i >= Rr * 128) return;
    int c = i & 127, r = i >> 7;
    int b = r / Nn, t = r - b * Nn;
    float4 v = (t < Mm) ? ((const float4*)meta)[t * 128 + c]
                        : ((const float4*)x)[(size_t)(b * Ss + (t - Mm)) * 128 + c];
    float vv[4] = { v.x, v.y, v.z, v.w };
    unsigned short h[4], l[4];
    #pragma unroll
    for (int e = 0; e < 4; ++e) { h[e] = f2bf(vv[e]); l[e] = f2bf(vv[e] - bf2f(h[e])); }
    *(ushort4*)(xh + (size_t)i * 4) = *(ushort4*)h;
    *(ushort4*)(xl + (size_t)i * 4) = *(ushort4*)l;
}

// ---- per-row scalar gates (reads xm hi/lo) --------------------------------
__global__ void k_gates(const unsigned short* __restrict__ xh, const unsigned short* __restrict__ xl,
                        const float* __restrict__ lw, const float* __restrict__ lb,
                        const float* __restrict__ fw, const float* __restrict__ fb,
                        const float* __restrict__ mw, const float* __restrict__ mb,
                        float* __restrict__ lr_t, float* __restrict__ fg_t, float* __restrict__ mo_t) {
    int r = blockIdx.x * 4 + (threadIdx.x >> 6);
    int lane = threadIdx.x & 63;
    if (r >= Rr) return;
    float s0 = 0.f, s1 = 0.f, s2 = 0.f;
    for (int j = lane; j < Dd; j += 64) {
        size_t o = (size_t)r * Dd + j;
        float v = bf2f(xh[o]) + bf2f(xl[o]);
        s0 += v * lw[j]; s1 += v * fw[j]; s2 += v * mw[j];
    }
    #pragma unroll
    for (int off = 32; off; off >>= 1) {
        s0 += __shfl_down(s0, off, 64);
        s1 += __shfl_down(s1, off, 64);
        s2 += __shfl_down(s2, off, 64);
    }
    if (lane == 0) {
        lr_t[r] = MAXLR * sigf(s0 + lb[0]);
        fg_t[r] = sigf(s1 + fb[0]);
        mo_t[r] = sigf(s2 + mb[0]);
    }
}

__global__ void k_gate_means(const float* __restrict__ lr_t, const float* __restrict__ fg_t,
                             const float* __restrict__ mo_t, float* __restrict__ scal) {
    __shared__ float red[256];
    const float* ptrs[3] = { fg_t, lr_t, mo_t };
    for (int w = 0; w < 3; ++w) {
        float acc = 0.f;
        for (int i = threadIdx.x; i < Rr; i += 256) acc += ptrs[w][i];
        red[threadIdx.x] = acc; __syncthreads();
        for (int off = 128; off; off >>= 1) {
            if (threadIdx.x < off) red[threadIdx.x] += red[threadIdx.x + off];
            __syncthreads();
        }
        if (threadIdx.x == 0) scal[w] = red[0] / (float)Rr;
        __syncthreads();
    }
}

// ---- weight convert: fp32 W[r][c] -> WT hi/lo [c][r]; optional natural hi --
struct WC { const float* w[11]; unsigned short* th[11]; unsigned short* tl[11]; unsigned short* nh[11]; };
__global__ void k_wconv(WC wc) {
    int seg = blockIdx.y;
    int i0 = blockIdx.x * 1024 + threadIdx.x * 4;
    float4 v4 = *(const float4*)(wc.w[seg] + i0);
    float vals[4] = { v4.x, v4.y, v4.z, v4.w };
    int r = i0 >> 9, c = i0 & 511;
    #pragma unroll
    for (int e = 0; e < 4; ++e) {
        unsigned short h = f2bf(vals[e]);
        unsigned short l = f2bf(vals[e] - bf2f(h));
        wc.th[seg][(size_t)(c + e) * 512 + r] = h;
        wc.tl[seg][(size_t)(c + e) * 512 + r] = l;
        if (wc.nh[seg]) wc.nh[seg][i0 + e] = h;
    }
}

// ---- MFMA GEMM ------------------------------------------------------------
// Tile 128x64, BK=32, 256 thr (4 waves, each 64x32 via 4x2 16x16x32 frags).
// TA=0: A row-major (M,K) bf16 hi(/lo) or fp32 (AF32, split on the fly).
// TA=1: A = actT: frag A[m][k] = act[k][m] (GRADW).
// TB=0: B pointer in [n][k] layout (transposed weights / natural W for dh).
// TB=1: B row-major [k][n] (grad matrices, GRADW).
// NS=3: bf16x2 split (A,B hi/lo; 3 MFMA per frag pair). NS=1: plain bf16 hi.
// EPI: 0 fp32(+bias,+accum) | 1 silu->hi/lo | 2 extraHL+silu->hi/lo
//      3 dpred->hi/lo | 4 accum fp32 prim + prim*dsilu(exf)->hi/lo
//      5 fp32 prim + silu->hi/lo | 6 fp32 prim + extraHL+silu->hi/lo
//      7 bias+slice fp32 -> d_out
struct TriW { const unsigned short* bh; const unsigned short* bl; const float* bias; float* c; };
struct TriSet { TriW t[3]; };

template<int TA, int TB, bool SPLITK, int EPI, bool MULTI, int NS, bool AF32>
__global__ __launch_bounds__(256) void k_mm(
        const void* Ap, const unsigned short* Al_,
        const unsigned short* Bh_, const unsigned short* Bl_,
        float* C, const float* bias, const float* __restrict__ exf,
        const unsigned short* __restrict__ exh, const unsigned short* __restrict__ exl,
        const float* __restrict__ lrp,
        unsigned short* oh, unsigned short* ol, TriSet ts,
        int Md, int Nd, int Kd, int accum) {
    __shared__ char smem[32768];
    unsigned short* AH = (unsigned short*)smem;   // 4096 elems
    unsigned short* AL = AH + 4096;
    unsigned short* BH = AH + 8192;               // 2048 elems
    unsigned short* BL = AH + 10240;
    const int tid = threadIdx.x;
    const int m0 = blockIdx.x * 128, n0 = blockIdx.y * 64;
    if constexpr (MULTI) {
        const TriW& tw = ts.t[blockIdx.z];
        Bh_ = tw.bh; Bl_ = tw.bl; bias = tw.bias; C = tw.c;
    }
    int kbg = 0, ke = Kd;
    if constexpr (SPLITK) {
        int kc = Kd / gridDim.z;
        kbg = blockIdx.z * kc; ke = kbg + kc;
        C += (size_t)blockIdx.z * Md * Nd;
    }
    const int astr = (TA == 0) ? Kd : Md;

    f32x4 acc[4][2];
    #pragma unroll
    for (int i = 0; i < 4; ++i)
        #pragma unroll
        for (int j = 0; j < 2; ++j)
            #pragma unroll
            for (int v = 0; v < 4; ++v) acc[i][j][v] = 0.f;

    short8 pAh[2], pAl[2], pBh, pBl;
    float4 pAf[4];

    auto gload = [&](int k0) {
        if constexpr (TA == 0) {
            int mm = tid >> 1, half = tid & 1;
            if constexpr (AF32) {
                const float* ap = (const float*)Ap + (size_t)(m0 + mm) * astr + k0 + half * 16;
                pAf[0] = *(const float4*)ap;       pAf[1] = *(const float4*)(ap + 4);
                pAf[2] = *(const float4*)(ap + 8); pAf[3] = *(const float4*)(ap + 12);
            } else {
                const unsigned short* ah = (const unsigned short*)Ap + (size_t)(m0 + mm) * astr + k0 + half * 16;
                pAh[0] = *(const short8*)ah; pAh[1] = *(const short8*)(ah + 8);
                if constexpr (NS == 3) {
                    const unsigned short* al = Al_ + (size_t)(m0 + mm) * astr + k0 + half * 16;
                    pAl[0] = *(const short8*)al; pAl[1] = *(const short8*)(al + 8);
                }
            }
        } else {
            #pragma unroll
            for (int l = 0; l < 2; ++l) {
                int idx = tid + l * 256, kk = idx >> 4, mg = (idx & 15) * 8;
                const unsigned short* ah = (const unsigned short*)Ap + (size_t)(k0 + kk) * astr + m0 + mg;
                pAh[l] = *(const short8*)ah;
                if constexpr (NS == 3) {
                    const unsigned short* al = Al_ + (size_t)(k0 + kk) * astr + m0 + mg;
                    pAl[l] = *(const short8*)al;
                }
            }
        }
        if constexpr (TB == 0) {
            int nr = tid >> 2, kc2 = (tid & 3) * 8;
            pBh = *(const short8*)(Bh_ + (size_t)(n0 + nr) * Kd + k0 + kc2);
            if constexpr (NS == 3) pBl = *(const short8*)(Bl_ + (size_t)(n0 + nr) * Kd + k0 + kc2);
        } else {
            int kk = tid >> 3, ng = (tid & 7) * 8;
            pBh = *(const short8*)(Bh_ + (size_t)(k0 + kk) * Nd + n0 + ng);
            if constexpr (NS == 3) pBl = *(const short8*)(Bl_ + (size_t)(k0 + kk) * Nd + n0 + ng);
        }
    };
    auto lstore = [&]() {
        if constexpr (TA == 0) {
            int mm = tid >> 1, half = tid & 1, f = mm >> 4, r = mm & 15;
            int base = ((f * 4 + half * 2) * 16 + r) * 8;
            if constexpr (AF32) {
                unsigned short hh[16], ll[16];
                const float* pf = (const float*)pAf;
                #pragma unroll
                for (int e = 0; e < 16; ++e) { hh[e] = f2bf(pf[e]); ll[e] = f2bf(pf[e] - bf2f(hh[e])); }
                *(short8*)(AH + base) = *(short8*)hh;  *(short8*)(AH + base + 128) = *(short8*)(hh + 8);
                *(short8*)(AL + base) = *(short8*)ll;  *(short8*)(AL + base + 128) = *(short8*)(ll + 8);
            } else {
                *(short8*)(AH + base) = pAh[0]; *(short8*)(AH + base + 128) = pAh[1];
                if constexpr (NS == 3) { *(short8*)(AL + base) = pAl[0]; *(short8*)(AL + base + 128) = pAl[1]; }
            }
        } else {
            #pragma unroll
            for (int l = 0; l < 2; ++l) {
                int idx = tid + l * 256, kk = idx >> 4, mg = (idx & 15) * 8;
                int f = mg >> 4, rb = mg & 15, q = kk >> 3, j = kk & 7;
                int base = ((f * 4 + q) * 16 + rb) * 8 + j;
                unsigned short tmp[8]; *(short8*)tmp = pAh[l];
                #pragma unroll
                for (int c2 = 0; c2 < 8; ++c2) AH[base + c2 * 8] = tmp[c2];
                if constexpr (NS == 3) {
                    *(short8*)tmp = pAl[l];
                    #pragma unroll
                    for (int c2 = 0; c2 < 8; ++c2) AL[base + c2 * 8] = tmp[c2];
                }
            }
        }
        if constexpr (TB == 0) {
            int nr = tid >> 2, kc2 = (tid & 3) * 8;
            int base = (((nr >> 4) * 4 + (kc2 >> 3)) * 16 + (nr & 15)) * 8;
            *(short8*)(BH + base) = pBh;
            if constexpr (NS == 3) *(short8*)(BL + base) = pBl;
        } else {
            int kk = tid >> 3, ng = (tid & 7) * 8;
            int f = ng >> 4, rb = ng & 15, q = kk >> 3, j = kk & 7;
            int base = ((f * 4 + q) * 16 + rb) * 8 + j;
            unsigned short tmp[8]; *(short8*)tmp = pBh;
            #pragma unroll
            for (int c2 = 0; c2 < 8; ++c2) BH[base + c2 * 8] = tmp[c2];
            if constexpr (NS == 3) {
                *(short8*)tmp = pBl;
                #pragma unroll
                for (int c2 = 0; c2 < 8; ++c2) BL[base + c2 * 8] = tmp[c2];
            }
        }
    };

    const int w = tid >> 6, lr16 = tid & 15, lq = (tid >> 4) & 3;
    const int mh = w & 1, nh = w >> 1;

    gload(kbg); lstore();
    __syncthreads();
    for (int k0 = kbg; k0 < ke; k0 += 32) {
        bool more = (k0 + 32) < ke;
        if (more) gload(k0 + 32);
        short8 fa[4], fal[4], fb[2], fbl[2];
        #pragma unroll
        for (int i = 0; i < 4; ++i) {
            int off = (((mh * 4 + i) * 4 + lq) * 16 + lr16) * 8;
            fa[i] = *(const short8*)(AH + off);
            if constexpr (NS == 3) fal[i] = *(const short8*)(AL + off);
        }
        #pragma unroll
        for (int j = 0; j < 2; ++j) {
            int off = (((nh * 2 + j) * 4 + lq) * 16 + lr16) * 8;
            fb[j] = *(const short8*)(BH + off);
            if constexpr (NS == 3) fbl[j] = *(const short8*)(BL + off);
        }
        #pragma unroll
        for (int i = 0; i < 4; ++i)
            #pragma unroll
            for (int j = 0; j < 2; ++j) {
                acc[i][j] = __builtin_amdgcn_mfma_f32_16x16x32_bf16(fa[i], fb[j], acc[i][j], 0, 0, 0);
                if constexpr (NS == 3) {
                    acc[i][j] = __builtin_amdgcn_mfma_f32_16x16x32_bf16(fa[i], fbl[j], acc[i][j], 0, 0, 0);
                    acc[i][j] = __builtin_amdgcn_mfma_f32_16x16x32_bf16(fal[i], fb[j], acc[i][j], 0, 0, 0);
                }
            }
        if (more) { __syncthreads(); lstore(); __syncthreads(); }
    }
    __syncthreads();

    // ---- epilogue: acc -> swizzled LDS fp32 -> row-major per-thread ----
    float* EP = (float*)smem;
    #pragma unroll
    for (int i = 0; i < 4; ++i)
        #pragma unroll
        for (int j = 0; j < 2; ++j)
            #pragma unroll
            for (int v = 0; v < 4; ++v) {
                int row = mh * 64 + i * 16 + lq * 4 + v;
                int col = nh * 32 + j * 16 + lr16;
                int u = col >> 2, up = u ^ (row & 15);
                EP[row * 64 + up * 4 + (col & 3)] = acc[i][j][v];
            }
    __syncthreads();
    int r = tid >> 1, hh2 = tid & 1;
    float vv[32];
    #pragma unroll
    for (int uu = 0; uu < 8; ++uu) {
        int u = hh2 * 8 + uu;
        *(float4*)&vv[uu * 4] = *(const float4*)&EP[r * 64 + ((u ^ (r & 15)) * 4)];
    }
    int m = m0 + r, nb = n0 + hh2 * 32;
    size_t idx = (size_t)m * Nd + nb;

    if constexpr (SPLITK) {
        #pragma unroll
        for (int uu = 0; uu < 8; ++uu) *(float4*)(C + idx + uu * 4) = *(float4*)&vv[uu * 4];
        return;
    }
    if (bias) {
        #pragma unroll
        for (int uu = 0; uu < 8; ++uu) {
            float4 b4 = *(const float4*)(bias + nb + uu * 4);
            vv[uu * 4 + 0] += b4.x; vv[uu * 4 + 1] += b4.y;
            vv[uu * 4 + 2] += b4.z; vv[uu * 4 + 3] += b4.w;
        }
    }
    unsigned short eh8[32], el8[32];
    if constexpr (EPI == 2 || EPI == 3 || EPI == 6) {
        #pragma unroll
        for (int k4 = 0; k4 < 4; ++k4) {
            *(short8*)&eh8[k4 * 8] = *(const short8*)(exh + idx + k4 * 8);
            *(short8*)&el8[k4 * 8] = *(const short8*)(exl + idx + k4 * 8);
        }
    }
    auto store_hl = [&](const float* s) {
        unsigned short hb[32], lb2[32];
        #pragma unroll
        for (int e = 0; e < 32; ++e) { hb[e] = f2bf(s[e]); lb2[e] = f2bf(s[e] - bf2f(hb[e])); }
        #pragma unroll
        for (int k4 = 0; k4 < 4; ++k4) {
            *(short8*)(oh + idx + k4 * 8) = *(short8*)&hb[k4 * 8];
            *(short8*)(ol + idx + k4 * 8) = *(short8*)&lb2[k4 * 8];
        }
    };
    if constexpr (EPI == 0) {
        if (accum) {
            #pragma unroll
            for (int uu = 0; uu < 8; ++uu) {
                float4 o4 = *(const float4*)(C + idx + uu * 4);
                vv[uu * 4 + 0] += o4.x; vv[uu * 4 + 1] += o4.y;
                vv[uu * 4 + 2] += o4.z; vv[uu * 4 + 3] += o4.w;
            }
        }
        #pragma unroll
        for (int uu = 0; uu < 8; ++uu) *(float4*)(C + idx + uu * 4) = *(float4*)&vv[uu * 4];
    } else if constexpr (EPI == 1) {
        float s[32];
        #pragma unroll
        for (int e = 0; e < 32; ++e) s[e] = siluf(vv[e]);
        store_hl(s);
    } else if constexpr (EPI == 2) {
        float s[32];
        #pragma unroll
        for (int e = 0; e < 32; ++e) s[e] = bf2f(eh8[e]) + bf2f(el8[e]) + siluf(vv[e]);
        store_hl(s);
    } else if constexpr (EPI == 3) {
        float sc = (2.0f / 512.0f) * lrp[m];
        float s[32];
        #pragma unroll
        for (int e = 0; e < 32; ++e) s[e] = sc * (vv[e] - (bf2f(eh8[e]) + bf2f(el8[e])));
        store_hl(s);
    } else if constexpr (EPI == 4) {
        if (accum) {
            #pragma unroll
            for (int uu = 0; uu < 8; ++uu) {
                float4 o4 = *(const float4*)(C + idx + uu * 4);
                vv[uu * 4 + 0] += o4.x; vv[uu * 4 + 1] += o4.y;
                vv[uu * 4 + 2] += o4.z; vv[uu * 4 + 3] += o4.w;
            }
        }
        #pragma unroll
        for (int uu = 0; uu < 8; ++uu) *(float4*)(C + idx + uu * 4) = *(float4*)&vv[uu * 4];
        float s[32];
        #pragma unroll
        for (int e = 0; e < 32; ++e) s[e] = vv[e] * dsiluf(exf[idx + e]);
        store_hl(s);
    } else if constexpr (EPI == 5) {
        #pragma unroll
        for (int uu = 0; uu < 8; ++uu) *(float4*)(C + idx + uu * 4) = *(float4*)&vv[uu * 4];
        float s[32];
        #pragma unroll
        for (int e = 0; e < 32; ++e) s[e] = siluf(vv[e]);
        store_hl(s);
    } else if constexpr (EPI == 6) {
        #pragma unroll
        for (int uu = 0; uu < 8; ++uu) *(float4*)(C + idx + uu * 4) = *(float4*)&vv[uu * 4];
        float s[32];
        #pragma unroll
        for (int e = 0; e < 32; ++e) s[e] = bf2f(eh8[e]) + bf2f(el8[e]) + siluf(vv[e]);
        store_hl(s);
    } else if constexpr (EPI == 7) {
        int b2 = m / Nn, t2 = m - b2 * Nn;
        if (t2 >= Mm) {
            float* dst = C + (size_t)(b2 * Ss + (t2 - Mm)) * Nd + nb;
            #pragma unroll
            for (int uu = 0; uu < 8; ++uu) *(float4*)(dst + uu * 4) = *(float4*)&vv[uu * 4];
        }
    }
}

__global__ void k_reduce_splitk(const float* __restrict__ part, float* __restrict__ out,
                                int n, int z, float alpha) {
    int i = blockIdx.x * 256 + threadIdx.x;
    if (i >= n) return;
    float s = 0.f;
    for (int zz = 0; zz < z; ++zz) s += part[(size_t)zz * n + i];
    out[i] = alpha * s;
}

// ---- causal depthwise conv K=4 + SiLU (+L2n for q,k); fp32 in, hi/lo out --
__global__ __launch_bounds__(256) void k_conv3(
        const float* __restrict__ yq, const float* __restrict__ yk, const float* __restrict__ yv,
        const float* __restrict__ cq, const float* __restrict__ ck, const float* __restrict__ cv,
        unsigned short* oqh, unsigned short* oql, unsigned short* okh, unsigned short* okl,
        unsigned short* ovh, unsigned short* ovl) {
    int which = blockIdx.y;
    const float* y  = which == 0 ? yq : which == 1 ? yk : yv;
    const float* cw = which == 0 ? cq : which == 1 ? ck : cv;
    unsigned short* oh = which == 0 ? oqh : which == 1 ? okh : ovh;
    unsigned short* ol = which == 0 ? oql : which == 1 ? okl : ovl;
    bool norm = which < 2;
    int r = blockIdx.x;
    int b = r / Nn, t = r - b * Nn;
    const size_t rowbase = (size_t)r * Dd;
    float s[2];
    #pragma unroll
    for (int u = 0; u < 2; ++u) {
        int d = threadIdx.x + u * 256;
        float acc = 0.f;
        #pragma unroll
        for (int k = 0; k < 4; ++k) {
            int tt = t - 3 + k;
            if (tt >= 0) acc += y[(size_t)(b * Nn + tt) * Dd + d] * cw[d * 4 + k];
        }
        s[u] = siluf(acc);
    }
    float denom = 1.0f;
    if (norm) {
        __shared__ float red[256];
        red[threadIdx.x] = s[0] * s[0] + s[1] * s[1];
        __syncthreads();
        for (int off = 128; off; off >>= 1) {
            if (threadIdx.x < off) red[threadIdx.x] += red[threadIdx.x + off];
            __syncthreads();
        }
        denom = fmaxf(sqrtf(red[0]), 1e-12f);
    }
    #pragma unroll
    for (int u = 0; u < 2; ++u) {
        float v = s[u] / denom;
        unsigned short h = f2bf(v);
        oh[rowbase + threadIdx.x + u * 256] = h;
        ol[rowbase + threadIdx.x + u * 256] = f2bf(v - bf2f(h));
    }
}

// ---- column sums for bias grads (hi/lo input) -----------------------------
__global__ void k_colsum(const unsigned short* __restrict__ gh, const unsigned short* __restrict__ gl,
                         float* __restrict__ part) {
    int col = blockIdx.x * 256 + threadIdx.x;
    int chunk = blockIdx.y;
    int r0 = chunk * (Rr / 64);
    float s = 0.f;
    for (int r = r0; r < r0 + Rr / 64; ++r) {
        size_t o = (size_t)r * Dd + col;
        s += bf2f(gh[o]) + bf2f(gl[o]);
    }
    part[chunk * Dd + col] = s;
}
__global__ void k_colsum_reduce(const float* __restrict__ part, float* __restrict__ out, float alpha) {
    int col = blockIdx.x * 256 + threadIdx.x;
    if (col >= Dd) return;
    float s = 0.f;
    for (int c = 0; c < 64; ++c) s += part[c * Dd + col];
    out[col] = alpha * s;
}

// ---- parameter updates ----------------------------------------------------
struct UpdW4 { const float* p[4]; const float* mo[4]; const float* g[4];
               unsigned short* th[4]; unsigned short* tl[4]; };
__global__ void k_updW(UpdW4 u, const float* __restrict__ scal) {
    int seg = blockIdx.y;
    int i0 = blockIdx.x * 1024 + threadIdx.x * 4;
    float4 p4 = *(const float4*)(u.p[seg] + i0);
    float4 m4 = *(const float4*)(u.mo[seg] + i0);
    float4 g4 = *(const float4*)(u.g[seg] + i0);
    float a = 1.0f - scal[0], et = scal[2], th = scal[1];
    float vals[4] = { p4.x * a + et * m4.x - th * g4.x, p4.y * a + et * m4.y - th * g4.y,
                      p4.z * a + et * m4.z - th * g4.z, p4.w * a + et * m4.w - th * g4.w };
    int r = i0 >> 9, c = i0 & 511;
    #pragma unroll
    for (int e = 0; e < 4; ++e) {
        unsigned short h = f2bf(vals[e]);
        u.th[seg][(size_t)(c + e) * 512 + r] = h;
        u.tl[seg][(size_t)(c + e) * 512 + r] = f2bf(vals[e] - bf2f(h));
    }
}
struct UpdB4 { const float* p[4]; const float* mo[4]; const float* g[4]; float* o[4]; };
__global__ void k_updB(UpdB4 u, const float* __restrict__ scal) {
    int seg = blockIdx.x >> 1;
    int i = (blockIdx.x & 1) * 256 + threadIdx.x;
    u.o[seg][i] = u.p[seg][i] * (1.0f - scal[0]) + scal[2] * u.mo[seg][i] - scal[1] * u.g[seg][i];
}

// ---- flash-tiled sliding-window attention (fp32, unchanged from R2) -------
__global__ __launch_bounds__(256) void k_swa(const float* __restrict__ qs,
                                             const float* __restrict__ ks,
                                             const float* __restrict__ vs,
                                             float* __restrict__ out) {
    __shared__ float Ks[32][64];
    __shared__ float Vs[32][64];
    const int tid = threadIdx.x;
    const int q0 = blockIdx.x * 64;
    const int bh = blockIdx.y;
    const int h = bh & 7, b = bh >> 3;
    const int ql = tid >> 2, g = tid & 3;
    const int i = q0 + ql;
    const size_t srow = (size_t)(b * Nn) * Dd + h * HD;

    float qreg[16], o[16];
    #pragma unroll
    for (int d4 = 0; d4 < 4; ++d4)
        *(float4*)&qreg[d4 * 4] = *(const float4*)(qs + srow + (size_t)i * Dd + g * 16 + d4 * 4);
    #pragma unroll
    for (int d = 0; d < 16; ++d) o[d] = 0.f;
    float mrun = -1e30f, lrun = 0.f;

    int wstart = q0 - (WINw - 1);
    int jt0 = wstart <= 0 ? 0 : (wstart & ~31);
    for (int jt = jt0; jt <= q0 + 63; jt += 32) {
        __syncthreads();
        #pragma unroll
        for (int u = 0; u < 2; ++u) {
            int idx = tid + u * 256;
            int row = idx >> 4, c4 = (idx & 15) * 4;
            *(float4*)&Ks[row][c4] = *(const float4*)(ks + srow + (size_t)(jt + row) * Dd + c4);
            *(float4*)&Vs[row][c4] = *(const float4*)(vs + srow + (size_t)(jt + row) * Dd + c4);
        }
        __syncthreads();

        float sreg[32];
        #pragma unroll
        for (int j = 0; j < 32; ++j) {
            float p = 0.f;
            #pragma unroll
            for (int d4 = 0; d4 < 4; ++d4) {
                float4 kv = *(const float4*)&Ks[j][g * 16 + d4 * 4];
                p += qreg[d4 * 4 + 0] * kv.x + qreg[d4 * 4 + 1] * kv.y
                   + qreg[d4 * 4 + 2] * kv.z + qreg[d4 * 4 + 3] * kv.w;
            }
            p += __shfl_xor(p, 1);
            p += __shfl_xor(p, 2);
            int jg = jt + j;
            bool ok = (jg <= i) && (i - jg < WINw);
            sreg[j] = ok ? p * 0.125f : -1e30f;
        }
        float mt = -1e30f;
        #pragma unroll
        for (int j = 0; j < 32; ++j) mt = fmaxf(mt, sreg[j]);
        float mnew = fmaxf(mrun, mt);
        float corr = __expf(mrun - mnew);
        lrun *= corr;
        #pragma unroll
        for (int d = 0; d < 16; ++d) o[d] *= corr;
        #pragma unroll
        for (int j = 0; j < 32; ++j) {
            float pj = (sreg[j] > -1e29f) ? __expf(sreg[j] - mnew) : 0.f;
            lrun += pj;
            #pragma unroll
            for (int d4 = 0; d4 < 4; ++d4) {
                float4 vvv = *(const float4*)&Vs[j][g * 16 + d4 * 4];
                o[d4 * 4 + 0] += pj * vvv.x; o[d4 * 4 + 1] += pj * vvv.y;
                o[d4 * 4 + 2] += pj * vvv.z; o[d4 * 4 + 3] += pj * vvv.w;
            }
        }
        mrun = mnew;
    }
    float invl = 1.0f / lrun;
    #pragma unroll
    for (int d4 = 0; d4 < 4; ++d4) {
        float4 v;
        v.x = o[d4 * 4 + 0] * invl; v.y = o[d4 * 4 + 1] * invl;
        v.z = o[d4 * 4 + 2] * invl; v.w = o[d4 * 4 + 3] * invl;
        *(float4*)(out + srow + (size_t)i * Dd + g * 16 + d4 * 4) = v;
    }
}

} // namespace

extern "C" void kernel_launch(void* const* d_in, const int* in_sizes, int n_in,
                              void* d_out, int out_size, void* d_ws, size_t ws_size,
                              hipStream_t stream) {
    const float* x       = (const float*)d_in[0];
    const float* meta    = (const float*)d_in[1];
    const float* mWin    = (const float*)d_in[2];
    const float* mbin    = (const float*)d_in[3];
    const float* mWh     = (const float*)d_in[4];
    const float* mbh     = (const float*)d_in[5];
    const float* mWout   = (const float*)d_in[6];
    const float* mbout   = (const float*)d_in[7];
    const float* momWin  = (const float*)d_in[8];
    const float* mombin  = (const float*)d_in[9];
    const float* momWh   = (const float*)d_in[10];
    const float* mombh   = (const float*)d_in[11];
    const float* momWout = (const float*)d_in[12];
    const float* mombout = (const float*)d_in[13];
    const float* q_w = (const float*)d_in[14]; const float* q_b = (const float*)d_in[15]; const float* q_c = (const float*)d_in[16];
    const float* k_w = (const float*)d_in[17]; const float* k_b = (const float*)d_in[18]; const float* k_c = (const float*)d_in[19];
    const float* v_w = (const float*)d_in[20]; const float* v_b = (const float*)d_in[21]; const float* v_c = (const float*)d_in[22];
    const float* lr_w = (const float*)d_in[23]; const float* lr_b = (const float*)d_in[24];
    const float* fg_w = (const float*)d_in[25]; const float* fg_b = (const float*)d_in[26];
    const float* mo_w = (const float*)d_in[27]; const float* mo_b = (const float*)d_in[28];
    const float* swa_wq = (const float*)d_in[29]; const float* swa_wk = (const float*)d_in[30];
    const float* swa_wv = (const float*)d_in[31]; const float* swa_wo = (const float*)d_in[32];
    const float* swa_bq = (const float*)d_in[33]; const float* swa_bk = (const float*)d_in[34];
    const float* swa_bv = (const float*)d_in[35]; const float* swa_bo = (const float*)d_in[36];
    (void)in_sizes; (void)n_in; (void)out_size; (void)ws_size;

    char* wsb = (char*)d_ws;
    size_t off = 0;
    auto allocB = [&](size_t bytes) { void* p = wsb + off; off = (off + bytes + 255) & ~(size_t)255; return p; };
    auto allocU = [&](size_t elems) { return (unsigned short*)allocB(elems * 2); };
    auto allocF = [&](size_t elems) { return (float*)allocB(elems * 4); };

    unsigned short *xm_h = allocU(NBD), *xm_l = allocU(NBD);     // reused as gB
    unsigned short *qb_h = allocU(NBD), *qb_l = allocU(NBD);
    unsigned short *kb_h = allocU(NBD), *kb_l = allocU(NBD);
    unsigned short *vb_h = allocU(NBD), *vb_l = allocU(NBD);     // reused as gA
    unsigned short *h0_h = allocU(NBD), *h0_l = allocU(NBD);
    unsigned short *h1_h = allocU(NBD), *h1_l = allocU(NBD);
    unsigned short *h2_h = allocU(NBD), *h2_l = allocU(NBD);
    unsigned short *g1_h = allocU(NBD), *g1_l = allocU(NBD);
    float *f0 = allocF(NBD), *f1 = allocF(NBD), *f2 = allocF(NBD), *f3 = allocF(NBD);
    float *parts = allocF((size_t)12 * 262144);
    const int WEL = 262144;
    unsigned short *wt_h[11], *wt_l[11], *wn_h[11];
    for (int i = 0; i < 11; ++i) { wt_h[i] = allocU(WEL); wt_l[i] = allocU(WEL); wn_h[i] = nullptr; }
    for (int i = 8; i < 11; ++i) wn_h[i] = allocU(WEL);          // natural hi: mWh0, mWh1, mWout
    unsigned short *nWinT_h = allocU(WEL), *nWinT_l = allocU(WEL);
    unsigned short *nWh0T_h = allocU(WEL), *nWh0T_l = allocU(WEL);
    unsigned short *nWh1T_h = allocU(WEL), *nWh1T_l = allocU(WEL);
    unsigned short *nWoutT_h = allocU(WEL), *nWoutT_l = allocU(WEL);
    float *gWin = allocF(WEL), *gWh0 = allocF(WEL), *gWh1 = allocF(WEL), *gWout = allocF(WEL);
    float *gbin = allocF(512), *gbh0 = allocF(512), *gbh1 = allocF(512), *gbout = allocF(512);
    float *nbin = allocF(512), *nbh0 = allocF(512), *nbh1 = allocF(512), *nbout = allocF(512);
    float *lr_t = allocF(Rr), *fg_t = allocF(Rr), *mo_t = allocF(Rr);
    float *scal = allocF(8);
    float *cpart = allocF(64 * 512);
    unsigned short *gA_h = vb_h, *gA_l = vb_l;
    unsigned short *gB_h = xm_h, *gB_l = xm_l;

    TriSet none{};
    const dim3 GG(33, 8);

    // ---- weight conversion (transposed hi/lo; natural hi for bwd) ----
    WC wc{};
    const float* wlist[11] = { q_w, k_w, v_w, swa_wq, swa_wk, swa_wv, swa_wo,
                               mWin, mWh, mWh + WEL, mWout };
    for (int i = 0; i < 11; ++i) { wc.w[i] = wlist[i]; wc.th[i] = wt_h[i]; wc.tl[i] = wt_l[i]; wc.nh[i] = wn_h[i]; }
    k_wconv<<<dim3(256, 11), 256, 0, stream>>>(wc);

    // ---- Phase A ----
    k_build_xm<<<(Rr * 128 + 255) / 256, 256, 0, stream>>>(x, meta, xm_h, xm_l);
    k_gates<<<Rr / 4, 256, 0, stream>>>(xm_h, xm_l, lr_w, lr_b, fg_w, fg_b, mo_w, mo_b, lr_t, fg_t, mo_t);
    k_gate_means<<<1, 256, 0, stream>>>(lr_t, fg_t, mo_t, scal);

    TriSet qkvA{{ { wt_h[0], wt_l[0], q_b, f0 }, { wt_h[1], wt_l[1], k_b, f1 }, { wt_h[2], wt_l[2], v_b, f2 } }};
    k_mm<0, 0, false, 0, true, 3, false><<<dim3(33, 8, 3), 256, 0, stream>>>(
        xm_h, xm_l, nullptr, nullptr, nullptr, nullptr, nullptr, nullptr, nullptr, nullptr,
        nullptr, nullptr, qkvA, Rr, Dd, Dd, 0);
    k_conv3<<<dim3(Rr, 3), 256, 0, stream>>>(f0, f1, f2, q_c, k_c, v_c,
                                             qb_h, qb_l, kb_h, kb_l, vb_h, vb_l);

    // ---- Phase B: memory-MLP forward (plain bf16; theta-damped path) ----
    k_mm<0, 0, false, 5, false, 1, false><<<GG, 256, 0, stream>>>(
        kb_h, nullptr, wt_h[7], nullptr, f0, mbin, nullptr, nullptr, nullptr, nullptr,
        h0_h, h0_l, none, Rr, Dd, Dd, 0);                               // z0=f0, h0
    k_mm<0, 0, false, 6, false, 1, false><<<GG, 256, 0, stream>>>(
        h0_h, nullptr, wt_h[8], nullptr, f1, mbh, nullptr, h0_h, h0_l, nullptr,
        h1_h, h1_l, none, Rr, Dd, Dd, 0);                               // a0=f1, h1
    k_mm<0, 0, false, 6, false, 1, false><<<GG, 256, 0, stream>>>(
        h1_h, nullptr, wt_h[9], nullptr, f2, mbh + 512, nullptr, h1_h, h1_l, nullptr,
        h2_h, h2_l, none, Rr, Dd, Dd, 0);                               // a1=f2, h2
    k_mm<0, 0, false, 3, false, 1, false><<<GG, 256, 0, stream>>>(
        h2_h, nullptr, wt_h[10], nullptr, nullptr, mbout, nullptr, vb_h, vb_l, lr_t,
        g1_h, g1_l, none, Rr, Dd, Dd, 0);                               // g1 = dpred

    // ---- Phase C: backward ----
    auto GRADW = [&](const unsigned short* ah, const unsigned short* bh, float* gout) {
        k_mm<1, 1, true, 0, false, 1, false><<<dim3(4, 8, 12), 256, 0, stream>>>(
            ah, nullptr, bh, nullptr, parts, nullptr, nullptr, nullptr, nullptr, nullptr,
            nullptr, nullptr, none, Dd, Dd, Rr, 0);
        k_reduce_splitk<<<1024, 256, 0, stream>>>(parts, gout, WEL, 12, 1.0f / NCc);
    };
    auto COLSUM = [&](const unsigned short* gh, const unsigned short* gl, float* bo) {
        k_colsum<<<dim3(2, 64), 256, 0, stream>>>(gh, gl, cpart);
        k_colsum_reduce<<<2, 256, 0, stream>>>(cpart, bo, 1.0f / NCc);
    };
    GRADW(h2_h, g1_h, gWout);  COLSUM(g1_h, g1_l, gbout);
    k_mm<0, 0, false, 4, false, 1, false><<<GG, 256, 0, stream>>>(
        g1_h, nullptr, wn_h[10], nullptr, f3, nullptr, f2, nullptr, nullptr, nullptr,
        gA_h, gA_l, none, Rr, Dd, Dd, 0);                               // f3=dh2, gA=da1
    GRADW(h1_h, gA_h, gWh1);   COLSUM(gA_h, gA_l, gbh1);
    k_mm<0, 0, false, 4, false, 1, false><<<GG, 256, 0, stream>>>(
        gA_h, nullptr, wn_h[9], nullptr, f3, nullptr, f1, nullptr, nullptr, nullptr,
        gB_h, gB_l, none, Rr, Dd, Dd, 1);                               // f3=dh1, gB=da0
    GRADW(h0_h, gB_h, gWh0);   COLSUM(gB_h, gB_l, gbh0);
    k_mm<0, 0, false, 4, false, 1, false><<<GG, 256, 0, stream>>>(
        gB_h, nullptr, wn_h[8], nullptr, f3, nullptr, f0, nullptr, nullptr, nullptr,
        gA_h, gA_l, none, Rr, Dd, Dd, 1);                               // gA=dz0
    GRADW(kb_h, gA_h, gWin);   COLSUM(gA_h, gA_l, gbin);

    // ---- Phase D: updates ----
    UpdW4 uw{ { mWin, mWh, mWh + WEL, mWout },
              { momWin, momWh, momWh + WEL, momWout },
              { gWin, gWh0, gWh1, gWout },
              { nWinT_h, nWh0T_h, nWh1T_h, nWoutT_h },
              { nWinT_l, nWh0T_l, nWh1T_l, nWoutT_l } };
    k_updW<<<dim3(256, 4), 256, 0, stream>>>(uw, scal);
    UpdB4 ub{ { mbin, mbh, mbh + 512, mbout },
              { mombin, mombh, mombh + 512, mombout },
              { gbin, gbh0, gbh1, gbout },
              { nbin, nbh0, nbh1, nbout } };
    k_updB<<<8, 256, 0, stream>>>(ub, scal);

    // ---- Phase E: retrieval MLP on q (bf16x2 split) ----
    k_mm<0, 0, false, 1, false, 3, false><<<GG, 256, 0, stream>>>(
        qb_h, qb_l, nWinT_h, nWinT_l, nullptr, nbin, nullptr, nullptr, nullptr, nullptr,
        g1_h, g1_l, none, Rr, Dd, Dd, 0);                               // e0 -> g1
    k_mm<0, 0, false, 2, false, 3, false><<<GG, 256, 0, stream>>>(
        g1_h, g1_l, nWh0T_h, nWh0T_l, nullptr, nbh0, nullptr, g1_h, g1_l, nullptr,
        h0_h, h0_l, none, Rr, Dd, Dd, 0);                               // e1 -> h0
    k_mm<0, 0, false, 2, false, 3, false><<<GG, 256, 0, stream>>>(
        h0_h, h0_l, nWh1T_h, nWh1T_l, nullptr, nbh1, nullptr, h0_h, h0_l, nullptr,
        h1_h, h1_l, none, Rr, Dd, Dd, 0);                               // e2 -> h1
    k_mm<0, 0, false, 1, false, 3, false><<<GG, 256, 0, stream>>>(
        h1_h, h1_l, nWoutT_h, nWoutT_l, nullptr, nbout, nullptr, nullptr, nullptr, nullptr,
        h2_h, h2_l, none, Rr, Dd, Dd, 0);                               // retrieved -> h2

    // ---- Phase F: SWA qkv (fp32 out), attention, fused out-proj+slice ----
    TriSet qkvF{{ { wt_h[3], wt_l[3], swa_bq, f0 }, { wt_h[4], wt_l[4], swa_bk, f1 },
                  { wt_h[5], wt_l[5], swa_bv, f2 } }};
    k_mm<0, 0, false, 0, true, 3, false><<<dim3(33, 8, 3), 256, 0, stream>>>(
        h2_h, h2_l, nullptr, nullptr, nullptr, nullptr, nullptr, nullptr, nullptr, nullptr,
        nullptr, nullptr, qkvF, Rr, Dd, Dd, 0);
    k_swa<<<dim3(Nn / 64, Bb * NHh), 256, 0, stream>>>(f0, f1, f2, f3);
    k_mm<0, 0, false, 7, false, 3, true><<<GG, 256, 0, stream>>>(
        f3, nullptr, wt_h[6], wt_l[6], (float*)d_out, swa_bo, nullptr, nullptr, nullptr, nullptr,
        nullptr, nullptr, none, Rr, Dd, Dd, 0);
}

// Round 4
// 861.570 us; speedup vs baseline: 3.1868x; 1.1815x over previous
//
#include <hip/hip_runtime.h>
#include <cmath>

// ---------------------------------------------------------------------------
// NeuralMemory R4: 64x64-tile BK=64 MFMA GEMM (2+ blocks/CU), wave-autonomous
// key-split flash SWA (no LDS, no barriers) + merge pass.
// ---------------------------------------------------------------------------

namespace {

constexpr int Bb   = 2;
constexpr int Ss   = 2048;
constexpr int Dd   = 512;
constexpr int Mm   = 64;
constexpr int NCc  = 16;
constexpr int NHh  = 8;
constexpr int HD   = 64;
constexpr int WINw = 256;
constexpr int Nn   = Mm + Ss;    // 2112
constexpr int Rr   = Bb * Nn;    // 4224
constexpr int NBD  = Rr * Dd;
constexpr float MAXLR = 0.1f;

typedef __attribute__((ext_vector_type(8))) short short8;
typedef __attribute__((ext_vector_type(4))) float f32x4;

__device__ __forceinline__ float sigf(float x)  { return 1.0f / (1.0f + __expf(-x)); }
__device__ __forceinline__ float siluf(float x) { return x * sigf(x); }
__device__ __forceinline__ float dsiluf(float x){ float s = sigf(x); return s * (1.0f + x * (1.0f - s)); }
__device__ __forceinline__ unsigned short f2bf(float f) {
    unsigned int u = __float_as_uint(f);
    u = (u + 0x7FFFu + ((u >> 16) & 1u)) >> 16;
    return (unsigned short)u;
}
__device__ __forceinline__ float bf2f(unsigned short h) {
    return __uint_as_float(((unsigned int)h) << 16);
}

// ---- build xm (hi/lo bf16) ------------------------------------------------
__global__ void k_build_xm(const float* __restrict__ x, const float* __restrict__ meta,
                           unsigned short* __restrict__ xh, unsigned short* __restrict__ xl) {
    int i = blockIdx.x * 256 + threadIdx.x;      // float4 units
    if (i >= Rr * 128) return;
    int c = i & 127, r = i >> 7;
    int b = r / Nn, t = r - b * Nn;
    float4 v = (t < Mm) ? ((const float4*)meta)[t * 128 + c]
                        : ((const float4*)x)[(size_t)(b * Ss + (t - Mm)) * 128 + c];
    float vv[4] = { v.x, v.y, v.z, v.w };
    unsigned short h[4], l[4];
    #pragma unroll
    for (int e = 0; e < 4; ++e) { h[e] = f2bf(vv[e]); l[e] = f2bf(vv[e] - bf2f(h[e])); }
    *(ushort4*)(xh + (size_t)i * 4) = *(ushort4*)h;
    *(ushort4*)(xl + (size_t)i * 4) = *(ushort4*)l;
}

// ---- per-row scalar gates -------------------------------------------------
__global__ void k_gates(const unsigned short* __restrict__ xh, const unsigned short* __restrict__ xl,
                        const float* __restrict__ lw, const float* __restrict__ lb,
                        const float* __restrict__ fw, const float* __restrict__ fb,
                        const float* __restrict__ mw, const float* __restrict__ mb,
                        float* __restrict__ lr_t, float* __restrict__ fg_t, float* __restrict__ mo_t) {
    int r = blockIdx.x * 4 + (threadIdx.x >> 6);
    int lane = threadIdx.x & 63;
    if (r >= Rr) return;
    float s0 = 0.f, s1 = 0.f, s2 = 0.f;
    for (int j = lane; j < Dd; j += 64) {
        size_t o = (size_t)r * Dd + j;
        float v = bf2f(xh[o]) + bf2f(xl[o]);
        s0 += v * lw[j]; s1 += v * fw[j]; s2 += v * mw[j];
    }
    #pragma unroll
    for (int off = 32; off; off >>= 1) {
        s0 += __shfl_down(s0, off, 64);
        s1 += __shfl_down(s1, off, 64);
        s2 += __shfl_down(s2, off, 64);
    }
    if (lane == 0) {
        lr_t[r] = MAXLR * sigf(s0 + lb[0]);
        fg_t[r] = sigf(s1 + fb[0]);
        mo_t[r] = sigf(s2 + mb[0]);
    }
}

__global__ void k_gate_means(const float* __restrict__ lr_t, const float* __restrict__ fg_t,
                             const float* __restrict__ mo_t, float* __restrict__ scal) {
    __shared__ float red[256];
    const float* ptrs[3] = { fg_t, lr_t, mo_t };
    for (int w = 0; w < 3; ++w) {
        float acc = 0.f;
        for (int i = threadIdx.x; i < Rr; i += 256) acc += ptrs[w][i];
        red[threadIdx.x] = acc; __syncthreads();
        for (int off = 128; off; off >>= 1) {
            if (threadIdx.x < off) red[threadIdx.x] += red[threadIdx.x + off];
            __syncthreads();
        }
        if (threadIdx.x == 0) scal[w] = red[0] / (float)Rr;
        __syncthreads();
    }
}

// ---- weight convert: fp32 W[r][c] -> WT hi/lo [c][r]; optional natural hi --
struct WC { const float* w[11]; unsigned short* th[11]; unsigned short* tl[11]; unsigned short* nh[11]; };
__global__ void k_wconv(WC wc) {
    int seg = blockIdx.y;
    int i0 = blockIdx.x * 1024 + threadIdx.x * 4;
    float4 v4 = *(const float4*)(wc.w[seg] + i0);
    float vals[4] = { v4.x, v4.y, v4.z, v4.w };
    int r = i0 >> 9, c = i0 & 511;
    #pragma unroll
    for (int e = 0; e < 4; ++e) {
        unsigned short h = f2bf(vals[e]);
        unsigned short l = f2bf(vals[e] - bf2f(h));
        wc.th[seg][(size_t)(c + e) * 512 + r] = h;
        wc.tl[seg][(size_t)(c + e) * 512 + r] = l;
        if (wc.nh[seg]) wc.nh[seg][i0 + e] = h;
    }
}

// ---- MFMA GEMM: 64x64 tile, BK=64, 256 thr (4 waves, each 32x32) ----------
// TA=0: A row-major (M,K); TA=1: A stored [k][m] (A^T B, GRADW).
// TB=0: B in [n][k] layout; TB=1: B row-major [k][n] (GRADW).
// NS=3: bf16x2 split; NS=1 plain hi. AF32: A fp32, split on the fly.
// EPI: 0 fp32(+bias,+accum) | 1 silu->hl | 2 extraHL+silu->hl | 3 dpred->hl
//      4 accum fp32 + *dsilu(exf)->hl | 5 fp32 + silu->hl | 6 fp32 + ex+silu->hl
//      7 bias+slice fp32 -> d_out
struct TriW { const unsigned short* bh; const unsigned short* bl; const float* bias; float* c; };
struct TriSet { TriW t[3]; };

template<int TA, int TB, bool SPLITK, int EPI, bool MULTI, int NS, bool AF32>
__global__ __launch_bounds__(256) void k_mm(
        const void* Ap, const unsigned short* Al_,
        const unsigned short* Bh_, const unsigned short* Bl_,
        float* C, const float* bias, const float* __restrict__ exf,
        const unsigned short* __restrict__ exh, const unsigned short* __restrict__ exl,
        const float* __restrict__ lrp,
        unsigned short* oh, unsigned short* ol, TriSet ts,
        int Md, int Nd, int Kd, int accum) {
    constexpr int SMEMB = (NS == 3) ? 32768 : 16384;
    __shared__ char smem[SMEMB];
    unsigned short* AH = (unsigned short*)smem;
    unsigned short* AL = AH + 4096;
    unsigned short* BH = AH + ((NS == 3) ? 8192 : 4096);
    unsigned short* BL = BH + 4096;
    const int tid = threadIdx.x;
    const int m0 = blockIdx.x * 64, n0 = blockIdx.y * 64;
    if constexpr (MULTI) {
        const TriW& tw = ts.t[blockIdx.z];
        Bh_ = tw.bh; Bl_ = tw.bl; bias = tw.bias; C = tw.c;
    }
    int kbg = 0, ke = Kd;
    if constexpr (SPLITK) {
        int kc = Kd / gridDim.z;
        kbg = blockIdx.z * kc; ke = kbg + kc;
        C += (size_t)blockIdx.z * Md * Nd;
    }
    const int astr = (TA == 0) ? Kd : Md;

    f32x4 acc[2][2];
    #pragma unroll
    for (int i = 0; i < 2; ++i)
        #pragma unroll
        for (int j = 0; j < 2; ++j)
            #pragma unroll
            for (int v = 0; v < 4; ++v) acc[i][j][v] = 0.f;

    short8 pA0, pA1, pAl0, pAl1, pB0, pB1, pBl0, pBl1;
    float4 pAf[4];

    auto gload = [&](int k0) {
        if constexpr (TA == 0) {
            int r = tid >> 2, ks2 = (tid & 3) * 16;
            if constexpr (AF32) {
                const float* ap = (const float*)Ap + (size_t)(m0 + r) * astr + k0 + ks2;
                pAf[0] = *(const float4*)ap;       pAf[1] = *(const float4*)(ap + 4);
                pAf[2] = *(const float4*)(ap + 8); pAf[3] = *(const float4*)(ap + 12);
            } else {
                const unsigned short* ah = (const unsigned short*)Ap + (size_t)(m0 + r) * astr + k0 + ks2;
                pA0 = *(const short8*)ah; pA1 = *(const short8*)(ah + 8);
                if constexpr (NS == 3) {
                    const unsigned short* al = Al_ + (size_t)(m0 + r) * astr + k0 + ks2;
                    pAl0 = *(const short8*)al; pAl1 = *(const short8*)(al + 8);
                }
            }
        } else {
            int kr = tid >> 2, ms = (tid & 3) * 16;
            const unsigned short* ah = (const unsigned short*)Ap + (size_t)(k0 + kr) * astr + m0 + ms;
            pA0 = *(const short8*)ah; pA1 = *(const short8*)(ah + 8);
            if constexpr (NS == 3) {
                const unsigned short* al = Al_ + (size_t)(k0 + kr) * astr + m0 + ms;
                pAl0 = *(const short8*)al; pAl1 = *(const short8*)(al + 8);
            }
        }
        if constexpr (TB == 0) {
            int nr = tid >> 2, ks2 = (tid & 3) * 16;
            const unsigned short* bh = Bh_ + (size_t)(n0 + nr) * Kd + k0 + ks2;
            pB0 = *(const short8*)bh; pB1 = *(const short8*)(bh + 8);
            if constexpr (NS == 3) {
                const unsigned short* bl = Bl_ + (size_t)(n0 + nr) * Kd + k0 + ks2;
                pBl0 = *(const short8*)bl; pBl1 = *(const short8*)(bl + 8);
            }
        } else {
            int kr = tid >> 2, nseg = (tid & 3) * 16;
            const unsigned short* bh = Bh_ + (size_t)(k0 + kr) * Nd + n0 + nseg;
            pB0 = *(const short8*)bh; pB1 = *(const short8*)(bh + 8);
            if constexpr (NS == 3) {
                const unsigned short* bl = Bl_ + (size_t)(k0 + kr) * Nd + n0 + nseg;
                pBl0 = *(const short8*)bl; pBl1 = *(const short8*)(bl + 8);
            }
        }
    };
    auto lstore = [&]() {
        if constexpr (TA == 0) {
            int r = tid >> 2, ks2 = (tid & 3) * 16;
            int f = r >> 4, rr = r & 15, kf = ks2 >> 5, q = (ks2 >> 3) & 3;
            int base = (((f * 2 + kf) * 4 + q) * 16 + rr) * 8;
            if constexpr (AF32) {
                unsigned short hh[16], ll[16];
                const float* pf = (const float*)pAf;
                #pragma unroll
                for (int e = 0; e < 16; ++e) { hh[e] = f2bf(pf[e]); ll[e] = f2bf(pf[e] - bf2f(hh[e])); }
                *(short8*)(AH + base) = *(short8*)hh;  *(short8*)(AH + base + 128) = *(short8*)(hh + 8);
                *(short8*)(AL + base) = *(short8*)ll;  *(short8*)(AL + base + 128) = *(short8*)(ll + 8);
            } else {
                *(short8*)(AH + base) = pA0; *(short8*)(AH + base + 128) = pA1;
                if constexpr (NS == 3) { *(short8*)(AL + base) = pAl0; *(short8*)(AL + base + 128) = pAl1; }
            }
        } else {
            int kr = tid >> 2, ms = (tid & 3) * 16;
            int f = ms >> 4, kf = kr >> 5, q = (kr >> 3) & 3, kk = kr & 7;
            int base = (((f * 2 + kf) * 4 + q) * 16) * 8 + kk;
            unsigned short tmp[16];
            *(short8*)tmp = pA0; *(short8*)(tmp + 8) = pA1;
            #pragma unroll
            for (int e = 0; e < 16; ++e) AH[base + e * 8] = tmp[e];
            if constexpr (NS == 3) {
                *(short8*)tmp = pAl0; *(short8*)(tmp + 8) = pAl1;
                #pragma unroll
                for (int e = 0; e < 16; ++e) AL[base + e * 8] = tmp[e];
            }
        }
        if constexpr (TB == 0) {
            int nr = tid >> 2, ks2 = (tid & 3) * 16;
            int f = nr >> 4, rr = nr & 15, kf = ks2 >> 5, q = (ks2 >> 3) & 3;
            int base = (((f * 2 + kf) * 4 + q) * 16 + rr) * 8;
            *(short8*)(BH + base) = pB0; *(short8*)(BH + base + 128) = pB1;
            if constexpr (NS == 3) { *(short8*)(BL + base) = pBl0; *(short8*)(BL + base + 128) = pBl1; }
        } else {
            int kr = tid >> 2, nseg = (tid & 3) * 16;
            int f = nseg >> 4, kf = kr >> 5, q = (kr >> 3) & 3, kk = kr & 7;
            int base = (((f * 2 + kf) * 4 + q) * 16) * 8 + kk;
            unsigned short tmp[16];
            *(short8*)tmp = pB0; *(short8*)(tmp + 8) = pB1;
            #pragma unroll
            for (int e = 0; e < 16; ++e) BH[base + e * 8] = tmp[e];
            if constexpr (NS == 3) {
                *(short8*)tmp = pBl0; *(short8*)(tmp + 8) = pBl1;
                #pragma unroll
                for (int e = 0; e < 16; ++e) BL[base + e * 8] = tmp[e];
            }
        }
    };

    const int wv = tid >> 6, lr16 = tid & 15, lq = (tid >> 4) & 3;
    const int wm = wv & 1, wn = wv >> 1;

    gload(kbg); lstore();
    __syncthreads();
    for (int k0 = kbg; k0 < ke; k0 += 64) {
        bool more = (k0 + 64) < ke;
        if (more) gload(k0 + 64);
        #pragma unroll
        for (int kf = 0; kf < 2; ++kf) {
            short8 fa[2], fal[2], fb[2], fbl[2];
            #pragma unroll
            for (int i = 0; i < 2; ++i) {
                int off = ((((wm * 2 + i) * 2 + kf) * 4 + lq) * 16 + lr16) * 8;
                fa[i] = *(const short8*)(AH + off);
                if constexpr (NS == 3) fal[i] = *(const short8*)(AL + off);
            }
            #pragma unroll
            for (int j = 0; j < 2; ++j) {
                int off = ((((wn * 2 + j) * 2 + kf) * 4 + lq) * 16 + lr16) * 8;
                fb[j] = *(const short8*)(BH + off);
                if constexpr (NS == 3) fbl[j] = *(const short8*)(BL + off);
            }
            #pragma unroll
            for (int i = 0; i < 2; ++i)
                #pragma unroll
                for (int j = 0; j < 2; ++j) {
                    acc[i][j] = __builtin_amdgcn_mfma_f32_16x16x32_bf16(fa[i], fb[j], acc[i][j], 0, 0, 0);
                    if constexpr (NS == 3) {
                        acc[i][j] = __builtin_amdgcn_mfma_f32_16x16x32_bf16(fa[i], fbl[j], acc[i][j], 0, 0, 0);
                        acc[i][j] = __builtin_amdgcn_mfma_f32_16x16x32_bf16(fal[i], fb[j], acc[i][j], 0, 0, 0);
                    }
                }
        }
        if (more) { __syncthreads(); lstore(); __syncthreads(); }
    }
    __syncthreads();

    // ---- epilogue: acc -> swizzled LDS fp32 -> row-major per-thread ----
    float* EP = (float*)smem;
    #pragma unroll
    for (int i = 0; i < 2; ++i)
        #pragma unroll
        for (int j = 0; j < 2; ++j)
            #pragma unroll
            for (int v = 0; v < 4; ++v) {
                int row = wm * 32 + i * 16 + lq * 4 + v;
                int col = wn * 32 + j * 16 + lr16;
                int u = col >> 2, up = u ^ (row & 15);
                EP[row * 64 + up * 4 + (col & 3)] = acc[i][j][v];
            }
    __syncthreads();
    int r = tid >> 2, cg = tid & 3;
    float vv[16];
    #pragma unroll
    for (int uu = 0; uu < 4; ++uu) {
        int u = cg * 4 + uu;
        *(float4*)&vv[uu * 4] = *(const float4*)&EP[r * 64 + ((u ^ (r & 15)) * 4)];
    }
    int m = m0 + r, nb = n0 + cg * 16;
    size_t idx = (size_t)m * Nd + nb;

    if constexpr (SPLITK) {
        #pragma unroll
        for (int uu = 0; uu < 4; ++uu) *(float4*)(C + idx + uu * 4) = *(float4*)&vv[uu * 4];
        return;
    }
    if (bias) {
        #pragma unroll
        for (int uu = 0; uu < 4; ++uu) {
            float4 b4 = *(const float4*)(bias + nb + uu * 4);
            vv[uu * 4 + 0] += b4.x; vv[uu * 4 + 1] += b4.y;
            vv[uu * 4 + 2] += b4.z; vv[uu * 4 + 3] += b4.w;
        }
    }
    unsigned short eh8[16], el8[16];
    if constexpr (EPI == 2 || EPI == 3 || EPI == 6) {
        #pragma unroll
        for (int k4 = 0; k4 < 2; ++k4) {
            *(short8*)&eh8[k4 * 8] = *(const short8*)(exh + idx + k4 * 8);
            *(short8*)&el8[k4 * 8] = *(const short8*)(exl + idx + k4 * 8);
        }
    }
    auto store_hl = [&](const float* s) {
        unsigned short hb[16], lb2[16];
        #pragma unroll
        for (int e = 0; e < 16; ++e) { hb[e] = f2bf(s[e]); lb2[e] = f2bf(s[e] - bf2f(hb[e])); }
        #pragma unroll
        for (int k4 = 0; k4 < 2; ++k4) {
            *(short8*)(oh + idx + k4 * 8) = *(short8*)&hb[k4 * 8];
            *(short8*)(ol + idx + k4 * 8) = *(short8*)&lb2[k4 * 8];
        }
    };
    auto accum_add = [&]() {
        #pragma unroll
        for (int uu = 0; uu < 4; ++uu) {
            float4 o4 = *(const float4*)(C + idx + uu * 4);
            vv[uu * 4 + 0] += o4.x; vv[uu * 4 + 1] += o4.y;
            vv[uu * 4 + 2] += o4.z; vv[uu * 4 + 3] += o4.w;
        }
    };
    auto store_f = [&]() {
        #pragma unroll
        for (int uu = 0; uu < 4; ++uu) *(float4*)(C + idx + uu * 4) = *(float4*)&vv[uu * 4];
    };
    if constexpr (EPI == 0) {
        if (accum) accum_add();
        store_f();
    } else if constexpr (EPI == 1) {
        float s[16];
        #pragma unroll
        for (int e = 0; e < 16; ++e) s[e] = siluf(vv[e]);
        store_hl(s);
    } else if constexpr (EPI == 2) {
        float s[16];
        #pragma unroll
        for (int e = 0; e < 16; ++e) s[e] = bf2f(eh8[e]) + bf2f(el8[e]) + siluf(vv[e]);
        store_hl(s);
    } else if constexpr (EPI == 3) {
        float sc = (2.0f / 512.0f) * lrp[m];
        float s[16];
        #pragma unroll
        for (int e = 0; e < 16; ++e) s[e] = sc * (vv[e] - (bf2f(eh8[e]) + bf2f(el8[e])));
        store_hl(s);
    } else if constexpr (EPI == 4) {
        if (accum) accum_add();
        store_f();
        float s[16];
        #pragma unroll
        for (int e = 0; e < 16; ++e) s[e] = vv[e] * dsiluf(exf[idx + e]);
        store_hl(s);
    } else if constexpr (EPI == 5) {
        store_f();
        float s[16];
        #pragma unroll
        for (int e = 0; e < 16; ++e) s[e] = siluf(vv[e]);
        store_hl(s);
    } else if constexpr (EPI == 6) {
        store_f();
        float s[16];
        #pragma unroll
        for (int e = 0; e < 16; ++e) s[e] = bf2f(eh8[e]) + bf2f(el8[e]) + siluf(vv[e]);
        store_hl(s);
    } else if constexpr (EPI == 7) {
        int b2 = m / Nn, t2 = m - b2 * Nn;
        if (t2 >= Mm) {
            float* dst = C + (size_t)(b2 * Ss + (t2 - Mm)) * Nd + nb;
            #pragma unroll
            for (int uu = 0; uu < 4; ++uu) *(float4*)(dst + uu * 4) = *(float4*)&vv[uu * 4];
        }
    }
}

__global__ void k_reduce_splitk(const float* __restrict__ part, float* __restrict__ out,
                                int n, int z, float alpha) {
    int i = blockIdx.x * 256 + threadIdx.x;
    if (i >= n) return;
    float s = 0.f;
    for (int zz = 0; zz < z; ++zz) s += part[(size_t)zz * n + i];
    out[i] = alpha * s;
}

// ---- causal depthwise conv K=4 + SiLU (+L2n for q,k); fp32 in, hi/lo out --
__global__ __launch_bounds__(256) void k_conv3(
        const float* __restrict__ yq, const float* __restrict__ yk, const float* __restrict__ yv,
        const float* __restrict__ cq, const float* __restrict__ ck, const float* __restrict__ cv,
        unsigned short* oqh, unsigned short* oql, unsigned short* okh, unsigned short* okl,
        unsigned short* ovh, unsigned short* ovl) {
    int which = blockIdx.y;
    const float* y  = which == 0 ? yq : which == 1 ? yk : yv;
    const float* cw = which == 0 ? cq : which == 1 ? ck : cv;
    unsigned short* oh = which == 0 ? oqh : which == 1 ? okh : ovh;
    unsigned short* ol = which == 0 ? oql : which == 1 ? okl : ovl;
    bool norm = which < 2;
    int r = blockIdx.x;
    int b = r / Nn, t = r - b * Nn;
    const size_t rowbase = (size_t)r * Dd;
    float s[2];
    #pragma unroll
    for (int u = 0; u < 2; ++u) {
        int d = threadIdx.x + u * 256;
        float acc = 0.f;
        #pragma unroll
        for (int k = 0; k < 4; ++k) {
            int tt = t - 3 + k;
            if (tt >= 0) acc += y[(size_t)(b * Nn + tt) * Dd + d] * cw[d * 4 + k];
        }
        s[u] = siluf(acc);
    }
    float denom = 1.0f;
    if (norm) {
        __shared__ float red[256];
        red[threadIdx.x] = s[0] * s[0] + s[1] * s[1];
        __syncthreads();
        for (int off = 128; off; off >>= 1) {
            if (threadIdx.x < off) red[threadIdx.x] += red[threadIdx.x + off];
            __syncthreads();
        }
        denom = fmaxf(sqrtf(red[0]), 1e-12f);
    }
    #pragma unroll
    for (int u = 0; u < 2; ++u) {
        float v = s[u] / denom;
        unsigned short h = f2bf(v);
        oh[rowbase + threadIdx.x + u * 256] = h;
        ol[rowbase + threadIdx.x + u * 256] = f2bf(v - bf2f(h));
    }
}

// ---- column sums for bias grads (hi/lo input) -----------------------------
__global__ void k_colsum(const unsigned short* __restrict__ gh, const unsigned short* __restrict__ gl,
                         float* __restrict__ part) {
    int col = blockIdx.x * 256 + threadIdx.x;
    int chunk = blockIdx.y;
    int r0 = chunk * (Rr / 64);
    float s = 0.f;
    for (int r = r0; r < r0 + Rr / 64; ++r) {
        size_t o = (size_t)r * Dd + col;
        s += bf2f(gh[o]) + bf2f(gl[o]);
    }
    part[chunk * Dd + col] = s;
}
__global__ void k_colsum_reduce(const float* __restrict__ part, float* __restrict__ out, float alpha) {
    int col = blockIdx.x * 256 + threadIdx.x;
    if (col >= Dd) return;
    float s = 0.f;
    for (int c = 0; c < 64; ++c) s += part[c * Dd + col];
    out[col] = alpha * s;
}

// ---- parameter updates ----------------------------------------------------
struct UpdW4 { const float* p[4]; const float* mo[4]; const float* g[4];
               unsigned short* th[4]; unsigned short* tl[4]; };
__global__ void k_updW(UpdW4 u, const float* __restrict__ scal) {
    int seg = blockIdx.y;
    int i0 = blockIdx.x * 1024 + threadIdx.x * 4;
    float4 p4 = *(const float4*)(u.p[seg] + i0);
    float4 m4 = *(const float4*)(u.mo[seg] + i0);
    float4 g4 = *(const float4*)(u.g[seg] + i0);
    float a = 1.0f - scal[0], et = scal[2], th = scal[1];
    float vals[4] = { p4.x * a + et * m4.x - th * g4.x, p4.y * a + et * m4.y - th * g4.y,
                      p4.z * a + et * m4.z - th * g4.z, p4.w * a + et * m4.w - th * g4.w };
    int r = i0 >> 9, c = i0 & 511;
    #pragma unroll
    for (int e = 0; e < 4; ++e) {
        unsigned short h = f2bf(vals[e]);
        u.th[seg][(size_t)(c + e) * 512 + r] = h;
        u.tl[seg][(size_t)(c + e) * 512 + r] = f2bf(vals[e] - bf2f(h));
    }
}
struct UpdB4 { const float* p[4]; const float* mo[4]; const float* g[4]; float* o[4]; };
__global__ void k_updB(UpdB4 u, const float* __restrict__ scal) {
    int seg = blockIdx.x >> 1;
    int i = (blockIdx.x & 1) * 256 + threadIdx.x;
    u.o[seg][i] = u.p[seg][i] * (1.0f - scal[0]) + scal[2] * u.mo[seg][i] - scal[1] * u.g[seg][i];
}

// ---- SWA: wave-autonomous key-split partials ------------------------------
// Block = 1 wave of 64 lanes; lane = query. blockIdx: (q-tile, bh, key-chunk).
// K/V rows read wave-uniformly (scalar-load broadcast); per-lane online
// softmax (no shuffles, no LDS, no barriers).
__global__ __launch_bounds__(64) void k_swa_part(const float* __restrict__ qs,
                                                 const float* __restrict__ ks,
                                                 const float* __restrict__ vs,
                                                 float* __restrict__ po,
                                                 float* __restrict__ pml) {
    const int lane = threadIdx.x;
    const int q0 = blockIdx.x * 64;
    const int bh = blockIdx.y;
    const int s  = blockIdx.z;
    const int h = bh & 7, b = bh >> 3;
    const size_t srow = (size_t)(b * Nn) * Dd + h * HD;
    const int i = q0 + lane;

    float q[64];
    const float* qr = qs + srow + (size_t)i * Dd;
    #pragma unroll
    for (int d4 = 0; d4 < 16; ++d4) *(float4*)&q[d4 * 4] = ((const float4*)qr)[d4];
    float o[64];
    #pragma unroll
    for (int d = 0; d < 64; ++d) o[d] = 0.f;
    float m = -1e30f, l = 0.f;

    int jlo = q0 - (WINw - 1); if (jlo < 0) jlo = 0;
    const int T = q0 + 64 - jlo;
    const int chunk = (T + 3) >> 2;
    const int js = jlo + s * chunk;
    int je = js + chunk; if (je > jlo + T) je = jlo + T;

    for (int jt = js; jt < je; jt += 16) {
        float sv[16];
        #pragma unroll
        for (int e = 0; e < 16; ++e) {
            int j = jt + e;
            int jr = (j < je) ? j : (je - 1);          // uniform clamp, stay in-bounds
            const float* kr = ks + srow + (size_t)jr * Dd;
            float sc = 0.f;
            #pragma unroll
            for (int d4 = 0; d4 < 16; ++d4) {
                float4 k4 = ((const float4*)kr)[d4];
                sc += q[d4 * 4 + 0] * k4.x + q[d4 * 4 + 1] * k4.y
                    + q[d4 * 4 + 2] * k4.z + q[d4 * 4 + 3] * k4.w;
            }
            bool ok = (j < je) && (j <= i) && (i - j < WINw);
            sv[e] = ok ? sc * 0.125f : -1e30f;
        }
        float mt = -1e30f;
        #pragma unroll
        for (int e = 0; e < 16; ++e) mt = fmaxf(mt, sv[e]);
        float mnew = fmaxf(m, mt);
        float corr = __expf(m - mnew);
        l *= corr;
        #pragma unroll
        for (int d = 0; d < 64; ++d) o[d] *= corr;
        #pragma unroll
        for (int e = 0; e < 16; ++e) {
            int j = jt + e;
            int jr = (j < je) ? j : (je - 1);
            float pe = (sv[e] > -1e29f) ? __expf(sv[e] - mnew) : 0.f;
            l += pe;
            const float* vr = vs + srow + (size_t)jr * Dd;
            #pragma unroll
            for (int d4 = 0; d4 < 16; ++d4) {
                float4 v4 = ((const float4*)vr)[d4];
                o[d4 * 4 + 0] += pe * v4.x; o[d4 * 4 + 1] += pe * v4.y;
                o[d4 * 4 + 2] += pe * v4.z; o[d4 * 4 + 3] += pe * v4.w;
            }
        }
        m = mnew;
    }
    size_t slot = (size_t)(s * 16 + bh) * 2112 + i;
    float* op = po + slot * 64;
    #pragma unroll
    for (int d4 = 0; d4 < 16; ++d4) *(float4*)(op + d4 * 4) = *(float4*)&o[d4 * 4];
    pml[slot * 2]     = m;
    pml[slot * 2 + 1] = l;
}

__global__ __launch_bounds__(256) void k_swa_merge(const float* __restrict__ po,
                                                   const float* __restrict__ pml,
                                                   float* __restrict__ out) {
    const int tid = threadIdx.x;
    const int qloc = tid >> 2, dg = tid & 3;
    const int i = blockIdx.x * 64 + qloc;
    const int bh = blockIdx.y;
    const int h = bh & 7, b = bh >> 3;
    const size_t bq = (size_t)bh * 2112 + i;
    float ms[4], ls[4];
    #pragma unroll
    for (int s = 0; s < 4; ++s) {
        size_t sl = (size_t)s * 16 * 2112 + bq;
        ms[s] = pml[sl * 2]; ls[s] = pml[sl * 2 + 1];
    }
    float mstar = fmaxf(fmaxf(ms[0], ms[1]), fmaxf(ms[2], ms[3]));
    float w[4], lstar = 0.f;
    #pragma unroll
    for (int s = 0; s < 4; ++s) { w[s] = __expf(ms[s] - mstar); lstar += w[s] * ls[s]; }
    float inv = 1.0f / lstar;
    const size_t srow = (size_t)(b * Nn) * Dd + h * HD;
    float* op = out + srow + (size_t)i * Dd + dg * 16;
    #pragma unroll
    for (int u = 0; u < 4; ++u) {
        float ax = 0.f, ay = 0.f, az = 0.f, aw = 0.f;
        #pragma unroll
        for (int s = 0; s < 4; ++s) {
            const float* pp = po + ((size_t)s * 16 * 2112 + bq) * 64 + dg * 16 + u * 4;
            float4 p4 = *(const float4*)pp;
            ax += w[s] * p4.x; ay += w[s] * p4.y; az += w[s] * p4.z; aw += w[s] * p4.w;
        }
        float4 r4; r4.x = ax * inv; r4.y = ay * inv; r4.z = az * inv; r4.w = aw * inv;
        *(float4*)(op + u * 4) = r4;
    }
}

} // namespace

extern "C" void kernel_launch(void* const* d_in, const int* in_sizes, int n_in,
                              void* d_out, int out_size, void* d_ws, size_t ws_size,
                              hipStream_t stream) {
    const float* x       = (const float*)d_in[0];
    const float* meta    = (const float*)d_in[1];
    const float* mWin    = (const float*)d_in[2];
    const float* mbin    = (const float*)d_in[3];
    const float* mWh     = (const float*)d_in[4];
    const float* mbh     = (const float*)d_in[5];
    const float* mWout   = (const float*)d_in[6];
    const float* mbout   = (const float*)d_in[7];
    const float* momWin  = (const float*)d_in[8];
    const float* mombin  = (const float*)d_in[9];
    const float* momWh   = (const float*)d_in[10];
    const float* mombh   = (const float*)d_in[11];
    const float* momWout = (const float*)d_in[12];
    const float* mombout = (const float*)d_in[13];
    const float* q_w = (const float*)d_in[14]; const float* q_b = (const float*)d_in[15]; const float* q_c = (const float*)d_in[16];
    const float* k_w = (const float*)d_in[17]; const float* k_b = (const float*)d_in[18]; const float* k_c = (const float*)d_in[19];
    const float* v_w = (const float*)d_in[20]; const float* v_b = (const float*)d_in[21]; const float* v_c = (const float*)d_in[22];
    const float* lr_w = (const float*)d_in[23]; const float* lr_b = (const float*)d_in[24];
    const float* fg_w = (const float*)d_in[25]; const float* fg_b = (const float*)d_in[26];
    const float* mo_w = (const float*)d_in[27]; const float* mo_b = (const float*)d_in[28];
    const float* swa_wq = (const float*)d_in[29]; const float* swa_wk = (const float*)d_in[30];
    const float* swa_wv = (const float*)d_in[31]; const float* swa_wo = (const float*)d_in[32];
    const float* swa_bq = (const float*)d_in[33]; const float* swa_bk = (const float*)d_in[34];
    const float* swa_bv = (const float*)d_in[35]; const float* swa_bo = (const float*)d_in[36];
    (void)in_sizes; (void)n_in; (void)out_size; (void)ws_size;

    char* wsb = (char*)d_ws;
    size_t off = 0;
    auto allocB = [&](size_t bytes) { void* p = wsb + off; off = (off + bytes + 255) & ~(size_t)255; return p; };
    auto allocU = [&](size_t elems) { return (unsigned short*)allocB(elems * 2); };
    auto allocF = [&](size_t elems) { return (float*)allocB(elems * 4); };

    unsigned short *xm_h = allocU(NBD), *xm_l = allocU(NBD);     // reused as gB
    unsigned short *qb_h = allocU(NBD), *qb_l = allocU(NBD);     // po overlay start
    unsigned short *kb_h = allocU(NBD), *kb_l = allocU(NBD);
    unsigned short *vb_h = allocU(NBD), *vb_l = allocU(NBD);     // reused as gA
    unsigned short *h0_h = allocU(NBD), *h0_l = allocU(NBD);     // po overlay end
    unsigned short *h1_h = allocU(NBD), *h1_l = allocU(NBD);     // pml overlay
    unsigned short *h2_h = allocU(NBD), *h2_l = allocU(NBD);
    unsigned short *g1_h = allocU(NBD), *g1_l = allocU(NBD);
    float *f0 = allocF(NBD), *f1 = allocF(NBD), *f2 = allocF(NBD), *f3 = allocF(NBD);
    float *parts = allocF((size_t)12 * 262144);
    const int WEL = 262144;
    unsigned short *wt_h[11], *wt_l[11], *wn_h[11];
    for (int i = 0; i < 11; ++i) { wt_h[i] = allocU(WEL); wt_l[i] = allocU(WEL); wn_h[i] = nullptr; }
    for (int i = 8; i < 11; ++i) wn_h[i] = allocU(WEL);          // natural hi: mWh0, mWh1, mWout
    unsigned short *nWinT_h = allocU(WEL), *nWinT_l = allocU(WEL);
    unsigned short *nWh0T_h = allocU(WEL), *nWh0T_l = allocU(WEL);
    unsigned short *nWh1T_h = allocU(WEL), *nWh1T_l = allocU(WEL);
    unsigned short *nWoutT_h = allocU(WEL), *nWoutT_l = allocU(WEL);
    float *gWin = allocF(WEL), *gWh0 = allocF(WEL), *gWh1 = allocF(WEL), *gWout = allocF(WEL);
    float *gbin = allocF(512), *gbh0 = allocF(512), *gbh1 = allocF(512), *gbout = allocF(512);
    float *nbin = allocF(512), *nbh0 = allocF(512), *nbh1 = allocF(512), *nbout = allocF(512);
    float *lr_t = allocF(Rr), *fg_t = allocF(Rr), *mo_t = allocF(Rr);
    float *scal = allocF(8);
    float *cpart = allocF(64 * 512);
    unsigned short *gA_h = vb_h, *gA_l = vb_l;
    unsigned short *gB_h = xm_h, *gB_l = xm_l;
    // SWA partial overlays (regions dead by Phase F):
    float* po  = (float*)qb_h;      // 4*16*2112*64 floats = 34.6 MB = qb..h0 block
    float* pml = (float*)h1_h;      // 4*16*2112*2 floats

    TriSet none{};
    const dim3 GG(66, 8);

    // ---- weight conversion ----
    WC wc{};
    const float* wlist[11] = { q_w, k_w, v_w, swa_wq, swa_wk, swa_wv, swa_wo,
                               mWin, mWh, mWh + WEL, mWout };
    for (int i = 0; i < 11; ++i) { wc.w[i] = wlist[i]; wc.th[i] = wt_h[i]; wc.tl[i] = wt_l[i]; wc.nh[i] = wn_h[i]; }
    k_wconv<<<dim3(256, 11), 256, 0, stream>>>(wc);

    // ---- Phase A ----
    k_build_xm<<<(Rr * 128 + 255) / 256, 256, 0, stream>>>(x, meta, xm_h, xm_l);
    k_gates<<<Rr / 4, 256, 0, stream>>>(xm_h, xm_l, lr_w, lr_b, fg_w, fg_b, mo_w, mo_b, lr_t, fg_t, mo_t);
    k_gate_means<<<1, 256, 0, stream>>>(lr_t, fg_t, mo_t, scal);

    TriSet qkvA{{ { wt_h[0], wt_l[0], q_b, f0 }, { wt_h[1], wt_l[1], k_b, f1 }, { wt_h[2], wt_l[2], v_b, f2 } }};
    k_mm<0, 0, false, 0, true, 3, false><<<dim3(66, 8, 3), 256, 0, stream>>>(
        xm_h, xm_l, nullptr, nullptr, nullptr, nullptr, nullptr, nullptr, nullptr, nullptr,
        nullptr, nullptr, qkvA, Rr, Dd, Dd, 0);
    k_conv3<<<dim3(Rr, 3), 256, 0, stream>>>(f0, f1, f2, q_c, k_c, v_c,
                                             qb_h, qb_l, kb_h, kb_l, vb_h, vb_l);

    // ---- Phase B: memory-MLP forward (plain bf16; theta-damped path) ----
    k_mm<0, 0, false, 5, false, 1, false><<<GG, 256, 0, stream>>>(
        kb_h, nullptr, wt_h[7], nullptr, f0, mbin, nullptr, nullptr, nullptr, nullptr,
        h0_h, h0_l, none, Rr, Dd, Dd, 0);                               // z0=f0, h0
    k_mm<0, 0, false, 6, false, 1, false><<<GG, 256, 0, stream>>>(
        h0_h, nullptr, wt_h[8], nullptr, f1, mbh, nullptr, h0_h, h0_l, nullptr,
        h1_h, h1_l, none, Rr, Dd, Dd, 0);                               // a0=f1, h1
    k_mm<0, 0, false, 6, false, 1, false><<<GG, 256, 0, stream>>>(
        h1_h, nullptr, wt_h[9], nullptr, f2, mbh + 512, nullptr, h1_h, h1_l, nullptr,
        h2_h, h2_l, none, Rr, Dd, Dd, 0);                               // a1=f2, h2
    k_mm<0, 0, false, 3, false, 1, false><<<GG, 256, 0, stream>>>(
        h2_h, nullptr, wt_h[10], nullptr, nullptr, mbout, nullptr, vb_h, vb_l, lr_t,
        g1_h, g1_l, none, Rr, Dd, Dd, 0);                               // g1 = dpred

    // ---- Phase C: backward ----
    auto GRADW = [&](const unsigned short* ah, const unsigned short* bh, float* gout) {
        k_mm<1, 1, true, 0, false, 1, false><<<dim3(8, 8, 11), 256, 0, stream>>>(
            ah, nullptr, bh, nullptr, parts, nullptr, nullptr, nullptr, nullptr, nullptr,
            nullptr, nullptr, none, Dd, Dd, Rr, 0);
        k_reduce_splitk<<<1024, 256, 0, stream>>>(parts, gout, WEL, 11, 1.0f / NCc);
    };
    auto COLSUM = [&](const unsigned short* gh, const unsigned short* gl, float* bo) {
        k_colsum<<<dim3(2, 64), 256, 0, stream>>>(gh, gl, cpart);
        k_colsum_reduce<<<2, 256, 0, stream>>>(cpart, bo, 1.0f / NCc);
    };
    GRADW(h2_h, g1_h, gWout);  COLSUM(g1_h, g1_l, gbout);
    k_mm<0, 0, false, 4, false, 1, false><<<GG, 256, 0, stream>>>(
        g1_h, nullptr, wn_h[10], nullptr, f3, nullptr, f2, nullptr, nullptr, nullptr,
        gA_h, gA_l, none, Rr, Dd, Dd, 0);                               // f3=dh2, gA=da1
    GRADW(h1_h, gA_h, gWh1);   COLSUM(gA_h, gA_l, gbh1);
    k_mm<0, 0, false, 4, false, 1, false><<<GG, 256, 0, stream>>>(
        gA_h, nullptr, wn_h[9], nullptr, f3, nullptr, f1, nullptr, nullptr, nullptr,
        gB_h, gB_l, none, Rr, Dd, Dd, 1);                               // f3=dh1, gB=da0
    GRADW(h0_h, gB_h, gWh0);   COLSUM(gB_h, gB_l, gbh0);
    k_mm<0, 0, false, 4, false, 1, false><<<GG, 256, 0, stream>>>(
        gB_h, nullptr, wn_h[8], nullptr, f3, nullptr, f0, nullptr, nullptr, nullptr,
        gA_h, gA_l, none, Rr, Dd, Dd, 1);                               // gA=dz0
    GRADW(kb_h, gA_h, gWin);   COLSUM(gA_h, gA_l, gbin);

    // ---- Phase D: updates ----
    UpdW4 uw{ { mWin, mWh, mWh + WEL, mWout },
              { momWin, momWh, momWh + WEL, momWout },
              { gWin, gWh0, gWh1, gWout },
              { nWinT_h, nWh0T_h, nWh1T_h, nWoutT_h },
              { nWinT_l, nWh0T_l, nWh1T_l, nWoutT_l } };
    k_updW<<<dim3(256, 4), 256, 0, stream>>>(uw, scal);
    UpdB4 ub{ { mbin, mbh, mbh + 512, mbout },
              { mombin, mombh, mombh + 512, mombout },
              { gbin, gbh0, gbh1, gbout },
              { nbin, nbh0, nbh1, nbout } };
    k_updB<<<8, 256, 0, stream>>>(ub, scal);

    // ---- Phase E: retrieval MLP on q (bf16x2 split) ----
    k_mm<0, 0, false, 1, false, 3, false><<<GG, 256, 0, stream>>>(
        qb_h, qb_l, nWinT_h, nWinT_l, nullptr, nbin, nullptr, nullptr, nullptr, nullptr,
        g1_h, g1_l, none, Rr, Dd, Dd, 0);                               // e0 -> g1
    k_mm<0, 0, false, 2, false, 3, false><<<GG, 256, 0, stream>>>(
        g1_h, g1_l, nWh0T_h, nWh0T_l, nullptr, nbh0, nullptr, g1_h, g1_l, nullptr,
        h0_h, h0_l, none, Rr, Dd, Dd, 0);                               // e1 -> h0
    k_mm<0, 0, false, 2, false, 3, false><<<GG, 256, 0, stream>>>(
        h0_h, h0_l, nWh1T_h, nWh1T_l, nullptr, nbh1, nullptr, h0_h, h0_l, nullptr,
        h1_h, h1_l, none, Rr, Dd, Dd, 0);                               // e2 -> h1
    k_mm<0, 0, false, 1, false, 3, false><<<GG, 256, 0, stream>>>(
        h1_h, h1_l, nWoutT_h, nWoutT_l, nullptr, nbout, nullptr, nullptr, nullptr, nullptr,
        h2_h, h2_l, none, Rr, Dd, Dd, 0);                               // retrieved -> h2

    // ---- Phase F: SWA qkv (fp32 out), attention, fused out-proj+slice ----
    TriSet qkvF{{ { wt_h[3], wt_l[3], swa_bq, f0 }, { wt_h[4], wt_l[4], swa_bk, f1 },
                  { wt_h[5], wt_l[5], swa_bv, f2 } }};
    k_mm<0, 0, false, 0, true, 3, false><<<dim3(66, 8, 3), 256, 0, stream>>>(
        h2_h, h2_l, nullptr, nullptr, nullptr, nullptr, nullptr, nullptr, nullptr, nullptr,
        nullptr, nullptr, qkvF, Rr, Dd, Dd, 0);
    k_swa_part<<<dim3(Nn / 64, Bb * NHh, 4), 64, 0, stream>>>(f0, f1, f2, po, pml);
    k_swa_merge<<<dim3(Nn / 64, Bb * NHh), 256, 0, stream>>>(po, pml, f3);
    k_mm<0, 0, false, 7, false, 3, true><<<GG, 256, 0, stream>>>(
        f3, nullptr, wt_h[6], wt_l[6], (float*)d_out, swa_bo, nullptr, nullptr, nullptr, nullptr,
        nullptr, nullptr, none, Rr, Dd, Dd, 0);
}

// Round 5
// 841.573 us; speedup vs baseline: 3.2625x; 1.0238x over previous
//
#include <hip/hip_runtime.h>
#include <cmath>

// ---------------------------------------------------------------------------
// NeuralMemory R5: SWA re-split (32q x 2 dim-halves per wave, 4224 waves),
// XOR-swizzled LDS transpose stores in GRADW (kills 16-way bank conflicts),
// shuffle-based conv reduction. GEMM core/numerics unchanged from R4.
// ---------------------------------------------------------------------------

namespace {

constexpr int Bb   = 2;
constexpr int Ss   = 2048;
constexpr int Dd   = 512;
constexpr int Mm   = 64;
constexpr int NCc  = 16;
constexpr int NHh  = 8;
constexpr int HD   = 64;
constexpr int WINw = 256;
constexpr int Nn   = Mm + Ss;    // 2112
constexpr int Rr   = Bb * Nn;    // 4224
constexpr int NBD  = Rr * Dd;
constexpr float MAXLR = 0.1f;

typedef __attribute__((ext_vector_type(8))) short short8;
typedef __attribute__((ext_vector_type(4))) float f32x4;

__device__ __forceinline__ float sigf(float x)  { return 1.0f / (1.0f + __expf(-x)); }
__device__ __forceinline__ float siluf(float x) { return x * sigf(x); }
__device__ __forceinline__ float dsiluf(float x){ float s = sigf(x); return s * (1.0f + x * (1.0f - s)); }
__device__ __forceinline__ unsigned short f2bf(float f) {
    unsigned int u = __float_as_uint(f);
    u = (u + 0x7FFFu + ((u >> 16) & 1u)) >> 16;
    return (unsigned short)u;
}
__device__ __forceinline__ float bf2f(unsigned short h) {
    return __uint_as_float(((unsigned int)h) << 16);
}

// ---- build xm (hi/lo bf16) ------------------------------------------------
__global__ void k_build_xm(const float* __restrict__ x, const float* __restrict__ meta,
                           unsigned short* __restrict__ xh, unsigned short* __restrict__ xl) {
    int i = blockIdx.x * 256 + threadIdx.x;      // float4 units
    if (i >= Rr * 128) return;
    int c = i & 127, r = i >> 7;
    int b = r / Nn, t = r - b * Nn;
    float4 v = (t < Mm) ? ((const float4*)meta)[t * 128 + c]
                        : ((const float4*)x)[(size_t)(b * Ss + (t - Mm)) * 128 + c];
    float vv[4] = { v.x, v.y, v.z, v.w };
    unsigned short h[4], l[4];
    #pragma unroll
    for (int e = 0; e < 4; ++e) { h[e] = f2bf(vv[e]); l[e] = f2bf(vv[e] - bf2f(h[e])); }
    *(ushort4*)(xh + (size_t)i * 4) = *(ushort4*)h;
    *(ushort4*)(xl + (size_t)i * 4) = *(ushort4*)l;
}

// ---- per-row scalar gates -------------------------------------------------
__global__ void k_gates(const unsigned short* __restrict__ xh, const unsigned short* __restrict__ xl,
                        const float* __restrict__ lw, const float* __restrict__ lb,
                        const float* __restrict__ fw, const float* __restrict__ fb,
                        const float* __restrict__ mw, const float* __restrict__ mb,
                        float* __restrict__ lr_t, float* __restrict__ fg_t, float* __restrict__ mo_t) {
    int r = blockIdx.x * 4 + (threadIdx.x >> 6);
    int lane = threadIdx.x & 63;
    if (r >= Rr) return;
    float s0 = 0.f, s1 = 0.f, s2 = 0.f;
    for (int j = lane; j < Dd; j += 64) {
        size_t o = (size_t)r * Dd + j;
        float v = bf2f(xh[o]) + bf2f(xl[o]);
        s0 += v * lw[j]; s1 += v * fw[j]; s2 += v * mw[j];
    }
    #pragma unroll
    for (int off = 32; off; off >>= 1) {
        s0 += __shfl_down(s0, off, 64);
        s1 += __shfl_down(s1, off, 64);
        s2 += __shfl_down(s2, off, 64);
    }
    if (lane == 0) {
        lr_t[r] = MAXLR * sigf(s0 + lb[0]);
        fg_t[r] = sigf(s1 + fb[0]);
        mo_t[r] = sigf(s2 + mb[0]);
    }
}

__global__ void k_gate_means(const float* __restrict__ lr_t, const float* __restrict__ fg_t,
                             const float* __restrict__ mo_t, float* __restrict__ scal) {
    __shared__ float red[256];
    const float* ptrs[3] = { fg_t, lr_t, mo_t };
    for (int w = 0; w < 3; ++w) {
        float acc = 0.f;
        for (int i = threadIdx.x; i < Rr; i += 256) acc += ptrs[w][i];
        red[threadIdx.x] = acc; __syncthreads();
        for (int off = 128; off; off >>= 1) {
            if (threadIdx.x < off) red[threadIdx.x] += red[threadIdx.x + off];
            __syncthreads();
        }
        if (threadIdx.x == 0) scal[w] = red[0] / (float)Rr;
        __syncthreads();
    }
}

// ---- weight convert: fp32 W[r][c] -> WT hi/lo [c][r]; optional natural hi --
struct WC { const float* w[11]; unsigned short* th[11]; unsigned short* tl[11]; unsigned short* nh[11]; };
__global__ void k_wconv(WC wc) {
    int seg = blockIdx.y;
    int i0 = blockIdx.x * 1024 + threadIdx.x * 4;
    float4 v4 = *(const float4*)(wc.w[seg] + i0);
    float vals[4] = { v4.x, v4.y, v4.z, v4.w };
    int r = i0 >> 9, c = i0 & 511;
    #pragma unroll
    for (int e = 0; e < 4; ++e) {
        unsigned short h = f2bf(vals[e]);
        unsigned short l = f2bf(vals[e] - bf2f(h));
        wc.th[seg][(size_t)(c + e) * 512 + r] = h;
        wc.tl[seg][(size_t)(c + e) * 512 + r] = l;
        if (wc.nh[seg]) wc.nh[seg][i0 + e] = h;
    }
}

// ---- MFMA GEMM: 64x64 tile, BK=64, 256 thr (4 waves, each 32x32) ----------
// TA=0: A row-major (M,K); TA=1: A stored [k][m] (A^T B, GRADW).
// TB=0: B in [n][k] layout; TB=1: B row-major [k][n] (GRADW).
// Transpose paths (TA=1/TB=1) use XOR bank swizzle on the 16B LDS unit:
// phys_unit = (F*16 + row) ^ (f + (q&1)*4) — reader applies the same XOR;
// reads stay single contiguous ds_read_b128.
// NS=3: bf16x2 split; NS=1 plain hi. AF32: A fp32, split on the fly.
struct TriW { const unsigned short* bh; const unsigned short* bl; const float* bias; float* c; };
struct TriSet { TriW t[3]; };

template<int TA, int TB, bool SPLITK, int EPI, bool MULTI, int NS, bool AF32>
__global__ __launch_bounds__(256) void k_mm(
        const void* Ap, const unsigned short* Al_,
        const unsigned short* Bh_, const unsigned short* Bl_,
        float* C, const float* bias, const float* __restrict__ exf,
        const unsigned short* __restrict__ exh, const unsigned short* __restrict__ exl,
        const float* __restrict__ lrp,
        unsigned short* oh, unsigned short* ol, TriSet ts,
        int Md, int Nd, int Kd, int accum) {
    constexpr int SMEMB = (NS == 3) ? 32768 : 16384;
    __shared__ char smem[SMEMB];
    unsigned short* AH = (unsigned short*)smem;
    unsigned short* AL = AH + 4096;
    unsigned short* BH = AH + ((NS == 3) ? 8192 : 4096);
    unsigned short* BL = BH + 4096;
    const int tid = threadIdx.x;
    const int m0 = blockIdx.x * 64, n0 = blockIdx.y * 64;
    if constexpr (MULTI) {
        const TriW& tw = ts.t[blockIdx.z];
        Bh_ = tw.bh; Bl_ = tw.bl; bias = tw.bias; C = tw.c;
    }
    int kbg = 0, ke = Kd;
    if constexpr (SPLITK) {
        int kc = Kd / gridDim.z;
        kbg = blockIdx.z * kc; ke = kbg + kc;
        C += (size_t)blockIdx.z * Md * Nd;
    }
    const int astr = (TA == 0) ? Kd : Md;

    f32x4 acc[2][2];
    #pragma unroll
    for (int i = 0; i < 2; ++i)
        #pragma unroll
        for (int j = 0; j < 2; ++j)
            #pragma unroll
            for (int v = 0; v < 4; ++v) acc[i][j][v] = 0.f;

    short8 pA0, pA1, pAl0, pAl1, pB0, pB1, pBl0, pBl1;
    float4 pAf[4];

    auto gload = [&](int k0) {
        if constexpr (TA == 0) {
            int r = tid >> 2, ks2 = (tid & 3) * 16;
            if constexpr (AF32) {
                const float* ap = (const float*)Ap + (size_t)(m0 + r) * astr + k0 + ks2;
                pAf[0] = *(const float4*)ap;       pAf[1] = *(const float4*)(ap + 4);
                pAf[2] = *(const float4*)(ap + 8); pAf[3] = *(const float4*)(ap + 12);
            } else {
                const unsigned short* ah = (const unsigned short*)Ap + (size_t)(m0 + r) * astr + k0 + ks2;
                pA0 = *(const short8*)ah; pA1 = *(const short8*)(ah + 8);
                if constexpr (NS == 3) {
                    const unsigned short* al = Al_ + (size_t)(m0 + r) * astr + k0 + ks2;
                    pAl0 = *(const short8*)al; pAl1 = *(const short8*)(al + 8);
                }
            }
        } else {
            int kr = tid >> 2, ms = (tid & 3) * 16;
            const unsigned short* ah = (const unsigned short*)Ap + (size_t)(k0 + kr) * astr + m0 + ms;
            pA0 = *(const short8*)ah; pA1 = *(const short8*)(ah + 8);
            if constexpr (NS == 3) {
                const unsigned short* al = Al_ + (size_t)(k0 + kr) * astr + m0 + ms;
                pAl0 = *(const short8*)al; pAl1 = *(const short8*)(al + 8);
            }
        }
        if constexpr (TB == 0) {
            int nr = tid >> 2, ks2 = (tid & 3) * 16;
            const unsigned short* bh = Bh_ + (size_t)(n0 + nr) * Kd + k0 + ks2;
            pB0 = *(const short8*)bh; pB1 = *(const short8*)(bh + 8);
            if constexpr (NS == 3) {
                const unsigned short* bl = Bl_ + (size_t)(n0 + nr) * Kd + k0 + ks2;
                pBl0 = *(const short8*)bl; pBl1 = *(const short8*)(bl + 8);
            }
        } else {
            int kr = tid >> 2, nseg = (tid & 3) * 16;
            const unsigned short* bh = Bh_ + (size_t)(k0 + kr) * Nd + n0 + nseg;
            pB0 = *(const short8*)bh; pB1 = *(const short8*)(bh + 8);
            if constexpr (NS == 3) {
                const unsigned short* bl = Bl_ + (size_t)(k0 + kr) * Nd + n0 + nseg;
                pBl0 = *(const short8*)bl; pBl1 = *(const short8*)(bl + 8);
            }
        }
    };
    auto lstore = [&]() {
        if constexpr (TA == 0) {
            int r = tid >> 2, ks2 = (tid & 3) * 16;
            int f = r >> 4, rr = r & 15, kf = ks2 >> 5, q = (ks2 >> 3) & 3;
            int base = (((f * 2 + kf) * 4 + q) * 16 + rr) * 8;
            if constexpr (AF32) {
                unsigned short hh[16], ll[16];
                const float* pf = (const float*)pAf;
                #pragma unroll
                for (int e = 0; e < 16; ++e) { hh[e] = f2bf(pf[e]); ll[e] = f2bf(pf[e] - bf2f(hh[e])); }
                *(short8*)(AH + base) = *(short8*)hh;  *(short8*)(AH + base + 128) = *(short8*)(hh + 8);
                *(short8*)(AL + base) = *(short8*)ll;  *(short8*)(AL + base + 128) = *(short8*)(ll + 8);
            } else {
                *(short8*)(AH + base) = pA0; *(short8*)(AH + base + 128) = pA1;
                if constexpr (NS == 3) { *(short8*)(AL + base) = pAl0; *(short8*)(AL + base + 128) = pAl1; }
            }
        } else {
            int kr = tid >> 2, ms = (tid & 3) * 16;
            int f = ms >> 4, kf = kr >> 5, q = (kr >> 3) & 3, kk = kr & 7;
            int F = (f * 2 + kf) * 4 + q;
            int g = f + (q & 1) * 4;               // bank-swizzle key
            unsigned short tmp[16];
            *(short8*)tmp = pA0; *(short8*)(tmp + 8) = pA1;
            #pragma unroll
            for (int e = 0; e < 16; ++e) AH[(((F << 4) | e) ^ g) * 8 + kk] = tmp[e];
            if constexpr (NS == 3) {
                *(short8*)tmp = pAl0; *(short8*)(tmp + 8) = pAl1;
                #pragma unroll
                for (int e = 0; e < 16; ++e) AL[(((F << 4) | e) ^ g) * 8 + kk] = tmp[e];
            }
        }
        if constexpr (TB == 0) {
            int nr = tid >> 2, ks2 = (tid & 3) * 16;
            int f = nr >> 4, rr = nr & 15, kf = ks2 >> 5, q = (ks2 >> 3) & 3;
            int base = (((f * 2 + kf) * 4 + q) * 16 + rr) * 8;
            *(short8*)(BH + base) = pB0; *(short8*)(BH + base + 128) = pB1;
            if constexpr (NS == 3) { *(short8*)(BL + base) = pBl0; *(short8*)(BL + base + 128) = pBl1; }
        } else {
            int kr = tid >> 2, nseg = (tid & 3) * 16;
            int f = nseg >> 4, kf = kr >> 5, q = (kr >> 3) & 3, kk = kr & 7;
            int F = (f * 2 + kf) * 4 + q;
            int g = f + (q & 1) * 4;
            unsigned short tmp[16];
            *(short8*)tmp = pB0; *(short8*)(tmp + 8) = pB1;
            #pragma unroll
            for (int e = 0; e < 16; ++e) BH[(((F << 4) | e) ^ g) * 8 + kk] = tmp[e];
            if constexpr (NS == 3) {
                *(short8*)tmp = pBl0; *(short8*)(tmp + 8) = pBl1;
                #pragma unroll
                for (int e = 0; e < 16; ++e) BL[(((F << 4) | e) ^ g) * 8 + kk] = tmp[e];
            }
        }
    };

    const int wv = tid >> 6, lr16 = tid & 15, lq = (tid >> 4) & 3;
    const int wm = wv & 1, wn = wv >> 1;

    gload(kbg); lstore();
    __syncthreads();
    for (int k0 = kbg; k0 < ke; k0 += 64) {
        bool more = (k0 + 64) < ke;
        if (more) gload(k0 + 64);
        #pragma unroll
        for (int kf = 0; kf < 2; ++kf) {
            short8 fa[2], fal[2], fb[2], fbl[2];
            #pragma unroll
            for (int i = 0; i < 2; ++i) {
                int fA = wm * 2 + i;
                int u = ((fA * 2 + kf) * 4 + lq) * 16 + lr16;
                if constexpr (TA == 1) u ^= fA + (lq & 1) * 4;
                fa[i] = *(const short8*)(AH + u * 8);
                if constexpr (NS == 3) fal[i] = *(const short8*)(AL + u * 8);
            }
            #pragma unroll
            for (int j = 0; j < 2; ++j) {
                int fB = wn * 2 + j;
                int u = ((fB * 2 + kf) * 4 + lq) * 16 + lr16;
                if constexpr (TB == 1) u ^= fB + (lq & 1) * 4;
                fb[j] = *(const short8*)(BH + u * 8);
                if constexpr (NS == 3) fbl[j] = *(const short8*)(BL + u * 8);
            }
            #pragma unroll
            for (int i = 0; i < 2; ++i)
                #pragma unroll
                for (int j = 0; j < 2; ++j) {
                    acc[i][j] = __builtin_amdgcn_mfma_f32_16x16x32_bf16(fa[i], fb[j], acc[i][j], 0, 0, 0);
                    if constexpr (NS == 3) {
                        acc[i][j] = __builtin_amdgcn_mfma_f32_16x16x32_bf16(fa[i], fbl[j], acc[i][j], 0, 0, 0);
                        acc[i][j] = __builtin_amdgcn_mfma_f32_16x16x32_bf16(fal[i], fb[j], acc[i][j], 0, 0, 0);
                    }
                }
        }
        if (more) { __syncthreads(); lstore(); __syncthreads(); }
    }
    __syncthreads();

    // ---- epilogue: acc -> swizzled LDS fp32 -> row-major per-thread ----
    float* EP = (float*)smem;
    #pragma unroll
    for (int i = 0; i < 2; ++i)
        #pragma unroll
        for (int j = 0; j < 2; ++j)
            #pragma unroll
            for (int v = 0; v < 4; ++v) {
                int row = wm * 32 + i * 16 + lq * 4 + v;
                int col = wn * 32 + j * 16 + lr16;
                int u = col >> 2, up = u ^ (row & 15);
                EP[row * 64 + up * 4 + (col & 3)] = acc[i][j][v];
            }
    __syncthreads();
    int r = tid >> 2, cg = tid & 3;
    float vv[16];
    #pragma unroll
    for (int uu = 0; uu < 4; ++uu) {
        int u = cg * 4 + uu;
        *(float4*)&vv[uu * 4] = *(const float4*)&EP[r * 64 + ((u ^ (r & 15)) * 4)];
    }
    int m = m0 + r, nb = n0 + cg * 16;
    size_t idx = (size_t)m * Nd + nb;

    if constexpr (SPLITK) {
        #pragma unroll
        for (int uu = 0; uu < 4; ++uu) *(float4*)(C + idx + uu * 4) = *(float4*)&vv[uu * 4];
        return;
    }
    if (bias) {
        #pragma unroll
        for (int uu = 0; uu < 4; ++uu) {
            float4 b4 = *(const float4*)(bias + nb + uu * 4);
            vv[uu * 4 + 0] += b4.x; vv[uu * 4 + 1] += b4.y;
            vv[uu * 4 + 2] += b4.z; vv[uu * 4 + 3] += b4.w;
        }
    }
    unsigned short eh8[16], el8[16];
    if constexpr (EPI == 2 || EPI == 3 || EPI == 6) {
        #pragma unroll
        for (int k4 = 0; k4 < 2; ++k4) {
            *(short8*)&eh8[k4 * 8] = *(const short8*)(exh + idx + k4 * 8);
            *(short8*)&el8[k4 * 8] = *(const short8*)(exl + idx + k4 * 8);
        }
    }
    auto store_hl = [&](const float* s) {
        unsigned short hb[16], lb2[16];
        #pragma unroll
        for (int e = 0; e < 16; ++e) { hb[e] = f2bf(s[e]); lb2[e] = f2bf(s[e] - bf2f(hb[e])); }
        #pragma unroll
        for (int k4 = 0; k4 < 2; ++k4) {
            *(short8*)(oh + idx + k4 * 8) = *(short8*)&hb[k4 * 8];
            *(short8*)(ol + idx + k4 * 8) = *(short8*)&lb2[k4 * 8];
        }
    };
    auto accum_add = [&]() {
        #pragma unroll
        for (int uu = 0; uu < 4; ++uu) {
            float4 o4 = *(const float4*)(C + idx + uu * 4);
            vv[uu * 4 + 0] += o4.x; vv[uu * 4 + 1] += o4.y;
            vv[uu * 4 + 2] += o4.z; vv[uu * 4 + 3] += o4.w;
        }
    };
    auto store_f = [&]() {
        #pragma unroll
        for (int uu = 0; uu < 4; ++uu) *(float4*)(C + idx + uu * 4) = *(float4*)&vv[uu * 4];
    };
    if constexpr (EPI == 0) {
        if (accum) accum_add();
        store_f();
    } else if constexpr (EPI == 1) {
        float s[16];
        #pragma unroll
        for (int e = 0; e < 16; ++e) s[e] = siluf(vv[e]);
        store_hl(s);
    } else if constexpr (EPI == 2) {
        float s[16];
        #pragma unroll
        for (int e = 0; e < 16; ++e) s[e] = bf2f(eh8[e]) + bf2f(el8[e]) + siluf(vv[e]);
        store_hl(s);
    } else if constexpr (EPI == 3) {
        float sc = (2.0f / 512.0f) * lrp[m];
        float s[16];
        #pragma unroll
        for (int e = 0; e < 16; ++e) s[e] = sc * (vv[e] - (bf2f(eh8[e]) + bf2f(el8[e])));
        store_hl(s);
    } else if constexpr (EPI == 4) {
        if (accum) accum_add();
        store_f();
        float s[16];
        #pragma unroll
        for (int e = 0; e < 16; ++e) s[e] = vv[e] * dsiluf(exf[idx + e]);
        store_hl(s);
    } else if constexpr (EPI == 5) {
        store_f();
        float s[16];
        #pragma unroll
        for (int e = 0; e < 16; ++e) s[e] = siluf(vv[e]);
        store_hl(s);
    } else if constexpr (EPI == 6) {
        store_f();
        float s[16];
        #pragma unroll
        for (int e = 0; e < 16; ++e) s[e] = bf2f(eh8[e]) + bf2f(el8[e]) + siluf(vv[e]);
        store_hl(s);
    } else if constexpr (EPI == 7) {
        int b2 = m / Nn, t2 = m - b2 * Nn;
        if (t2 >= Mm) {
            float* dst = C + (size_t)(b2 * Ss + (t2 - Mm)) * Nd + nb;
            #pragma unroll
            for (int uu = 0; uu < 4; ++uu) *(float4*)(dst + uu * 4) = *(float4*)&vv[uu * 4];
        }
    }
}

__global__ void k_reduce_splitk(const float* __restrict__ part, float* __restrict__ out,
                                int n, int z, float alpha) {
    int i = blockIdx.x * 256 + threadIdx.x;
    if (i >= n) return;
    float s = 0.f;
    for (int zz = 0; zz < z; ++zz) s += part[(size_t)zz * n + i];
    out[i] = alpha * s;
}

// ---- causal depthwise conv K=4 + SiLU (+L2n for q,k); fp32 in, hi/lo out --
__global__ __launch_bounds__(256) void k_conv3(
        const float* __restrict__ yq, const float* __restrict__ yk, const float* __restrict__ yv,
        const float* __restrict__ cq, const float* __restrict__ ck, const float* __restrict__ cv,
        unsigned short* oqh, unsigned short* oql, unsigned short* okh, unsigned short* okl,
        unsigned short* ovh, unsigned short* ovl) {
    int which = blockIdx.y;
    const float* y  = which == 0 ? yq : which == 1 ? yk : yv;
    const float* cw = which == 0 ? cq : which == 1 ? ck : cv;
    unsigned short* oh = which == 0 ? oqh : which == 1 ? okh : ovh;
    unsigned short* ol = which == 0 ? oql : which == 1 ? okl : ovl;
    bool norm = which < 2;
    int r = blockIdx.x;
    int b = r / Nn, t = r - b * Nn;
    const size_t rowbase = (size_t)r * Dd;
    float s[2];
    #pragma unroll
    for (int u = 0; u < 2; ++u) {
        int d = threadIdx.x + u * 256;
        float acc = 0.f;
        #pragma unroll
        for (int k = 0; k < 4; ++k) {
            int tt = t - 3 + k;
            if (tt >= 0) acc += y[(size_t)(b * Nn + tt) * Dd + d] * cw[d * 4 + k];
        }
        s[u] = siluf(acc);
    }
    float denom = 1.0f;
    if (norm) {
        __shared__ float wr[4];
        float v2 = s[0] * s[0] + s[1] * s[1];
        #pragma unroll
        for (int off = 32; off; off >>= 1) v2 += __shfl_xor(v2, off, 64);
        if ((threadIdx.x & 63) == 0) wr[threadIdx.x >> 6] = v2;
        __syncthreads();
        denom = fmaxf(sqrtf(wr[0] + wr[1] + wr[2] + wr[3]), 1e-12f);
    }
    #pragma unroll
    for (int u = 0; u < 2; ++u) {
        float v = s[u] / denom;
        unsigned short h = f2bf(v);
        oh[rowbase + threadIdx.x + u * 256] = h;
        ol[rowbase + threadIdx.x + u * 256] = f2bf(v - bf2f(h));
    }
}

// ---- column sums for bias grads (hi/lo input) -----------------------------
__global__ void k_colsum(const unsigned short* __restrict__ gh, const unsigned short* __restrict__ gl,
                         float* __restrict__ part) {
    int col = blockIdx.x * 256 + threadIdx.x;
    int chunk = blockIdx.y;
    int r0 = chunk * (Rr / 64);
    float s = 0.f;
    for (int r = r0; r < r0 + Rr / 64; ++r) {
        size_t o = (size_t)r * Dd + col;
        s += bf2f(gh[o]) + bf2f(gl[o]);
    }
    part[chunk * Dd + col] = s;
}
__global__ void k_colsum_reduce(const float* __restrict__ part, float* __restrict__ out, float alpha) {
    int col = blockIdx.x * 256 + threadIdx.x;
    if (col >= Dd) return;
    float s = 0.f;
    for (int c = 0; c < 64; ++c) s += part[c * Dd + col];
    out[col] = alpha * s;
}

// ---- parameter updates ----------------------------------------------------
struct UpdW4 { const float* p[4]; const float* mo[4]; const float* g[4];
               unsigned short* th[4]; unsigned short* tl[4]; };
__global__ void k_updW(UpdW4 u, const float* __restrict__ scal) {
    int seg = blockIdx.y;
    int i0 = blockIdx.x * 1024 + threadIdx.x * 4;
    float4 p4 = *(const float4*)(u.p[seg] + i0);
    float4 m4 = *(const float4*)(u.mo[seg] + i0);
    float4 g4 = *(const float4*)(u.g[seg] + i0);
    float a = 1.0f - scal[0], et = scal[2], th = scal[1];
    float vals[4] = { p4.x * a + et * m4.x - th * g4.x, p4.y * a + et * m4.y - th * g4.y,
                      p4.z * a + et * m4.z - th * g4.z, p4.w * a + et * m4.w - th * g4.w };
    int r = i0 >> 9, c = i0 & 511;
    #pragma unroll
    for (int e = 0; e < 4; ++e) {
        unsigned short h = f2bf(vals[e]);
        u.th[seg][(size_t)(c + e) * 512 + r] = h;
        u.tl[seg][(size_t)(c + e) * 512 + r] = f2bf(vals[e] - bf2f(h));
    }
}
struct UpdB4 { const float* p[4]; const float* mo[4]; const float* g[4]; float* o[4]; };
__global__ void k_updB(UpdB4 u, const float* __restrict__ scal) {
    int seg = blockIdx.x >> 1;
    int i = (blockIdx.x & 1) * 256 + threadIdx.x;
    u.o[seg][i] = u.p[seg][i] * (1.0f - scal[0]) + scal[2] * u.mo[seg][i] - scal[1] * u.g[seg][i];
}

// ---- SWA partials: lane = (query, dim-half) -------------------------------
// Block = 1 wave; 32 queries x 2 dim-halves. Dot completed by shfl_xor(32).
// grid (66 q-tiles, 16 bh, 4 key-chunks) = 4224 waves.
__global__ __launch_bounds__(64) void k_swa_part(const float* __restrict__ qs,
                                                 const float* __restrict__ ks,
                                                 const float* __restrict__ vs,
                                                 float* __restrict__ po,
                                                 float* __restrict__ pml) {
    const int lane = threadIdx.x;
    const int ql = lane & 31, dh = lane >> 5;
    const int q0 = blockIdx.x * 32;
    const int bh = blockIdx.y;
    const int s  = blockIdx.z;
    const int h = bh & 7, b = bh >> 3;
    const size_t srow = (size_t)(b * Nn) * Dd + h * HD;
    const int i = q0 + ql;
    const int dbase = dh * 32;

    float q[32];
    const float* qr = qs + srow + (size_t)i * Dd + dbase;
    #pragma unroll
    for (int d4 = 0; d4 < 8; ++d4) *(float4*)&q[d4 * 4] = ((const float4*)qr)[d4];
    float o[32];
    #pragma unroll
    for (int d = 0; d < 32; ++d) o[d] = 0.f;
    float m = -1e30f, l = 0.f;

    int jlo = q0 - (WINw - 1); if (jlo < 0) jlo = 0;
    const int jhiX = q0 + 32;                       // exclusive key upper bound
    const int T = jhiX - jlo;
    const int chunk = (T + 3) >> 2;
    const int js = jlo + s * chunk;
    int je = js + chunk; if (je > jhiX) je = jhiX;

    for (int jt = js; jt < je; jt += 8) {
        float sv[8];
        #pragma unroll
        for (int e = 0; e < 8; ++e) {
            int j = jt + e;
            int jr = (j < je) ? j : (je - 1);
            const float* kr = ks + srow + (size_t)jr * Dd + dbase;
            float sc = 0.f;
            #pragma unroll
            for (int d4 = 0; d4 < 8; ++d4) {
                float4 k4 = ((const float4*)kr)[d4];
                sc += q[d4 * 4 + 0] * k4.x + q[d4 * 4 + 1] * k4.y
                    + q[d4 * 4 + 2] * k4.z + q[d4 * 4 + 3] * k4.w;
            }
            sc += __shfl_xor(sc, 32, 64);
            bool ok = (j < je) && (j <= i) && (i - j < WINw);
            sv[e] = ok ? sc * 0.125f : -1e30f;
        }
        float mt = -1e30f;
        #pragma unroll
        for (int e = 0; e < 8; ++e) mt = fmaxf(mt, sv[e]);
        float mnew = fmaxf(m, mt);
        float corr = __expf(m - mnew);
        l *= corr;
        #pragma unroll
        for (int d = 0; d < 32; ++d) o[d] *= corr;
        #pragma unroll
        for (int e = 0; e < 8; ++e) {
            int j = jt + e;
            int jr = (j < je) ? j : (je - 1);
            float pe = (sv[e] > -1e29f) ? __expf(sv[e] - mnew) : 0.f;
            l += pe;
            const float* vr = vs + srow + (size_t)jr * Dd + dbase;
            #pragma unroll
            for (int d4 = 0; d4 < 8; ++d4) {
                float4 v4 = ((const float4*)vr)[d4];
                o[d4 * 4 + 0] += pe * v4.x; o[d4 * 4 + 1] += pe * v4.y;
                o[d4 * 4 + 2] += pe * v4.z; o[d4 * 4 + 3] += pe * v4.w;
            }
        }
        m = mnew;
    }
    size_t slot = (size_t)(s * 16 + bh) * 2112 + i;
    float* op = po + slot * 64 + dbase;
    #pragma unroll
    for (int d4 = 0; d4 < 8; ++d4) *(float4*)(op + d4 * 4) = *(float4*)&o[d4 * 4];
    if (dh == 0) {
        pml[slot * 2]     = m;
        pml[slot * 2 + 1] = l;
    }
}

__global__ __launch_bounds__(256) void k_swa_merge(const float* __restrict__ po,
                                                   const float* __restrict__ pml,
                                                   float* __restrict__ out) {
    const int tid = threadIdx.x;
    const int qloc = tid >> 2, dg = tid & 3;
    const int i = blockIdx.x * 64 + qloc;
    const int bh = blockIdx.y;
    const int h = bh & 7, b = bh >> 3;
    const size_t bq = (size_t)bh * 2112 + i;
    float ms[4], ls[4];
    #pragma unroll
    for (int s = 0; s < 4; ++s) {
        size_t sl = (size_t)s * 16 * 2112 + bq;
        ms[s] = pml[sl * 2]; ls[s] = pml[sl * 2 + 1];
    }
    float mstar = fmaxf(fmaxf(ms[0], ms[1]), fmaxf(ms[2], ms[3]));
    float w[4], lstar = 0.f;
    #pragma unroll
    for (int s = 0; s < 4; ++s) { w[s] = __expf(ms[s] - mstar); lstar += w[s] * ls[s]; }
    float inv = 1.0f / lstar;
    const size_t srow = (size_t)(b * Nn) * Dd + h * HD;
    float* op = out + srow + (size_t)i * Dd + dg * 16;
    #pragma unroll
    for (int u = 0; u < 4; ++u) {
        float ax = 0.f, ay = 0.f, az = 0.f, aw = 0.f;
        #pragma unroll
        for (int s = 0; s < 4; ++s) {
            const float* pp = po + ((size_t)s * 16 * 2112 + bq) * 64 + dg * 16 + u * 4;
            float4 p4 = *(const float4*)pp;
            ax += w[s] * p4.x; ay += w[s] * p4.y; az += w[s] * p4.z; aw += w[s] * p4.w;
        }
        float4 r4; r4.x = ax * inv; r4.y = ay * inv; r4.z = az * inv; r4.w = aw * inv;
        *(float4*)(op + u * 4) = r4;
    }
}

} // namespace

extern "C" void kernel_launch(void* const* d_in, const int* in_sizes, int n_in,
                              void* d_out, int out_size, void* d_ws, size_t ws_size,
                              hipStream_t stream) {
    const float* x       = (const float*)d_in[0];
    const float* meta    = (const float*)d_in[1];
    const float* mWin    = (const float*)d_in[2];
    const float* mbin    = (const float*)d_in[3];
    const float* mWh     = (const float*)d_in[4];
    const float* mbh     = (const float*)d_in[5];
    const float* mWout   = (const float*)d_in[6];
    const float* mbout   = (const float*)d_in[7];
    const float* momWin  = (const float*)d_in[8];
    const float* mombin  = (const float*)d_in[9];
    const float* momWh   = (const float*)d_in[10];
    const float* mombh   = (const float*)d_in[11];
    const float* momWout = (const float*)d_in[12];
    const float* mombout = (const float*)d_in[13];
    const float* q_w = (const float*)d_in[14]; const float* q_b = (const float*)d_in[15]; const float* q_c = (const float*)d_in[16];
    const float* k_w = (const float*)d_in[17]; const float* k_b = (const float*)d_in[18]; const float* k_c = (const float*)d_in[19];
    const float* v_w = (const float*)d_in[20]; const float* v_b = (const float*)d_in[21]; const float* v_c = (const float*)d_in[22];
    const float* lr_w = (const float*)d_in[23]; const float* lr_b = (const float*)d_in[24];
    const float* fg_w = (const float*)d_in[25]; const float* fg_b = (const float*)d_in[26];
    const float* mo_w = (const float*)d_in[27]; const float* mo_b = (const float*)d_in[28];
    const float* swa_wq = (const float*)d_in[29]; const float* swa_wk = (const float*)d_in[30];
    const float* swa_wv = (const float*)d_in[31]; const float* swa_wo = (const float*)d_in[32];
    const float* swa_bq = (const float*)d_in[33]; const float* swa_bk = (const float*)d_in[34];
    const float* swa_bv = (const float*)d_in[35]; const float* swa_bo = (const float*)d_in[36];
    (void)in_sizes; (void)n_in; (void)out_size; (void)ws_size;

    char* wsb = (char*)d_ws;
    size_t off = 0;
    auto allocB = [&](size_t bytes) { void* p = wsb + off; off = (off + bytes + 255) & ~(size_t)255; return p; };
    auto allocU = [&](size_t elems) { return (unsigned short*)allocB(elems * 2); };
    auto allocF = [&](size_t elems) { return (float*)allocB(elems * 4); };

    unsigned short *xm_h = allocU(NBD), *xm_l = allocU(NBD);     // reused as gB
    unsigned short *qb_h = allocU(NBD), *qb_l = allocU(NBD);     // po overlay start
    unsigned short *kb_h = allocU(NBD), *kb_l = allocU(NBD);
    unsigned short *vb_h = allocU(NBD), *vb_l = allocU(NBD);     // reused as gA
    unsigned short *h0_h = allocU(NBD), *h0_l = allocU(NBD);     // po overlay end
    unsigned short *h1_h = allocU(NBD), *h1_l = allocU(NBD);     // pml overlay
    unsigned short *h2_h = allocU(NBD), *h2_l = allocU(NBD);
    unsigned short *g1_h = allocU(NBD), *g1_l = allocU(NBD);
    float *f0 = allocF(NBD), *f1 = allocF(NBD), *f2 = allocF(NBD), *f3 = allocF(NBD);
    float *parts = allocF((size_t)12 * 262144);
    const int WEL = 262144;
    unsigned short *wt_h[11], *wt_l[11], *wn_h[11];
    for (int i = 0; i < 11; ++i) { wt_h[i] = allocU(WEL); wt_l[i] = allocU(WEL); wn_h[i] = nullptr; }
    for (int i = 8; i < 11; ++i) wn_h[i] = allocU(WEL);          // natural hi: mWh0, mWh1, mWout
    unsigned short *nWinT_h = allocU(WEL), *nWinT_l = allocU(WEL);
    unsigned short *nWh0T_h = allocU(WEL), *nWh0T_l = allocU(WEL);
    unsigned short *nWh1T_h = allocU(WEL), *nWh1T_l = allocU(WEL);
    unsigned short *nWoutT_h = allocU(WEL), *nWoutT_l = allocU(WEL);
    float *gWin = allocF(WEL), *gWh0 = allocF(WEL), *gWh1 = allocF(WEL), *gWout = allocF(WEL);
    float *gbin = allocF(512), *gbh0 = allocF(512), *gbh1 = allocF(512), *gbout = allocF(512);
    float *nbin = allocF(512), *nbh0 = allocF(512), *nbh1 = allocF(512), *nbout = allocF(512);
    float *lr_t = allocF(Rr), *fg_t = allocF(Rr), *mo_t = allocF(Rr);
    float *scal = allocF(8);
    float *cpart = allocF(64 * 512);
    unsigned short *gA_h = vb_h, *gA_l = vb_l;
    unsigned short *gB_h = xm_h, *gB_l = xm_l;
    // SWA partial overlays (regions dead by Phase F):
    float* po  = (float*)qb_h;      // 4*16*2112*64 floats = 34.6 MB = qb..h0 block
    float* pml = (float*)h1_h;      // 4*16*2112*2 floats

    TriSet none{};
    const dim3 GG(66, 8);

    // ---- weight conversion ----
    WC wc{};
    const float* wlist[11] = { q_w, k_w, v_w, swa_wq, swa_wk, swa_wv, swa_wo,
                               mWin, mWh, mWh + WEL, mWout };
    for (int i = 0; i < 11; ++i) { wc.w[i] = wlist[i]; wc.th[i] = wt_h[i]; wc.tl[i] = wt_l[i]; wc.nh[i] = wn_h[i]; }
    k_wconv<<<dim3(256, 11), 256, 0, stream>>>(wc);

    // ---- Phase A ----
    k_build_xm<<<(Rr * 128 + 255) / 256, 256, 0, stream>>>(x, meta, xm_h, xm_l);
    k_gates<<<Rr / 4, 256, 0, stream>>>(xm_h, xm_l, lr_w, lr_b, fg_w, fg_b, mo_w, mo_b, lr_t, fg_t, mo_t);
    k_gate_means<<<1, 256, 0, stream>>>(lr_t, fg_t, mo_t, scal);

    TriSet qkvA{{ { wt_h[0], wt_l[0], q_b, f0 }, { wt_h[1], wt_l[1], k_b, f1 }, { wt_h[2], wt_l[2], v_b, f2 } }};
    k_mm<0, 0, false, 0, true, 3, false><<<dim3(66, 8, 3), 256, 0, stream>>>(
        xm_h, xm_l, nullptr, nullptr, nullptr, nullptr, nullptr, nullptr, nullptr, nullptr,
        nullptr, nullptr, qkvA, Rr, Dd, Dd, 0);
    k_conv3<<<dim3(Rr, 3), 256, 0, stream>>>(f0, f1, f2, q_c, k_c, v_c,
                                             qb_h, qb_l, kb_h, kb_l, vb_h, vb_l);

    // ---- Phase B: memory-MLP forward (plain bf16; theta-damped path) ----
    k_mm<0, 0, false, 5, false, 1, false><<<GG, 256, 0, stream>>>(
        kb_h, nullptr, wt_h[7], nullptr, f0, mbin, nullptr, nullptr, nullptr, nullptr,
        h0_h, h0_l, none, Rr, Dd, Dd, 0);                               // z0=f0, h0
    k_mm<0, 0, false, 6, false, 1, false><<<GG, 256, 0, stream>>>(
        h0_h, nullptr, wt_h[8], nullptr, f1, mbh, nullptr, h0_h, h0_l, nullptr,
        h1_h, h1_l, none, Rr, Dd, Dd, 0);                               // a0=f1, h1
    k_mm<0, 0, false, 6, false, 1, false><<<GG, 256, 0, stream>>>(
        h1_h, nullptr, wt_h[9], nullptr, f2, mbh + 512, nullptr, h1_h, h1_l, nullptr,
        h2_h, h2_l, none, Rr, Dd, Dd, 0);                               // a1=f2, h2
    k_mm<0, 0, false, 3, false, 1, false><<<GG, 256, 0, stream>>>(
        h2_h, nullptr, wt_h[10], nullptr, nullptr, mbout, nullptr, vb_h, vb_l, lr_t,
        g1_h, g1_l, none, Rr, Dd, Dd, 0);                               // g1 = dpred

    // ---- Phase C: backward ----
    auto GRADW = [&](const unsigned short* ah, const unsigned short* bh, float* gout) {
        k_mm<1, 1, true, 0, false, 1, false><<<dim3(8, 8, 11), 256, 0, stream>>>(
            ah, nullptr, bh, nullptr, parts, nullptr, nullptr, nullptr, nullptr, nullptr,
            nullptr, nullptr, none, Dd, Dd, Rr, 0);
        k_reduce_splitk<<<1024, 256, 0, stream>>>(parts, gout, WEL, 11, 1.0f / NCc);
    };
    auto COLSUM = [&](const unsigned short* gh, const unsigned short* gl, float* bo) {
        k_colsum<<<dim3(2, 64), 256, 0, stream>>>(gh, gl, cpart);
        k_colsum_reduce<<<2, 256, 0, stream>>>(cpart, bo, 1.0f / NCc);
    };
    GRADW(h2_h, g1_h, gWout);  COLSUM(g1_h, g1_l, gbout);
    k_mm<0, 0, false, 4, false, 1, false><<<GG, 256, 0, stream>>>(
        g1_h, nullptr, wn_h[10], nullptr, f3, nullptr, f2, nullptr, nullptr, nullptr,
        gA_h, gA_l, none, Rr, Dd, Dd, 0);                               // f3=dh2, gA=da1
    GRADW(h1_h, gA_h, gWh1);   COLSUM(gA_h, gA_l, gbh1);
    k_mm<0, 0, false, 4, false, 1, false><<<GG, 256, 0, stream>>>(
        gA_h, nullptr, wn_h[9], nullptr, f3, nullptr, f1, nullptr, nullptr, nullptr,
        gB_h, gB_l, none, Rr, Dd, Dd, 1);                               // f3=dh1, gB=da0
    GRADW(h0_h, gB_h, gWh0);   COLSUM(gB_h, gB_l, gbh0);
    k_mm<0, 0, false, 4, false, 1, false><<<GG, 256, 0, stream>>>(
        gB_h, nullptr, wn_h[8], nullptr, f3, nullptr, f0, nullptr, nullptr, nullptr,
        gA_h, gA_l, none, Rr, Dd, Dd, 1);                               // gA=dz0
    GRADW(kb_h, gA_h, gWin);   COLSUM(gA_h, gA_l, gbin);

    // ---- Phase D: updates ----
    UpdW4 uw{ { mWin, mWh, mWh + WEL, mWout },
              { momWin, momWh, momWh + WEL, momWout },
              { gWin, gWh0, gWh1, gWout },
              { nWinT_h, nWh0T_h, nWh1T_h, nWoutT_h },
              { nWinT_l, nWh0T_l, nWh1T_l, nWoutT_l } };
    k_updW<<<dim3(256, 4), 256, 0, stream>>>(uw, scal);
    UpdB4 ub{ { mbin, mbh, mbh + 512, mbout },
              { mombin, mombh, mombh + 512, mombout },
              { gbin, gbh0, gbh1, gbout },
              { nbin, nbh0, nbh1, nbout } };
    k_updB<<<8, 256, 0, stream>>>(ub, scal);

    // ---- Phase E: retrieval MLP on q (bf16x2 split) ----
    k_mm<0, 0, false, 1, false, 3, false><<<GG, 256, 0, stream>>>(
        qb_h, qb_l, nWinT_h, nWinT_l, nullptr, nbin, nullptr, nullptr, nullptr, nullptr,
        g1_h, g1_l, none, Rr, Dd, Dd, 0);                               // e0 -> g1
    k_mm<0, 0, false, 2, false, 3, false><<<GG, 256, 0, stream>>>(
        g1_h, g1_l, nWh0T_h, nWh0T_l, nullptr, nbh0, nullptr, g1_h, g1_l, nullptr,
        h0_h, h0_l, none, Rr, Dd, Dd, 0);                               // e1 -> h0
    k_mm<0, 0, false, 2, false, 3, false><<<GG, 256, 0, stream>>>(
        h0_h, h0_l, nWh1T_h, nWh1T_l, nullptr, nbh1, nullptr, h0_h, h0_l, nullptr,
        h1_h, h1_l, none, Rr, Dd, Dd, 0);                               // e2 -> h1
    k_mm<0, 0, false, 1, false, 3, false><<<GG, 256, 0, stream>>>(
        h1_h, h1_l, nWoutT_h, nWoutT_l, nullptr, nbout, nullptr, nullptr, nullptr, nullptr,
        h2_h, h2_l, none, Rr, Dd, Dd, 0);                               // retrieved -> h2

    // ---- Phase F: SWA qkv (fp32 out), attention, fused out-proj+slice ----
    TriSet qkvF{{ { wt_h[3], wt_l[3], swa_bq, f0 }, { wt_h[4], wt_l[4], swa_bk, f1 },
                  { wt_h[5], wt_l[5], swa_bv, f2 } }};
    k_mm<0, 0, false, 0, true, 3, false><<<dim3(66, 8, 3), 256, 0, stream>>>(
        h2_h, h2_l, nullptr, nullptr, nullptr, nullptr, nullptr, nullptr, nullptr, nullptr,
        nullptr, nullptr, qkvF, Rr, Dd, Dd, 0);
    k_swa_part<<<dim3(Nn / 32, Bb * NHh, 4), 64, 0, stream>>>(f0, f1, f2, po, pml);
    k_swa_merge<<<dim3(Nn / 64, Bb * NHh), 256, 0, stream>>>(po, pml, f3);
    k_mm<0, 0, false, 7, false, 3, true><<<GG, 256, 0, stream>>>(
        f3, nullptr, wt_h[6], wt_l[6], (float*)d_out, swa_bo, nullptr, nullptr, nullptr, nullptr,
        nullptr, nullptr, none, Rr, Dd, Dd, 0);
}

// Round 6
// 696.502 us; speedup vs baseline: 3.9420x; 1.2083x over previous
//
#include <hip/hip_runtime.h>
#include <cmath>

// ---------------------------------------------------------------------------
// NeuralMemory R6: fused MFMA flash SWA (bf16x2-split QK^T and PV, online
// softmax, P via LDS C->A layout round-trip). GEMM stack unchanged from R5.
// ---------------------------------------------------------------------------

namespace {

constexpr int Bb   = 2;
constexpr int Ss   = 2048;
constexpr int Dd   = 512;
constexpr int Mm   = 64;
constexpr int NCc  = 16;
constexpr int NHh  = 8;
constexpr int HD   = 64;
constexpr int WINw = 256;
constexpr int Nn   = Mm + Ss;    // 2112
constexpr int Rr   = Bb * Nn;    // 4224
constexpr int NBD  = Rr * Dd;
constexpr float MAXLR = 0.1f;

typedef __attribute__((ext_vector_type(8))) short short8;
typedef __attribute__((ext_vector_type(4))) float f32x4;

__device__ __forceinline__ float sigf(float x)  { return 1.0f / (1.0f + __expf(-x)); }
__device__ __forceinline__ float siluf(float x) { return x * sigf(x); }
__device__ __forceinline__ float dsiluf(float x){ float s = sigf(x); return s * (1.0f + x * (1.0f - s)); }
__device__ __forceinline__ unsigned short f2bf(float f) {
    unsigned int u = __float_as_uint(f);
    u = (u + 0x7FFFu + ((u >> 16) & 1u)) >> 16;
    return (unsigned short)u;
}
__device__ __forceinline__ float bf2f(unsigned short h) {
    return __uint_as_float(((unsigned int)h) << 16);
}

// ---- build xm (hi/lo bf16) ------------------------------------------------
__global__ void k_build_xm(const float* __restrict__ x, const float* __restrict__ meta,
                           unsigned short* __restrict__ xh, unsigned short* __restrict__ xl) {
    int i = blockIdx.x * 256 + threadIdx.x;      // float4 units
    if (i >= Rr * 128) return;
    int c = i & 127, r = i >> 7;
    int b = r / Nn, t = r - b * Nn;
    float4 v = (t < Mm) ? ((const float4*)meta)[t * 128 + c]
                        : ((const float4*)x)[(size_t)(b * Ss + (t - Mm)) * 128 + c];
    float vv[4] = { v.x, v.y, v.z, v.w };
    unsigned short h[4], l[4];
    #pragma unroll
    for (int e = 0; e < 4; ++e) { h[e] = f2bf(vv[e]); l[e] = f2bf(vv[e] - bf2f(h[e])); }
    *(ushort4*)(xh + (size_t)i * 4) = *(ushort4*)h;
    *(ushort4*)(xl + (size_t)i * 4) = *(ushort4*)l;
}

// ---- per-row scalar gates -------------------------------------------------
__global__ void k_gates(const unsigned short* __restrict__ xh, const unsigned short* __restrict__ xl,
                        const float* __restrict__ lw, const float* __restrict__ lb,
                        const float* __restrict__ fw, const float* __restrict__ fb,
                        const float* __restrict__ mw, const float* __restrict__ mb,
                        float* __restrict__ lr_t, float* __restrict__ fg_t, float* __restrict__ mo_t) {
    int r = blockIdx.x * 4 + (threadIdx.x >> 6);
    int lane = threadIdx.x & 63;
    if (r >= Rr) return;
    float s0 = 0.f, s1 = 0.f, s2 = 0.f;
    for (int j = lane; j < Dd; j += 64) {
        size_t o = (size_t)r * Dd + j;
        float v = bf2f(xh[o]) + bf2f(xl[o]);
        s0 += v * lw[j]; s1 += v * fw[j]; s2 += v * mw[j];
    }
    #pragma unroll
    for (int off = 32; off; off >>= 1) {
        s0 += __shfl_down(s0, off, 64);
        s1 += __shfl_down(s1, off, 64);
        s2 += __shfl_down(s2, off, 64);
    }
    if (lane == 0) {
        lr_t[r] = MAXLR * sigf(s0 + lb[0]);
        fg_t[r] = sigf(s1 + fb[0]);
        mo_t[r] = sigf(s2 + mb[0]);
    }
}

__global__ void k_gate_means(const float* __restrict__ lr_t, const float* __restrict__ fg_t,
                             const float* __restrict__ mo_t, float* __restrict__ scal) {
    __shared__ float red[256];
    const float* ptrs[3] = { fg_t, lr_t, mo_t };
    for (int w = 0; w < 3; ++w) {
        float acc = 0.f;
        for (int i = threadIdx.x; i < Rr; i += 256) acc += ptrs[w][i];
        red[threadIdx.x] = acc; __syncthreads();
        for (int off = 128; off; off >>= 1) {
            if (threadIdx.x < off) red[threadIdx.x] += red[threadIdx.x + off];
            __syncthreads();
        }
        if (threadIdx.x == 0) scal[w] = red[0] / (float)Rr;
        __syncthreads();
    }
}

// ---- weight convert: fp32 W[r][c] -> WT hi/lo [c][r]; optional natural hi --
struct WC { const float* w[11]; unsigned short* th[11]; unsigned short* tl[11]; unsigned short* nh[11]; };
__global__ void k_wconv(WC wc) {
    int seg = blockIdx.y;
    int i0 = blockIdx.x * 1024 + threadIdx.x * 4;
    float4 v4 = *(const float4*)(wc.w[seg] + i0);
    float vals[4] = { v4.x, v4.y, v4.z, v4.w };
    int r = i0 >> 9, c = i0 & 511;
    #pragma unroll
    for (int e = 0; e < 4; ++e) {
        unsigned short h = f2bf(vals[e]);
        unsigned short l = f2bf(vals[e] - bf2f(h));
        wc.th[seg][(size_t)(c + e) * 512 + r] = h;
        wc.tl[seg][(size_t)(c + e) * 512 + r] = l;
        if (wc.nh[seg]) wc.nh[seg][i0 + e] = h;
    }
}

// ---- MFMA GEMM: 64x64 tile, BK=64, 256 thr (4 waves, each 32x32) ----------
struct TriW { const unsigned short* bh; const unsigned short* bl; const float* bias; float* c; };
struct TriSet { TriW t[3]; };

template<int TA, int TB, bool SPLITK, int EPI, bool MULTI, int NS, bool AF32>
__global__ __launch_bounds__(256) void k_mm(
        const void* Ap, const unsigned short* Al_,
        const unsigned short* Bh_, const unsigned short* Bl_,
        float* C, const float* bias, const float* __restrict__ exf,
        const unsigned short* __restrict__ exh, const unsigned short* __restrict__ exl,
        const float* __restrict__ lrp,
        unsigned short* oh, unsigned short* ol, TriSet ts,
        int Md, int Nd, int Kd, int accum) {
    constexpr int SMEMB = (NS == 3) ? 32768 : 16384;
    __shared__ char smem[SMEMB];
    unsigned short* AH = (unsigned short*)smem;
    unsigned short* AL = AH + 4096;
    unsigned short* BH = AH + ((NS == 3) ? 8192 : 4096);
    unsigned short* BL = BH + 4096;
    const int tid = threadIdx.x;
    const int m0 = blockIdx.x * 64, n0 = blockIdx.y * 64;
    if constexpr (MULTI) {
        const TriW& tw = ts.t[blockIdx.z];
        Bh_ = tw.bh; Bl_ = tw.bl; bias = tw.bias; C = tw.c;
    }
    int kbg = 0, ke = Kd;
    if constexpr (SPLITK) {
        int kc = Kd / gridDim.z;
        kbg = blockIdx.z * kc; ke = kbg + kc;
        C += (size_t)blockIdx.z * Md * Nd;
    }
    const int astr = (TA == 0) ? Kd : Md;

    f32x4 acc[2][2];
    #pragma unroll
    for (int i = 0; i < 2; ++i)
        #pragma unroll
        for (int j = 0; j < 2; ++j)
            #pragma unroll
            for (int v = 0; v < 4; ++v) acc[i][j][v] = 0.f;

    short8 pA0, pA1, pAl0, pAl1, pB0, pB1, pBl0, pBl1;
    float4 pAf[4];

    auto gload = [&](int k0) {
        if constexpr (TA == 0) {
            int r = tid >> 2, ks2 = (tid & 3) * 16;
            if constexpr (AF32) {
                const float* ap = (const float*)Ap + (size_t)(m0 + r) * astr + k0 + ks2;
                pAf[0] = *(const float4*)ap;       pAf[1] = *(const float4*)(ap + 4);
                pAf[2] = *(const float4*)(ap + 8); pAf[3] = *(const float4*)(ap + 12);
            } else {
                const unsigned short* ah = (const unsigned short*)Ap + (size_t)(m0 + r) * astr + k0 + ks2;
                pA0 = *(const short8*)ah; pA1 = *(const short8*)(ah + 8);
                if constexpr (NS == 3) {
                    const unsigned short* al = Al_ + (size_t)(m0 + r) * astr + k0 + ks2;
                    pAl0 = *(const short8*)al; pAl1 = *(const short8*)(al + 8);
                }
            }
        } else {
            int kr = tid >> 2, ms = (tid & 3) * 16;
            const unsigned short* ah = (const unsigned short*)Ap + (size_t)(k0 + kr) * astr + m0 + ms;
            pA0 = *(const short8*)ah; pA1 = *(const short8*)(ah + 8);
            if constexpr (NS == 3) {
                const unsigned short* al = Al_ + (size_t)(k0 + kr) * astr + m0 + ms;
                pAl0 = *(const short8*)al; pAl1 = *(const short8*)(al + 8);
            }
        }
        if constexpr (TB == 0) {
            int nr = tid >> 2, ks2 = (tid & 3) * 16;
            const unsigned short* bh = Bh_ + (size_t)(n0 + nr) * Kd + k0 + ks2;
            pB0 = *(const short8*)bh; pB1 = *(const short8*)(bh + 8);
            if constexpr (NS == 3) {
                const unsigned short* bl = Bl_ + (size_t)(n0 + nr) * Kd + k0 + ks2;
                pBl0 = *(const short8*)bl; pBl1 = *(const short8*)(bl + 8);
            }
        } else {
            int kr = tid >> 2, nseg = (tid & 3) * 16;
            const unsigned short* bh = Bh_ + (size_t)(k0 + kr) * Nd + n0 + nseg;
            pB0 = *(const short8*)bh; pB1 = *(const short8*)(bh + 8);
            if constexpr (NS == 3) {
                const unsigned short* bl = Bl_ + (size_t)(k0 + kr) * Nd + n0 + nseg;
                pBl0 = *(const short8*)bl; pBl1 = *(const short8*)(bl + 8);
            }
        }
    };
    auto lstore = [&]() {
        if constexpr (TA == 0) {
            int r = tid >> 2, ks2 = (tid & 3) * 16;
            int f = r >> 4, rr = r & 15, kf = ks2 >> 5, q = (ks2 >> 3) & 3;
            int base = (((f * 2 + kf) * 4 + q) * 16 + rr) * 8;
            if constexpr (AF32) {
                unsigned short hh[16], ll[16];
                const float* pf = (const float*)pAf;
                #pragma unroll
                for (int e = 0; e < 16; ++e) { hh[e] = f2bf(pf[e]); ll[e] = f2bf(pf[e] - bf2f(hh[e])); }
                *(short8*)(AH + base) = *(short8*)hh;  *(short8*)(AH + base + 128) = *(short8*)(hh + 8);
                *(short8*)(AL + base) = *(short8*)ll;  *(short8*)(AL + base + 128) = *(short8*)(ll + 8);
            } else {
                *(short8*)(AH + base) = pA0; *(short8*)(AH + base + 128) = pA1;
                if constexpr (NS == 3) { *(short8*)(AL + base) = pAl0; *(short8*)(AL + base + 128) = pAl1; }
            }
        } else {
            int kr = tid >> 2, ms = (tid & 3) * 16;
            int f = ms >> 4, kf = kr >> 5, q = (kr >> 3) & 3, kk = kr & 7;
            int F = (f * 2 + kf) * 4 + q;
            int g = f + (q & 1) * 4;               // bank-swizzle key
            unsigned short tmp[16];
            *(short8*)tmp = pA0; *(short8*)(tmp + 8) = pA1;
            #pragma unroll
            for (int e = 0; e < 16; ++e) AH[(((F << 4) | e) ^ g) * 8 + kk] = tmp[e];
            if constexpr (NS == 3) {
                *(short8*)tmp = pAl0; *(short8*)(tmp + 8) = pAl1;
                #pragma unroll
                for (int e = 0; e < 16; ++e) AL[(((F << 4) | e) ^ g) * 8 + kk] = tmp[e];
            }
        }
        if constexpr (TB == 0) {
            int nr = tid >> 2, ks2 = (tid & 3) * 16;
            int f = nr >> 4, rr = nr & 15, kf = ks2 >> 5, q = (ks2 >> 3) & 3;
            int base = (((f * 2 + kf) * 4 + q) * 16 + rr) * 8;
            *(short8*)(BH + base) = pB0; *(short8*)(BH + base + 128) = pB1;
            if constexpr (NS == 3) { *(short8*)(BL + base) = pBl0; *(short8*)(BL + base + 128) = pBl1; }
        } else {
            int kr = tid >> 2, nseg = (tid & 3) * 16;
            int f = nseg >> 4, kf = kr >> 5, q = (kr >> 3) & 3, kk = kr & 7;
            int F = (f * 2 + kf) * 4 + q;
            int g = f + (q & 1) * 4;
            unsigned short tmp[16];
            *(short8*)tmp = pB0; *(short8*)(tmp + 8) = pB1;
            #pragma unroll
            for (int e = 0; e < 16; ++e) BH[(((F << 4) | e) ^ g) * 8 + kk] = tmp[e];
            if constexpr (NS == 3) {
                *(short8*)tmp = pBl0; *(short8*)(tmp + 8) = pBl1;
                #pragma unroll
                for (int e = 0; e < 16; ++e) BL[(((F << 4) | e) ^ g) * 8 + kk] = tmp[e];
            }
        }
    };

    const int wv = tid >> 6, lr16 = tid & 15, lq = (tid >> 4) & 3;
    const int wm = wv & 1, wn = wv >> 1;

    gload(kbg); lstore();
    __syncthreads();
    for (int k0 = kbg; k0 < ke; k0 += 64) {
        bool more = (k0 + 64) < ke;
        if (more) gload(k0 + 64);
        #pragma unroll
        for (int kf = 0; kf < 2; ++kf) {
            short8 fa[2], fal[2], fb[2], fbl[2];
            #pragma unroll
            for (int i = 0; i < 2; ++i) {
                int fA = wm * 2 + i;
                int u = ((fA * 2 + kf) * 4 + lq) * 16 + lr16;
                if constexpr (TA == 1) u ^= fA + (lq & 1) * 4;
                fa[i] = *(const short8*)(AH + u * 8);
                if constexpr (NS == 3) fal[i] = *(const short8*)(AL + u * 8);
            }
            #pragma unroll
            for (int j = 0; j < 2; ++j) {
                int fB = wn * 2 + j;
                int u = ((fB * 2 + kf) * 4 + lq) * 16 + lr16;
                if constexpr (TB == 1) u ^= fB + (lq & 1) * 4;
                fb[j] = *(const short8*)(BH + u * 8);
                if constexpr (NS == 3) fbl[j] = *(const short8*)(BL + u * 8);
            }
            #pragma unroll
            for (int i = 0; i < 2; ++i)
                #pragma unroll
                for (int j = 0; j < 2; ++j) {
                    acc[i][j] = __builtin_amdgcn_mfma_f32_16x16x32_bf16(fa[i], fb[j], acc[i][j], 0, 0, 0);
                    if constexpr (NS == 3) {
                        acc[i][j] = __builtin_amdgcn_mfma_f32_16x16x32_bf16(fa[i], fbl[j], acc[i][j], 0, 0, 0);
                        acc[i][j] = __builtin_amdgcn_mfma_f32_16x16x32_bf16(fal[i], fb[j], acc[i][j], 0, 0, 0);
                    }
                }
        }
        if (more) { __syncthreads(); lstore(); __syncthreads(); }
    }
    __syncthreads();

    // ---- epilogue: acc -> swizzled LDS fp32 -> row-major per-thread ----
    float* EP = (float*)smem;
    #pragma unroll
    for (int i = 0; i < 2; ++i)
        #pragma unroll
        for (int j = 0; j < 2; ++j)
            #pragma unroll
            for (int v = 0; v < 4; ++v) {
                int row = wm * 32 + i * 16 + lq * 4 + v;
                int col = wn * 32 + j * 16 + lr16;
                int u = col >> 2, up = u ^ (row & 15);
                EP[row * 64 + up * 4 + (col & 3)] = acc[i][j][v];
            }
    __syncthreads();
    int r = tid >> 2, cg = tid & 3;
    float vv[16];
    #pragma unroll
    for (int uu = 0; uu < 4; ++uu) {
        int u = cg * 4 + uu;
        *(float4*)&vv[uu * 4] = *(const float4*)&EP[r * 64 + ((u ^ (r & 15)) * 4)];
    }
    int m = m0 + r, nb = n0 + cg * 16;
    size_t idx = (size_t)m * Nd + nb;

    if constexpr (SPLITK) {
        #pragma unroll
        for (int uu = 0; uu < 4; ++uu) *(float4*)(C + idx + uu * 4) = *(float4*)&vv[uu * 4];
        return;
    }
    if (bias) {
        #pragma unroll
        for (int uu = 0; uu < 4; ++uu) {
            float4 b4 = *(const float4*)(bias + nb + uu * 4);
            vv[uu * 4 + 0] += b4.x; vv[uu * 4 + 1] += b4.y;
            vv[uu * 4 + 2] += b4.z; vv[uu * 4 + 3] += b4.w;
        }
    }
    unsigned short eh8[16], el8[16];
    if constexpr (EPI == 2 || EPI == 3 || EPI == 6) {
        #pragma unroll
        for (int k4 = 0; k4 < 2; ++k4) {
            *(short8*)&eh8[k4 * 8] = *(const short8*)(exh + idx + k4 * 8);
            *(short8*)&el8[k4 * 8] = *(const short8*)(exl + idx + k4 * 8);
        }
    }
    auto store_hl = [&](const float* s) {
        unsigned short hb[16], lb2[16];
        #pragma unroll
        for (int e = 0; e < 16; ++e) { hb[e] = f2bf(s[e]); lb2[e] = f2bf(s[e] - bf2f(hb[e])); }
        #pragma unroll
        for (int k4 = 0; k4 < 2; ++k4) {
            *(short8*)(oh + idx + k4 * 8) = *(short8*)&hb[k4 * 8];
            *(short8*)(ol + idx + k4 * 8) = *(short8*)&lb2[k4 * 8];
        }
    };
    auto accum_add = [&]() {
        #pragma unroll
        for (int uu = 0; uu < 4; ++uu) {
            float4 o4 = *(const float4*)(C + idx + uu * 4);
            vv[uu * 4 + 0] += o4.x; vv[uu * 4 + 1] += o4.y;
            vv[uu * 4 + 2] += o4.z; vv[uu * 4 + 3] += o4.w;
        }
    };
    auto store_f = [&]() {
        #pragma unroll
        for (int uu = 0; uu < 4; ++uu) *(float4*)(C + idx + uu * 4) = *(float4*)&vv[uu * 4];
    };
    if constexpr (EPI == 0) {
        if (accum) accum_add();
        store_f();
    } else if constexpr (EPI == 1) {
        float s[16];
        #pragma unroll
        for (int e = 0; e < 16; ++e) s[e] = siluf(vv[e]);
        store_hl(s);
    } else if constexpr (EPI == 2) {
        float s[16];
        #pragma unroll
        for (int e = 0; e < 16; ++e) s[e] = bf2f(eh8[e]) + bf2f(el8[e]) + siluf(vv[e]);
        store_hl(s);
    } else if constexpr (EPI == 3) {
        float sc = (2.0f / 512.0f) * lrp[m];
        float s[16];
        #pragma unroll
        for (int e = 0; e < 16; ++e) s[e] = sc * (vv[e] - (bf2f(eh8[e]) + bf2f(el8[e])));
        store_hl(s);
    } else if constexpr (EPI == 4) {
        if (accum) accum_add();
        store_f();
        float s[16];
        #pragma unroll
        for (int e = 0; e < 16; ++e) s[e] = vv[e] * dsiluf(exf[idx + e]);
        store_hl(s);
    } else if constexpr (EPI == 5) {
        store_f();
        float s[16];
        #pragma unroll
        for (int e = 0; e < 16; ++e) s[e] = siluf(vv[e]);
        store_hl(s);
    } else if constexpr (EPI == 6) {
        store_f();
        float s[16];
        #pragma unroll
        for (int e = 0; e < 16; ++e) s[e] = bf2f(eh8[e]) + bf2f(el8[e]) + siluf(vv[e]);
        store_hl(s);
    } else if constexpr (EPI == 7) {
        int b2 = m / Nn, t2 = m - b2 * Nn;
        if (t2 >= Mm) {
            float* dst = C + (size_t)(b2 * Ss + (t2 - Mm)) * Nd + nb;
            #pragma unroll
            for (int uu = 0; uu < 4; ++uu) *(float4*)(dst + uu * 4) = *(float4*)&vv[uu * 4];
        }
    }
}

__global__ void k_reduce_splitk(const float* __restrict__ part, float* __restrict__ out,
                                int n, int z, float alpha) {
    int i = blockIdx.x * 256 + threadIdx.x;
    if (i >= n) return;
    float s = 0.f;
    for (int zz = 0; zz < z; ++zz) s += part[(size_t)zz * n + i];
    out[i] = alpha * s;
}

// ---- causal depthwise conv K=4 + SiLU (+L2n for q,k); fp32 in, hi/lo out --
__global__ __launch_bounds__(256) void k_conv3(
        const float* __restrict__ yq, const float* __restrict__ yk, const float* __restrict__ yv,
        const float* __restrict__ cq, const float* __restrict__ ck, const float* __restrict__ cv,
        unsigned short* oqh, unsigned short* oql, unsigned short* okh, unsigned short* okl,
        unsigned short* ovh, unsigned short* ovl) {
    int which = blockIdx.y;
    const float* y  = which == 0 ? yq : which == 1 ? yk : yv;
    const float* cw = which == 0 ? cq : which == 1 ? ck : cv;
    unsigned short* oh = which == 0 ? oqh : which == 1 ? okh : ovh;
    unsigned short* ol = which == 0 ? oql : which == 1 ? okl : ovl;
    bool norm = which < 2;
    int r = blockIdx.x;
    int b = r / Nn, t = r - b * Nn;
    const size_t rowbase = (size_t)r * Dd;
    float s[2];
    #pragma unroll
    for (int u = 0; u < 2; ++u) {
        int d = threadIdx.x + u * 256;
        float acc = 0.f;
        #pragma unroll
        for (int k = 0; k < 4; ++k) {
            int tt = t - 3 + k;
            if (tt >= 0) acc += y[(size_t)(b * Nn + tt) * Dd + d] * cw[d * 4 + k];
        }
        s[u] = siluf(acc);
    }
    float denom = 1.0f;
    if (norm) {
        __shared__ float wr[4];
        float v2 = s[0] * s[0] + s[1] * s[1];
        #pragma unroll
        for (int off = 32; off; off >>= 1) v2 += __shfl_xor(v2, off, 64);
        if ((threadIdx.x & 63) == 0) wr[threadIdx.x >> 6] = v2;
        __syncthreads();
        denom = fmaxf(sqrtf(wr[0] + wr[1] + wr[2] + wr[3]), 1e-12f);
    }
    #pragma unroll
    for (int u = 0; u < 2; ++u) {
        float v = s[u] / denom;
        unsigned short h = f2bf(v);
        oh[rowbase + threadIdx.x + u * 256] = h;
        ol[rowbase + threadIdx.x + u * 256] = f2bf(v - bf2f(h));
    }
}

// ---- column sums for bias grads (hi/lo input) -----------------------------
__global__ void k_colsum(const unsigned short* __restrict__ gh, const unsigned short* __restrict__ gl,
                         float* __restrict__ part) {
    int col = blockIdx.x * 256 + threadIdx.x;
    int chunk = blockIdx.y;
    int r0 = chunk * (Rr / 64);
    float s = 0.f;
    for (int r = r0; r < r0 + Rr / 64; ++r) {
        size_t o = (size_t)r * Dd + col;
        s += bf2f(gh[o]) + bf2f(gl[o]);
    }
    part[chunk * Dd + col] = s;
}
__global__ void k_colsum_reduce(const float* __restrict__ part, float* __restrict__ out, float alpha) {
    int col = blockIdx.x * 256 + threadIdx.x;
    if (col >= Dd) return;
    float s = 0.f;
    for (int c = 0; c < 64; ++c) s += part[c * Dd + col];
    out[col] = alpha * s;
}

// ---- parameter updates ----------------------------------------------------
struct UpdW4 { const float* p[4]; const float* mo[4]; const float* g[4];
               unsigned short* th[4]; unsigned short* tl[4]; };
__global__ void k_updW(UpdW4 u, const float* __restrict__ scal) {
    int seg = blockIdx.y;
    int i0 = blockIdx.x * 1024 + threadIdx.x * 4;
    float4 p4 = *(const float4*)(u.p[seg] + i0);
    float4 m4 = *(const float4*)(u.mo[seg] + i0);
    float4 g4 = *(const float4*)(u.g[seg] + i0);
    float a = 1.0f - scal[0], et = scal[2], th = scal[1];
    float vals[4] = { p4.x * a + et * m4.x - th * g4.x, p4.y * a + et * m4.y - th * g4.y,
                      p4.z * a + et * m4.z - th * g4.z, p4.w * a + et * m4.w - th * g4.w };
    int r = i0 >> 9, c = i0 & 511;
    #pragma unroll
    for (int e = 0; e < 4; ++e) {
        unsigned short h = f2bf(vals[e]);
        u.th[seg][(size_t)(c + e) * 512 + r] = h;
        u.tl[seg][(size_t)(c + e) * 512 + r] = f2bf(vals[e] - bf2f(h));
    }
}
struct UpdB4 { const float* p[4]; const float* mo[4]; const float* g[4]; float* o[4]; };
__global__ void k_updB(UpdB4 u, const float* __restrict__ scal) {
    int seg = blockIdx.x >> 1;
    int i = (blockIdx.x & 1) * 256 + threadIdx.x;
    u.o[seg][i] = u.p[seg][i] * (1.0f - scal[0]) + scal[2] * u.mo[seg][i] - scal[1] * u.g[seg][i];
}

// ---- fused MFMA flash SWA -------------------------------------------------
// Block: 64 queries x one (b,h); 4 waves x 16 queries. Per 32-key tile:
// S = Q K^T (bf16x2 split, 12 mfma), online softmax in C layout (quad-16
// shfl reduce), P -> per-wave LDS (C->A layout), PV (split, 12 mfma).
// Frag conventions identical to k_mm (A: m=lane&15,k=quad*8+j; C: row=
// quad*4+reg, col=lane&15).
__global__ __launch_bounds__(256) void k_swa(const float* __restrict__ qs,
                                             const float* __restrict__ ks,
                                             const float* __restrict__ vs,
                                             float* __restrict__ out) {
    __shared__ unsigned short KH[2048], KL[2048], VH[2048], VL[2048];
    __shared__ unsigned short PH[4][512], PL[4][512];
    const int tid = threadIdx.x;
    const int w = tid >> 6, lane = tid & 63;
    const int lq = lane >> 4, l16 = lane & 15;
    const int q0 = blockIdx.x * 64;
    const int bh = blockIdx.y;
    const int h = bh & 7, b = bh >> 3;
    const size_t srow = (size_t)(b * Nn) * Dd + h * HD;
    const int iq = q0 + w * 16 + l16;          // query for A-frag (m = l16)

    // Q A-frags hi/lo: k = kf*32 + lq*8 + j
    short8 qh[2], qlo[2];
    {
        const float* qr = qs + srow + (size_t)iq * Dd;
        #pragma unroll
        for (int kf = 0; kf < 2; ++kf) {
            float t8[8];
            *(float4*)&t8[0] = *(const float4*)(qr + kf * 32 + lq * 8);
            *(float4*)&t8[4] = *(const float4*)(qr + kf * 32 + lq * 8 + 4);
            unsigned short hh[8], ll[8];
            #pragma unroll
            for (int e = 0; e < 8; ++e) { hh[e] = f2bf(t8[e]); ll[e] = f2bf(t8[e] - bf2f(hh[e])); }
            qh[kf] = *(short8*)hh; qlo[kf] = *(short8*)ll;
        }
    }

    f32x4 o[4];
    #pragma unroll
    for (int nf = 0; nf < 4; ++nf)
        #pragma unroll
        for (int v = 0; v < 4; ++v) o[nf][v] = 0.f;
    float mrun[4] = { -1e30f, -1e30f, -1e30f, -1e30f };
    float lrun[4] = { 0.f, 0.f, 0.f, 0.f };
    const int iw = q0 + w * 16 + lq * 4;       // C-layout row base (i = iw + v)

    int jlo = q0 - (WINw - 1); if (jlo < 0) jlo = 0;
    jlo &= ~31;
    for (int jt = jlo; jt < q0 + 64; jt += 32) {
        __syncthreads();
        // stage K tile: B-frag [n=key(32)][k=dim(64)]
        {
            int nr = tid >> 3, ds8 = (tid & 7) * 8;
            const float* kr = ks + srow + (size_t)(jt + nr) * Dd + ds8;
            float t8[8];
            *(float4*)&t8[0] = *(const float4*)kr;
            *(float4*)&t8[4] = *(const float4*)(kr + 4);
            unsigned short hh[8], ll[8];
            #pragma unroll
            for (int e = 0; e < 8; ++e) { hh[e] = f2bf(t8[e]); ll[e] = f2bf(t8[e] - bf2f(hh[e])); }
            int f = nr >> 4, rr = nr & 15, kf = ds8 >> 5, q = (ds8 >> 3) & 3;
            int u = ((f * 2 + kf) * 4 + q) * 16 + rr;
            *(short8*)(KH + u * 8) = *(short8*)hh;
            *(short8*)(KL + u * 8) = *(short8*)ll;
        }
        // stage V^T tile: B-frag [n=dim(64)][k=key(32)] — coalesced loads
        {
            int d = tid & 63, kg = tid >> 6;
            unsigned short hh[8], ll[8];
            #pragma unroll
            for (int e = 0; e < 8; ++e) {
                float v = vs[srow + (size_t)(jt + kg * 8 + e) * Dd + d];
                hh[e] = f2bf(v); ll[e] = f2bf(v - bf2f(hh[e]));
            }
            int f = d >> 4, rr = d & 15;
            int u = (f * 4 + kg) * 16 + rr;
            *(short8*)(VH + u * 8) = *(short8*)hh;
            *(short8*)(VL + u * 8) = *(short8*)ll;
        }
        __syncthreads();

        // S = Q K^T (split)
        f32x4 s[2];
        #pragma unroll
        for (int nf = 0; nf < 2; ++nf) {
            #pragma unroll
            for (int v = 0; v < 4; ++v) s[nf][v] = 0.f;
            #pragma unroll
            for (int kf = 0; kf < 2; ++kf) {
                int u = ((nf * 2 + kf) * 4 + lq) * 16 + l16;
                short8 kbh = *(const short8*)(KH + u * 8);
                short8 kbl = *(const short8*)(KL + u * 8);
                s[nf] = __builtin_amdgcn_mfma_f32_16x16x32_bf16(qh[kf], kbh, s[nf], 0, 0, 0);
                s[nf] = __builtin_amdgcn_mfma_f32_16x16x32_bf16(qh[kf], kbl, s[nf], 0, 0, 0);
                s[nf] = __builtin_amdgcn_mfma_f32_16x16x32_bf16(qlo[kf], kbh, s[nf], 0, 0, 0);
            }
        }
        // mask + scale (1/sqrt(64)) + online softmax
        float mt[4];
        #pragma unroll
        for (int v = 0; v < 4; ++v) {
            int i = iw + v;
            int j0c = jt + l16, j1c = jt + 16 + l16;
            s[0][v] = ((j0c <= i) && (i - j0c < WINw)) ? s[0][v] * 0.125f : -1e30f;
            s[1][v] = ((j1c <= i) && (i - j1c < WINw)) ? s[1][v] * 0.125f : -1e30f;
            mt[v] = fmaxf(s[0][v], s[1][v]);
        }
        #pragma unroll
        for (int msk = 1; msk < 16; msk <<= 1)
            #pragma unroll
            for (int v = 0; v < 4; ++v) mt[v] = fmaxf(mt[v], __shfl_xor(mt[v], msk, 64));
        float rs[4];
        #pragma unroll
        for (int v = 0; v < 4; ++v) {
            float mnew = fmaxf(mrun[v], mt[v]);
            float corr = __expf(mrun[v] - mnew);
            mrun[v] = mnew;
            float p0 = (s[0][v] > -1e29f) ? __expf(s[0][v] - mnew) : 0.f;
            float p1 = (s[1][v] > -1e29f) ? __expf(s[1][v] - mnew) : 0.f;
            s[0][v] = p0; s[1][v] = p1;
            rs[v] = p0 + p1;
            lrun[v] *= corr;
            #pragma unroll
            for (int nf = 0; nf < 4; ++nf) o[nf][v] *= corr;
        }
        #pragma unroll
        for (int msk = 1; msk < 16; msk <<= 1)
            #pragma unroll
            for (int v = 0; v < 4; ++v) rs[v] += __shfl_xor(rs[v], msk, 64);
        #pragma unroll
        for (int v = 0; v < 4; ++v) lrun[v] += rs[v];

        // P: C layout -> per-wave A-frag LDS (hi/lo)
        #pragma unroll
        for (int nf = 0; nf < 2; ++nf)
            #pragma unroll
            for (int v = 0; v < 4; ++v) {
                float p = s[nf][v];
                unsigned short hh = f2bf(p);
                int addr = (lq * 4 + v) * 32 + nf * 16 + l16;
                PH[w][addr] = hh;
                PL[w][addr] = f2bf(p - bf2f(hh));
            }
        __syncthreads();
        short8 pah = *(const short8*)(&PH[w][l16 * 32 + lq * 8]);
        short8 pal = *(const short8*)(&PL[w][l16 * 32 + lq * 8]);
        #pragma unroll
        for (int nf = 0; nf < 4; ++nf) {
            int u = (nf * 4 + lq) * 16 + l16;
            short8 vth = *(const short8*)(VH + u * 8);
            short8 vtl = *(const short8*)(VL + u * 8);
            o[nf] = __builtin_amdgcn_mfma_f32_16x16x32_bf16(pah, vth, o[nf], 0, 0, 0);
            o[nf] = __builtin_amdgcn_mfma_f32_16x16x32_bf16(pah, vtl, o[nf], 0, 0, 0);
            o[nf] = __builtin_amdgcn_mfma_f32_16x16x32_bf16(pal, vth, o[nf], 0, 0, 0);
        }
    }
    float invl[4];
    #pragma unroll
    for (int v = 0; v < 4; ++v) invl[v] = 1.0f / lrun[v];
    #pragma unroll
    for (int nf = 0; nf < 4; ++nf)
        #pragma unroll
        for (int v = 0; v < 4; ++v)
            out[srow + (size_t)(iw + v) * Dd + nf * 16 + l16] = o[nf][v] * invl[v];
}

} // namespace

extern "C" void kernel_launch(void* const* d_in, const int* in_sizes, int n_in,
                              void* d_out, int out_size, void* d_ws, size_t ws_size,
                              hipStream_t stream) {
    const float* x       = (const float*)d_in[0];
    const float* meta    = (const float*)d_in[1];
    const float* mWin    = (const float*)d_in[2];
    const float* mbin    = (const float*)d_in[3];
    const float* mWh     = (const float*)d_in[4];
    const float* mbh     = (const float*)d_in[5];
    const float* mWout   = (const float*)d_in[6];
    const float* mbout   = (const float*)d_in[7];
    const float* momWin  = (const float*)d_in[8];
    const float* mombin  = (const float*)d_in[9];
    const float* momWh   = (const float*)d_in[10];
    const float* mombh   = (const float*)d_in[11];
    const float* momWout = (const float*)d_in[12];
    const float* mombout = (const float*)d_in[13];
    const float* q_w = (const float*)d_in[14]; const float* q_b = (const float*)d_in[15]; const float* q_c = (const float*)d_in[16];
    const float* k_w = (const float*)d_in[17]; const float* k_b = (const float*)d_in[18]; const float* k_c = (const float*)d_in[19];
    const float* v_w = (const float*)d_in[20]; const float* v_b = (const float*)d_in[21]; const float* v_c = (const float*)d_in[22];
    const float* lr_w = (const float*)d_in[23]; const float* lr_b = (const float*)d_in[24];
    const float* fg_w = (const float*)d_in[25]; const float* fg_b = (const float*)d_in[26];
    const float* mo_w = (const float*)d_in[27]; const float* mo_b = (const float*)d_in[28];
    const float* swa_wq = (const float*)d_in[29]; const float* swa_wk = (const float*)d_in[30];
    const float* swa_wv = (const float*)d_in[31]; const float* swa_wo = (const float*)d_in[32];
    const float* swa_bq = (const float*)d_in[33]; const float* swa_bk = (const float*)d_in[34];
    const float* swa_bv = (const float*)d_in[35]; const float* swa_bo = (const float*)d_in[36];
    (void)in_sizes; (void)n_in; (void)out_size; (void)ws_size;

    char* wsb = (char*)d_ws;
    size_t off = 0;
    auto allocB = [&](size_t bytes) { void* p = wsb + off; off = (off + bytes + 255) & ~(size_t)255; return p; };
    auto allocU = [&](size_t elems) { return (unsigned short*)allocB(elems * 2); };
    auto allocF = [&](size_t elems) { return (float*)allocB(elems * 4); };

    unsigned short *xm_h = allocU(NBD), *xm_l = allocU(NBD);     // reused as gB
    unsigned short *qb_h = allocU(NBD), *qb_l = allocU(NBD);
    unsigned short *kb_h = allocU(NBD), *kb_l = allocU(NBD);
    unsigned short *vb_h = allocU(NBD), *vb_l = allocU(NBD);     // reused as gA
    unsigned short *h0_h = allocU(NBD), *h0_l = allocU(NBD);
    unsigned short *h1_h = allocU(NBD), *h1_l = allocU(NBD);
    unsigned short *h2_h = allocU(NBD), *h2_l = allocU(NBD);
    unsigned short *g1_h = allocU(NBD), *g1_l = allocU(NBD);
    float *f0 = allocF(NBD), *f1 = allocF(NBD), *f2 = allocF(NBD), *f3 = allocF(NBD);
    float *parts = allocF((size_t)12 * 262144);
    const int WEL = 262144;
    unsigned short *wt_h[11], *wt_l[11], *wn_h[11];
    for (int i = 0; i < 11; ++i) { wt_h[i] = allocU(WEL); wt_l[i] = allocU(WEL); wn_h[i] = nullptr; }
    for (int i = 8; i < 11; ++i) wn_h[i] = allocU(WEL);          // natural hi: mWh0, mWh1, mWout
    unsigned short *nWinT_h = allocU(WEL), *nWinT_l = allocU(WEL);
    unsigned short *nWh0T_h = allocU(WEL), *nWh0T_l = allocU(WEL);
    unsigned short *nWh1T_h = allocU(WEL), *nWh1T_l = allocU(WEL);
    unsigned short *nWoutT_h = allocU(WEL), *nWoutT_l = allocU(WEL);
    float *gWin = allocF(WEL), *gWh0 = allocF(WEL), *gWh1 = allocF(WEL), *gWout = allocF(WEL);
    float *gbin = allocF(512), *gbh0 = allocF(512), *gbh1 = allocF(512), *gbout = allocF(512);
    float *nbin = allocF(512), *nbh0 = allocF(512), *nbh1 = allocF(512), *nbout = allocF(512);
    float *lr_t = allocF(Rr), *fg_t = allocF(Rr), *mo_t = allocF(Rr);
    float *scal = allocF(8);
    float *cpart = allocF(64 * 512);
    unsigned short *gA_h = vb_h, *gA_l = vb_l;
    unsigned short *gB_h = xm_h, *gB_l = xm_l;

    TriSet none{};
    const dim3 GG(66, 8);

    // ---- weight conversion ----
    WC wc{};
    const float* wlist[11] = { q_w, k_w, v_w, swa_wq, swa_wk, swa_wv, swa_wo,
                               mWin, mWh, mWh + WEL, mWout };
    for (int i = 0; i < 11; ++i) { wc.w[i] = wlist[i]; wc.th[i] = wt_h[i]; wc.tl[i] = wt_l[i]; wc.nh[i] = wn_h[i]; }
    k_wconv<<<dim3(256, 11), 256, 0, stream>>>(wc);

    // ---- Phase A ----
    k_build_xm<<<(Rr * 128 + 255) / 256, 256, 0, stream>>>(x, meta, xm_h, xm_l);
    k_gates<<<Rr / 4, 256, 0, stream>>>(xm_h, xm_l, lr_w, lr_b, fg_w, fg_b, mo_w, mo_b, lr_t, fg_t, mo_t);
    k_gate_means<<<1, 256, 0, stream>>>(lr_t, fg_t, mo_t, scal);

    TriSet qkvA{{ { wt_h[0], wt_l[0], q_b, f0 }, { wt_h[1], wt_l[1], k_b, f1 }, { wt_h[2], wt_l[2], v_b, f2 } }};
    k_mm<0, 0, false, 0, true, 3, false><<<dim3(66, 8, 3), 256, 0, stream>>>(
        xm_h, xm_l, nullptr, nullptr, nullptr, nullptr, nullptr, nullptr, nullptr, nullptr,
        nullptr, nullptr, qkvA, Rr, Dd, Dd, 0);
    k_conv3<<<dim3(Rr, 3), 256, 0, stream>>>(f0, f1, f2, q_c, k_c, v_c,
                                             qb_h, qb_l, kb_h, kb_l, vb_h, vb_l);

    // ---- Phase B: memory-MLP forward (plain bf16; theta-damped path) ----
    k_mm<0, 0, false, 5, false, 1, false><<<GG, 256, 0, stream>>>(
        kb_h, nullptr, wt_h[7], nullptr, f0, mbin, nullptr, nullptr, nullptr, nullptr,
        h0_h, h0_l, none, Rr, Dd, Dd, 0);                               // z0=f0, h0
    k_mm<0, 0, false, 6, false, 1, false><<<GG, 256, 0, stream>>>(
        h0_h, nullptr, wt_h[8], nullptr, f1, mbh, nullptr, h0_h, h0_l, nullptr,
        h1_h, h1_l, none, Rr, Dd, Dd, 0);                               // a0=f1, h1
    k_mm<0, 0, false, 6, false, 1, false><<<GG, 256, 0, stream>>>(
        h1_h, nullptr, wt_h[9], nullptr, f2, mbh + 512, nullptr, h1_h, h1_l, nullptr,
        h2_h, h2_l, none, Rr, Dd, Dd, 0);                               // a1=f2, h2
    k_mm<0, 0, false, 3, false, 1, false><<<GG, 256, 0, stream>>>(
        h2_h, nullptr, wt_h[10], nullptr, nullptr, mbout, nullptr, vb_h, vb_l, lr_t,
        g1_h, g1_l, none, Rr, Dd, Dd, 0);                               // g1 = dpred

    // ---- Phase C: backward ----
    auto GRADW = [&](const unsigned short* ah, const unsigned short* bh, float* gout) {
        k_mm<1, 1, true, 0, false, 1, false><<<dim3(8, 8, 11), 256, 0, stream>>>(
            ah, nullptr, bh, nullptr, parts, nullptr, nullptr, nullptr, nullptr, nullptr,
            nullptr, nullptr, none, Dd, Dd, Rr, 0);
        k_reduce_splitk<<<1024, 256, 0, stream>>>(parts, gout, WEL, 11, 1.0f / NCc);
    };
    auto COLSUM = [&](const unsigned short* gh, const unsigned short* gl, float* bo) {
        k_colsum<<<dim3(2, 64), 256, 0, stream>>>(gh, gl, cpart);
        k_colsum_reduce<<<2, 256, 0, stream>>>(cpart, bo, 1.0f / NCc);
    };
    GRADW(h2_h, g1_h, gWout);  COLSUM(g1_h, g1_l, gbout);
    k_mm<0, 0, false, 4, false, 1, false><<<GG, 256, 0, stream>>>(
        g1_h, nullptr, wn_h[10], nullptr, f3, nullptr, f2, nullptr, nullptr, nullptr,
        gA_h, gA_l, none, Rr, Dd, Dd, 0);                               // f3=dh2, gA=da1
    GRADW(h1_h, gA_h, gWh1);   COLSUM(gA_h, gA_l, gbh1);
    k_mm<0, 0, false, 4, false, 1, false><<<GG, 256, 0, stream>>>(
        gA_h, nullptr, wn_h[9], nullptr, f3, nullptr, f1, nullptr, nullptr, nullptr,
        gB_h, gB_l, none, Rr, Dd, Dd, 1);                               // f3=dh1, gB=da0
    GRADW(h0_h, gB_h, gWh0);   COLSUM(gB_h, gB_l, gbh0);
    k_mm<0, 0, false, 4, false, 1, false><<<GG, 256, 0, stream>>>(
        gB_h, nullptr, wn_h[8], nullptr, f3, nullptr, f0, nullptr, nullptr, nullptr,
        gA_h, gA_l, none, Rr, Dd, Dd, 1);                               // gA=dz0
    GRADW(kb_h, gA_h, gWin);   COLSUM(gA_h, gA_l, gbin);

    // ---- Phase D: updates ----
    UpdW4 uw{ { mWin, mWh, mWh + WEL, mWout },
              { momWin, momWh, momWh + WEL, momWout },
              { gWin, gWh0, gWh1, gWout },
              { nWinT_h, nWh0T_h, nWh1T_h, nWoutT_h },
              { nWinT_l, nWh0T_l, nWh1T_l, nWoutT_l } };
    k_updW<<<dim3(256, 4), 256, 0, stream>>>(uw, scal);
    UpdB4 ub{ { mbin, mbh, mbh + 512, mbout },
              { mombin, mombh, mombh + 512, mombout },
              { gbin, gbh0, gbh1, gbout },
              { nbin, nbh0, nbh1, nbout } };
    k_updB<<<8, 256, 0, stream>>>(ub, scal);

    // ---- Phase E: retrieval MLP on q (bf16x2 split) ----
    k_mm<0, 0, false, 1, false, 3, false><<<GG, 256, 0, stream>>>(
        qb_h, qb_l, nWinT_h, nWinT_l, nullptr, nbin, nullptr, nullptr, nullptr, nullptr,
        g1_h, g1_l, none, Rr, Dd, Dd, 0);                               // e0 -> g1
    k_mm<0, 0, false, 2, false, 3, false><<<GG, 256, 0, stream>>>(
        g1_h, g1_l, nWh0T_h, nWh0T_l, nullptr, nbh0, nullptr, g1_h, g1_l, nullptr,
        h0_h, h0_l, none, Rr, Dd, Dd, 0);                               // e1 -> h0
    k_mm<0, 0, false, 2, false, 3, false><<<GG, 256, 0, stream>>>(
        h0_h, h0_l, nWh1T_h, nWh1T_l, nullptr, nbh1, nullptr, h0_h, h0_l, nullptr,
        h1_h, h1_l, none, Rr, Dd, Dd, 0);                               // e2 -> h1
    k_mm<0, 0, false, 1, false, 3, false><<<GG, 256, 0, stream>>>(
        h1_h, h1_l, nWoutT_h, nWoutT_l, nullptr, nbout, nullptr, nullptr, nullptr, nullptr,
        h2_h, h2_l, none, Rr, Dd, Dd, 0);                               // retrieved -> h2

    // ---- Phase F: SWA qkv (fp32 out), fused MFMA flash SWA, out-proj+slice ----
    TriSet qkvF{{ { wt_h[3], wt_l[3], swa_bq, f0 }, { wt_h[4], wt_l[4], swa_bk, f1 },
                  { wt_h[5], wt_l[5], swa_bv, f2 } }};
    k_mm<0, 0, false, 0, true, 3, false><<<dim3(66, 8, 3), 256, 0, stream>>>(
        h2_h, h2_l, nullptr, nullptr, nullptr, nullptr, nullptr, nullptr, nullptr, nullptr,
        nullptr, nullptr, qkvF, Rr, Dd, Dd, 0);
    k_swa<<<dim3(Nn / 64, Bb * NHh), 256, 0, stream>>>(f0, f1, f2, f3);
    k_mm<0, 0, false, 7, false, 3, true><<<GG, 256, 0, stream>>>(
        f3, nullptr, wt_h[6], wt_l[6], (float*)d_out, swa_bo, nullptr, nullptr, nullptr, nullptr,
        nullptr, nullptr, none, Rr, Dd, Dd, 0);
}

// Round 7
// 638.472 us; speedup vs baseline: 4.3003x; 1.0909x over previous
//
#include <hip/hip_runtime.h>
#include <cmath>

// ---------------------------------------------------------------------------
// NeuralMemory R7: unified LDS XOR bank swizzle (swz) on ALL frag staging in
// k_mm and k_swa — kills the 8-way quartet conflicts (9.7M/dispatch in R6).
// Math identical to R6 (bf16x2 split GEMMs + MFMA flash SWA).
// ---------------------------------------------------------------------------

namespace {

constexpr int Bb   = 2;
constexpr int Ss   = 2048;
constexpr int Dd   = 512;
constexpr int Mm   = 64;
constexpr int NCc  = 16;
constexpr int NHh  = 8;
constexpr int HD   = 64;
constexpr int WINw = 256;
constexpr int Nn   = Mm + Ss;    // 2112
constexpr int Rr   = Bb * Nn;    // 4224
constexpr int NBD  = Rr * Dd;
constexpr float MAXLR = 0.1f;

typedef __attribute__((ext_vector_type(8))) short short8;
typedef __attribute__((ext_vector_type(4))) float f32x4;

__device__ __forceinline__ float sigf(float x)  { return 1.0f / (1.0f + __expf(-x)); }
__device__ __forceinline__ float siluf(float x) { return x * sigf(x); }
__device__ __forceinline__ float dsiluf(float x){ float s = sigf(x); return s * (1.0f + x * (1.0f - s)); }
__device__ __forceinline__ unsigned short f2bf(float f) {
    unsigned int u = __float_as_uint(f);
    u = (u + 0x7FFFu + ((u >> 16) & 1u)) >> 16;
    return (unsigned short)u;
}
__device__ __forceinline__ float bf2f(unsigned short h) {
    return __uint_as_float(((unsigned int)h) << 16);
}
// bank swizzle on 16B LDS units: decorrelates (unit mod 8) from the row index
__device__ __forceinline__ int swz(int u) { return u ^ ((u >> 4) & 7); }

// ---- build xm (hi/lo bf16) ------------------------------------------------
__global__ void k_build_xm(const float* __restrict__ x, const float* __restrict__ meta,
                           unsigned short* __restrict__ xh, unsigned short* __restrict__ xl) {
    int i = blockIdx.x * 256 + threadIdx.x;      // float4 units
    if (i >= Rr * 128) return;
    int c = i & 127, r = i >> 7;
    int b = r / Nn, t = r - b * Nn;
    float4 v = (t < Mm) ? ((const float4*)meta)[t * 128 + c]
                        : ((const float4*)x)[(size_t)(b * Ss + (t - Mm)) * 128 + c];
    float vv[4] = { v.x, v.y, v.z, v.w };
    unsigned short h[4], l[4];
    #pragma unroll
    for (int e = 0; e < 4; ++e) { h[e] = f2bf(vv[e]); l[e] = f2bf(vv[e] - bf2f(h[e])); }
    *(ushort4*)(xh + (size_t)i * 4) = *(ushort4*)h;
    *(ushort4*)(xl + (size_t)i * 4) = *(ushort4*)l;
}

// ---- per-row scalar gates -------------------------------------------------
__global__ void k_gates(const unsigned short* __restrict__ xh, const unsigned short* __restrict__ xl,
                        const float* __restrict__ lw, const float* __restrict__ lb,
                        const float* __restrict__ fw, const float* __restrict__ fb,
                        const float* __restrict__ mw, const float* __restrict__ mb,
                        float* __restrict__ lr_t, float* __restrict__ fg_t, float* __restrict__ mo_t) {
    int r = blockIdx.x * 4 + (threadIdx.x >> 6);
    int lane = threadIdx.x & 63;
    if (r >= Rr) return;
    float s0 = 0.f, s1 = 0.f, s2 = 0.f;
    for (int j = lane; j < Dd; j += 64) {
        size_t o = (size_t)r * Dd + j;
        float v = bf2f(xh[o]) + bf2f(xl[o]);
        s0 += v * lw[j]; s1 += v * fw[j]; s2 += v * mw[j];
    }
    #pragma unroll
    for (int off = 32; off; off >>= 1) {
        s0 += __shfl_down(s0, off, 64);
        s1 += __shfl_down(s1, off, 64);
        s2 += __shfl_down(s2, off, 64);
    }
    if (lane == 0) {
        lr_t[r] = MAXLR * sigf(s0 + lb[0]);
        fg_t[r] = sigf(s1 + fb[0]);
        mo_t[r] = sigf(s2 + mb[0]);
    }
}

__global__ void k_gate_means(const float* __restrict__ lr_t, const float* __restrict__ fg_t,
                             const float* __restrict__ mo_t, float* __restrict__ scal) {
    __shared__ float red[256];
    const float* ptrs[3] = { fg_t, lr_t, mo_t };
    for (int w = 0; w < 3; ++w) {
        float acc = 0.f;
        for (int i = threadIdx.x; i < Rr; i += 256) acc += ptrs[w][i];
        red[threadIdx.x] = acc; __syncthreads();
        for (int off = 128; off; off >>= 1) {
            if (threadIdx.x < off) red[threadIdx.x] += red[threadIdx.x + off];
            __syncthreads();
        }
        if (threadIdx.x == 0) scal[w] = red[0] / (float)Rr;
        __syncthreads();
    }
}

// ---- weight convert: fp32 W[r][c] -> WT hi/lo [c][r]; optional natural hi --
struct WC { const float* w[11]; unsigned short* th[11]; unsigned short* tl[11]; unsigned short* nh[11]; };
__global__ void k_wconv(WC wc) {
    int seg = blockIdx.y;
    int i0 = blockIdx.x * 1024 + threadIdx.x * 4;
    float4 v4 = *(const float4*)(wc.w[seg] + i0);
    float vals[4] = { v4.x, v4.y, v4.z, v4.w };
    int r = i0 >> 9, c = i0 & 511;
    #pragma unroll
    for (int e = 0; e < 4; ++e) {
        unsigned short h = f2bf(vals[e]);
        unsigned short l = f2bf(vals[e] - bf2f(h));
        wc.th[seg][(size_t)(c + e) * 512 + r] = h;
        wc.tl[seg][(size_t)(c + e) * 512 + r] = l;
        if (wc.nh[seg]) wc.nh[seg][i0 + e] = h;
    }
}

// ---- MFMA GEMM: 64x64 tile, BK=64, 256 thr (4 waves, each 32x32) ----------
// All LDS frag staging goes through swz() (both store and read sides).
struct TriW { const unsigned short* bh; const unsigned short* bl; const float* bias; float* c; };
struct TriSet { TriW t[3]; };

template<int TA, int TB, bool SPLITK, int EPI, bool MULTI, int NS, bool AF32>
__global__ __launch_bounds__(256) void k_mm(
        const void* Ap, const unsigned short* Al_,
        const unsigned short* Bh_, const unsigned short* Bl_,
        float* C, const float* bias, const float* __restrict__ exf,
        const unsigned short* __restrict__ exh, const unsigned short* __restrict__ exl,
        const float* __restrict__ lrp,
        unsigned short* oh, unsigned short* ol, TriSet ts,
        int Md, int Nd, int Kd, int accum) {
    constexpr int SMEMB = (NS == 3) ? 32768 : 16384;
    __shared__ char smem[SMEMB];
    unsigned short* AH = (unsigned short*)smem;
    unsigned short* AL = AH + 4096;
    unsigned short* BH = AH + ((NS == 3) ? 8192 : 4096);
    unsigned short* BL = BH + 4096;
    const int tid = threadIdx.x;
    const int m0 = blockIdx.x * 64, n0 = blockIdx.y * 64;
    if constexpr (MULTI) {
        const TriW& tw = ts.t[blockIdx.z];
        Bh_ = tw.bh; Bl_ = tw.bl; bias = tw.bias; C = tw.c;
    }
    int kbg = 0, ke = Kd;
    if constexpr (SPLITK) {
        int kc = Kd / gridDim.z;
        kbg = blockIdx.z * kc; ke = kbg + kc;
        C += (size_t)blockIdx.z * Md * Nd;
    }
    const int astr = (TA == 0) ? Kd : Md;

    f32x4 acc[2][2];
    #pragma unroll
    for (int i = 0; i < 2; ++i)
        #pragma unroll
        for (int j = 0; j < 2; ++j)
            #pragma unroll
            for (int v = 0; v < 4; ++v) acc[i][j][v] = 0.f;

    short8 pA0, pA1, pAl0, pAl1, pB0, pB1, pBl0, pBl1;
    float4 pAf[4];

    auto gload = [&](int k0) {
        if constexpr (TA == 0) {
            int r = tid >> 2, ks2 = (tid & 3) * 16;
            if constexpr (AF32) {
                const float* ap = (const float*)Ap + (size_t)(m0 + r) * astr + k0 + ks2;
                pAf[0] = *(const float4*)ap;       pAf[1] = *(const float4*)(ap + 4);
                pAf[2] = *(const float4*)(ap + 8); pAf[3] = *(const float4*)(ap + 12);
            } else {
                const unsigned short* ah = (const unsigned short*)Ap + (size_t)(m0 + r) * astr + k0 + ks2;
                pA0 = *(const short8*)ah; pA1 = *(const short8*)(ah + 8);
                if constexpr (NS == 3) {
                    const unsigned short* al = Al_ + (size_t)(m0 + r) * astr + k0 + ks2;
                    pAl0 = *(const short8*)al; pAl1 = *(const short8*)(al + 8);
                }
            }
        } else {
            int kr = tid >> 2, ms = (tid & 3) * 16;
            const unsigned short* ah = (const unsigned short*)Ap + (size_t)(k0 + kr) * astr + m0 + ms;
            pA0 = *(const short8*)ah; pA1 = *(const short8*)(ah + 8);
            if constexpr (NS == 3) {
                const unsigned short* al = Al_ + (size_t)(k0 + kr) * astr + m0 + ms;
                pAl0 = *(const short8*)al; pAl1 = *(const short8*)(al + 8);
            }
        }
        if constexpr (TB == 0) {
            int nr = tid >> 2, ks2 = (tid & 3) * 16;
            const unsigned short* bh = Bh_ + (size_t)(n0 + nr) * Kd + k0 + ks2;
            pB0 = *(const short8*)bh; pB1 = *(const short8*)(bh + 8);
            if constexpr (NS == 3) {
                const unsigned short* bl = Bl_ + (size_t)(n0 + nr) * Kd + k0 + ks2;
                pBl0 = *(const short8*)bl; pBl1 = *(const short8*)(bl + 8);
            }
        } else {
            int kr = tid >> 2, nseg = (tid & 3) * 16;
            const unsigned short* bh = Bh_ + (size_t)(k0 + kr) * Nd + n0 + nseg;
            pB0 = *(const short8*)bh; pB1 = *(const short8*)(bh + 8);
            if constexpr (NS == 3) {
                const unsigned short* bl = Bl_ + (size_t)(k0 + kr) * Nd + n0 + nseg;
                pBl0 = *(const short8*)bl; pBl1 = *(const short8*)(bl + 8);
            }
        }
    };
    auto lstore = [&]() {
        if constexpr (TA == 0) {
            int r = tid >> 2, ks2 = (tid & 3) * 16;
            int f = r >> 4, rr = r & 15, kf = ks2 >> 5, q = (ks2 >> 3) & 3;
            int F = (f * 2 + kf) * 4 + q;
            int u0 = swz(F * 16 + rr) * 8, u1 = swz((F + 1) * 16 + rr) * 8;
            if constexpr (AF32) {
                unsigned short hh[16], ll[16];
                const float* pf = (const float*)pAf;
                #pragma unroll
                for (int e = 0; e < 16; ++e) { hh[e] = f2bf(pf[e]); ll[e] = f2bf(pf[e] - bf2f(hh[e])); }
                *(short8*)(AH + u0) = *(short8*)hh;  *(short8*)(AH + u1) = *(short8*)(hh + 8);
                *(short8*)(AL + u0) = *(short8*)ll;  *(short8*)(AL + u1) = *(short8*)(ll + 8);
            } else {
                *(short8*)(AH + u0) = pA0; *(short8*)(AH + u1) = pA1;
                if constexpr (NS == 3) { *(short8*)(AL + u0) = pAl0; *(short8*)(AL + u1) = pAl1; }
            }
        } else {
            int kr = tid >> 2, ms = (tid & 3) * 16;
            int f = ms >> 4, kf = kr >> 5, q = (kr >> 3) & 3, kk = kr & 7;
            int F = (f * 2 + kf) * 4 + q;
            unsigned short tmp[16];
            *(short8*)tmp = pA0; *(short8*)(tmp + 8) = pA1;
            #pragma unroll
            for (int e = 0; e < 16; ++e) AH[swz((F << 4) | e) * 8 + kk] = tmp[e];
            if constexpr (NS == 3) {
                *(short8*)tmp = pAl0; *(short8*)(tmp + 8) = pAl1;
                #pragma unroll
                for (int e = 0; e < 16; ++e) AL[swz((F << 4) | e) * 8 + kk] = tmp[e];
            }
        }
        if constexpr (TB == 0) {
            int nr = tid >> 2, ks2 = (tid & 3) * 16;
            int f = nr >> 4, rr = nr & 15, kf = ks2 >> 5, q = (ks2 >> 3) & 3;
            int F = (f * 2 + kf) * 4 + q;
            int u0 = swz(F * 16 + rr) * 8, u1 = swz((F + 1) * 16 + rr) * 8;
            *(short8*)(BH + u0) = pB0; *(short8*)(BH + u1) = pB1;
            if constexpr (NS == 3) { *(short8*)(BL + u0) = pBl0; *(short8*)(BL + u1) = pBl1; }
        } else {
            int kr = tid >> 2, nseg = (tid & 3) * 16;
            int f = nseg >> 4, kf = kr >> 5, q = (kr >> 3) & 3, kk = kr & 7;
            int F = (f * 2 + kf) * 4 + q;
            unsigned short tmp[16];
            *(short8*)tmp = pB0; *(short8*)(tmp + 8) = pB1;
            #pragma unroll
            for (int e = 0; e < 16; ++e) BH[swz((F << 4) | e) * 8 + kk] = tmp[e];
            if constexpr (NS == 3) {
                *(short8*)tmp = pBl0; *(short8*)(tmp + 8) = pBl1;
                #pragma unroll
                for (int e = 0; e < 16; ++e) BL[swz((F << 4) | e) * 8 + kk] = tmp[e];
            }
        }
    };

    const int wv = tid >> 6, lr16 = tid & 15, lq = (tid >> 4) & 3;
    const int wm = wv & 1, wn = wv >> 1;

    gload(kbg); lstore();
    __syncthreads();
    for (int k0 = kbg; k0 < ke; k0 += 64) {
        bool more = (k0 + 64) < ke;
        if (more) gload(k0 + 64);
        #pragma unroll
        for (int kf = 0; kf < 2; ++kf) {
            short8 fa[2], fal[2], fb[2], fbl[2];
            #pragma unroll
            for (int i = 0; i < 2; ++i) {
                int fA = wm * 2 + i;
                int u = swz(((fA * 2 + kf) * 4 + lq) * 16 + lr16);
                fa[i] = *(const short8*)(AH + u * 8);
                if constexpr (NS == 3) fal[i] = *(const short8*)(AL + u * 8);
            }
            #pragma unroll
            for (int j = 0; j < 2; ++j) {
                int fB = wn * 2 + j;
                int u = swz(((fB * 2 + kf) * 4 + lq) * 16 + lr16);
                fb[j] = *(const short8*)(BH + u * 8);
                if constexpr (NS == 3) fbl[j] = *(const short8*)(BL + u * 8);
            }
            #pragma unroll
            for (int i = 0; i < 2; ++i)
                #pragma unroll
                for (int j = 0; j < 2; ++j) {
                    acc[i][j] = __builtin_amdgcn_mfma_f32_16x16x32_bf16(fa[i], fb[j], acc[i][j], 0, 0, 0);
                    if constexpr (NS == 3) {
                        acc[i][j] = __builtin_amdgcn_mfma_f32_16x16x32_bf16(fa[i], fbl[j], acc[i][j], 0, 0, 0);
                        acc[i][j] = __builtin_amdgcn_mfma_f32_16x16x32_bf16(fal[i], fb[j], acc[i][j], 0, 0, 0);
                    }
                }
        }
        if (more) { __syncthreads(); lstore(); __syncthreads(); }
    }
    __syncthreads();

    // ---- epilogue: acc -> swizzled LDS fp32 -> row-major per-thread ----
    float* EP = (float*)smem;
    #pragma unroll
    for (int i = 0; i < 2; ++i)
        #pragma unroll
        for (int j = 0; j < 2; ++j)
            #pragma unroll
            for (int v = 0; v < 4; ++v) {
                int row = wm * 32 + i * 16 + lq * 4 + v;
                int col = wn * 32 + j * 16 + lr16;
                int u = col >> 2, up = u ^ (row & 15);
                EP[row * 64 + up * 4 + (col & 3)] = acc[i][j][v];
            }
    __syncthreads();
    int r = tid >> 2, cg = tid & 3;
    float vv[16];
    #pragma unroll
    for (int uu = 0; uu < 4; ++uu) {
        int u = cg * 4 + uu;
        *(float4*)&vv[uu * 4] = *(const float4*)&EP[r * 64 + ((u ^ (r & 15)) * 4)];
    }
    int m = m0 + r, nb = n0 + cg * 16;
    size_t idx = (size_t)m * Nd + nb;

    if constexpr (SPLITK) {
        #pragma unroll
        for (int uu = 0; uu < 4; ++uu) *(float4*)(C + idx + uu * 4) = *(float4*)&vv[uu * 4];
        return;
    }
    if (bias) {
        #pragma unroll
        for (int uu = 0; uu < 4; ++uu) {
            float4 b4 = *(const float4*)(bias + nb + uu * 4);
            vv[uu * 4 + 0] += b4.x; vv[uu * 4 + 1] += b4.y;
            vv[uu * 4 + 2] += b4.z; vv[uu * 4 + 3] += b4.w;
        }
    }
    unsigned short eh8[16], el8[16];
    if constexpr (EPI == 2 || EPI == 3 || EPI == 6) {
        #pragma unroll
        for (int k4 = 0; k4 < 2; ++k4) {
            *(short8*)&eh8[k4 * 8] = *(const short8*)(exh + idx + k4 * 8);
            *(short8*)&el8[k4 * 8] = *(const short8*)(exl + idx + k4 * 8);
        }
    }
    auto store_hl = [&](const float* s) {
        unsigned short hb[16], lb2[16];
        #pragma unroll
        for (int e = 0; e < 16; ++e) { hb[e] = f2bf(s[e]); lb2[e] = f2bf(s[e] - bf2f(hb[e])); }
        #pragma unroll
        for (int k4 = 0; k4 < 2; ++k4) {
            *(short8*)(oh + idx + k4 * 8) = *(short8*)&hb[k4 * 8];
            *(short8*)(ol + idx + k4 * 8) = *(short8*)&lb2[k4 * 8];
        }
    };
    auto accum_add = [&]() {
        #pragma unroll
        for (int uu = 0; uu < 4; ++uu) {
            float4 o4 = *(const float4*)(C + idx + uu * 4);
            vv[uu * 4 + 0] += o4.x; vv[uu * 4 + 1] += o4.y;
            vv[uu * 4 + 2] += o4.z; vv[uu * 4 + 3] += o4.w;
        }
    };
    auto store_f = [&]() {
        #pragma unroll
        for (int uu = 0; uu < 4; ++uu) *(float4*)(C + idx + uu * 4) = *(float4*)&vv[uu * 4];
    };
    if constexpr (EPI == 0) {
        if (accum) accum_add();
        store_f();
    } else if constexpr (EPI == 1) {
        float s[16];
        #pragma unroll
        for (int e = 0; e < 16; ++e) s[e] = siluf(vv[e]);
        store_hl(s);
    } else if constexpr (EPI == 2) {
        float s[16];
        #pragma unroll
        for (int e = 0; e < 16; ++e) s[e] = bf2f(eh8[e]) + bf2f(el8[e]) + siluf(vv[e]);
        store_hl(s);
    } else if constexpr (EPI == 3) {
        float sc = (2.0f / 512.0f) * lrp[m];
        float s[16];
        #pragma unroll
        for (int e = 0; e < 16; ++e) s[e] = sc * (vv[e] - (bf2f(eh8[e]) + bf2f(el8[e])));
        store_hl(s);
    } else if constexpr (EPI == 4) {
        if (accum) accum_add();
        store_f();
        float s[16];
        #pragma unroll
        for (int e = 0; e < 16; ++e) s[e] = vv[e] * dsiluf(exf[idx + e]);
        store_hl(s);
    } else if constexpr (EPI == 5) {
        store_f();
        float s[16];
        #pragma unroll
        for (int e = 0; e < 16; ++e) s[e] = siluf(vv[e]);
        store_hl(s);
    } else if constexpr (EPI == 6) {
        store_f();
        float s[16];
        #pragma unroll
        for (int e = 0; e < 16; ++e) s[e] = bf2f(eh8[e]) + bf2f(el8[e]) + siluf(vv[e]);
        store_hl(s);
    } else if constexpr (EPI == 7) {
        int b2 = m / Nn, t2 = m - b2 * Nn;
        if (t2 >= Mm) {
            float* dst = C + (size_t)(b2 * Ss + (t2 - Mm)) * Nd + nb;
            #pragma unroll
            for (int uu = 0; uu < 4; ++uu) *(float4*)(dst + uu * 4) = *(float4*)&vv[uu * 4];
        }
    }
}

__global__ void k_reduce_splitk(const float* __restrict__ part, float* __restrict__ out,
                                int n, int z, float alpha) {
    int i = blockIdx.x * 256 + threadIdx.x;
    if (i >= n) return;
    float s = 0.f;
    for (int zz = 0; zz < z; ++zz) s += part[(size_t)zz * n + i];
    out[i] = alpha * s;
}

// ---- causal depthwise conv K=4 + SiLU (+L2n for q,k); fp32 in, hi/lo out --
__global__ __launch_bounds__(256) void k_conv3(
        const float* __restrict__ yq, const float* __restrict__ yk, const float* __restrict__ yv,
        const float* __restrict__ cq, const float* __restrict__ ck, const float* __restrict__ cv,
        unsigned short* oqh, unsigned short* oql, unsigned short* okh, unsigned short* okl,
        unsigned short* ovh, unsigned short* ovl) {
    int which = blockIdx.y;
    const float* y  = which == 0 ? yq : which == 1 ? yk : yv;
    const float* cw = which == 0 ? cq : which == 1 ? ck : cv;
    unsigned short* oh = which == 0 ? oqh : which == 1 ? okh : ovh;
    unsigned short* ol = which == 0 ? oql : which == 1 ? okl : ovl;
    bool norm = which < 2;
    int r = blockIdx.x;
    int b = r / Nn, t = r - b * Nn;
    const size_t rowbase = (size_t)r * Dd;
    float s[2];
    #pragma unroll
    for (int u = 0; u < 2; ++u) {
        int d = threadIdx.x + u * 256;
        float acc = 0.f;
        #pragma unroll
        for (int k = 0; k < 4; ++k) {
            int tt = t - 3 + k;
            if (tt >= 0) acc += y[(size_t)(b * Nn + tt) * Dd + d] * cw[d * 4 + k];
        }
        s[u] = siluf(acc);
    }
    float denom = 1.0f;
    if (norm) {
        __shared__ float wr[4];
        float v2 = s[0] * s[0] + s[1] * s[1];
        #pragma unroll
        for (int off = 32; off; off >>= 1) v2 += __shfl_xor(v2, off, 64);
        if ((threadIdx.x & 63) == 0) wr[threadIdx.x >> 6] = v2;
        __syncthreads();
        denom = fmaxf(sqrtf(wr[0] + wr[1] + wr[2] + wr[3]), 1e-12f);
    }
    #pragma unroll
    for (int u = 0; u < 2; ++u) {
        float v = s[u] / denom;
        unsigned short h = f2bf(v);
        oh[rowbase + threadIdx.x + u * 256] = h;
        ol[rowbase + threadIdx.x + u * 256] = f2bf(v - bf2f(h));
    }
}

// ---- column sums for bias grads (hi/lo input) -----------------------------
__global__ void k_colsum(const unsigned short* __restrict__ gh, const unsigned short* __restrict__ gl,
                         float* __restrict__ part) {
    int col = blockIdx.x * 256 + threadIdx.x;
    int chunk = blockIdx.y;
    int r0 = chunk * (Rr / 64);
    float s = 0.f;
    for (int r = r0; r < r0 + Rr / 64; ++r) {
        size_t o = (size_t)r * Dd + col;
        s += bf2f(gh[o]) + bf2f(gl[o]);
    }
    part[chunk * Dd + col] = s;
}
__global__ void k_colsum_reduce(const float* __restrict__ part, float* __restrict__ out, float alpha) {
    int col = blockIdx.x * 256 + threadIdx.x;
    if (col >= Dd) return;
    float s = 0.f;
    for (int c = 0; c < 64; ++c) s += part[c * Dd + col];
    out[col] = alpha * s;
}

// ---- parameter updates ----------------------------------------------------
struct UpdW4 { const float* p[4]; const float* mo[4]; const float* g[4];
               unsigned short* th[4]; unsigned short* tl[4]; };
__global__ void k_updW(UpdW4 u, const float* __restrict__ scal) {
    int seg = blockIdx.y;
    int i0 = blockIdx.x * 1024 + threadIdx.x * 4;
    float4 p4 = *(const float4*)(u.p[seg] + i0);
    float4 m4 = *(const float4*)(u.mo[seg] + i0);
    float4 g4 = *(const float4*)(u.g[seg] + i0);
    float a = 1.0f - scal[0], et = scal[2], th = scal[1];
    float vals[4] = { p4.x * a + et * m4.x - th * g4.x, p4.y * a + et * m4.y - th * g4.y,
                      p4.z * a + et * m4.z - th * g4.z, p4.w * a + et * m4.w - th * g4.w };
    int r = i0 >> 9, c = i0 & 511;
    #pragma unroll
    for (int e = 0; e < 4; ++e) {
        unsigned short h = f2bf(vals[e]);
        u.th[seg][(size_t)(c + e) * 512 + r] = h;
        u.tl[seg][(size_t)(c + e) * 512 + r] = f2bf(vals[e] - bf2f(h));
    }
}
struct UpdB4 { const float* p[4]; const float* mo[4]; const float* g[4]; float* o[4]; };
__global__ void k_updB(UpdB4 u, const float* __restrict__ scal) {
    int seg = blockIdx.x >> 1;
    int i = (blockIdx.x & 1) * 256 + threadIdx.x;
    u.o[seg][i] = u.p[seg][i] * (1.0f - scal[0]) + scal[2] * u.mo[seg][i] - scal[1] * u.g[seg][i];
}

// ---- fused MFMA flash SWA (swz'd staging + keyed P round-trip) ------------
__global__ __launch_bounds__(256) void k_swa(const float* __restrict__ qs,
                                             const float* __restrict__ ks,
                                             const float* __restrict__ vs,
                                             float* __restrict__ out) {
    __shared__ unsigned short KH[2048], KL[2048], VH[2048], VL[2048];
    __shared__ unsigned short PH[4][512], PL[4][512];
    const int tid = threadIdx.x;
    const int w = tid >> 6, lane = tid & 63;
    const int lq = lane >> 4, l16 = lane & 15;
    const int q0 = blockIdx.x * 64;
    const int bh = blockIdx.y;
    const int h = bh & 7, b = bh >> 3;
    const size_t srow = (size_t)(b * Nn) * Dd + h * HD;
    const int iq = q0 + w * 16 + l16;          // query for A-frag (m = l16)

    // Q A-frags hi/lo: k = kf*32 + lq*8 + j
    short8 qh[2], qlo[2];
    {
        const float* qr = qs + srow + (size_t)iq * Dd;
        #pragma unroll
        for (int kf = 0; kf < 2; ++kf) {
            float t8[8];
            *(float4*)&t8[0] = *(const float4*)(qr + kf * 32 + lq * 8);
            *(float4*)&t8[4] = *(const float4*)(qr + kf * 32 + lq * 8 + 4);
            unsigned short hh[8], ll[8];
            #pragma unroll
            for (int e = 0; e < 8; ++e) { hh[e] = f2bf(t8[e]); ll[e] = f2bf(t8[e] - bf2f(hh[e])); }
            qh[kf] = *(short8*)hh; qlo[kf] = *(short8*)ll;
        }
    }

    f32x4 o[4];
    #pragma unroll
    for (int nf = 0; nf < 4; ++nf)
        #pragma unroll
        for (int v = 0; v < 4; ++v) o[nf][v] = 0.f;
    float mrun[4] = { -1e30f, -1e30f, -1e30f, -1e30f };
    float lrun[4] = { 0.f, 0.f, 0.f, 0.f };
    const int iw = q0 + w * 16 + lq * 4;       // C-layout row base (i = iw + v)

    int jlo = q0 - (WINw - 1); if (jlo < 0) jlo = 0;
    jlo &= ~31;
    for (int jt = jlo; jt < q0 + 64; jt += 32) {
        __syncthreads();
        // stage K tile: B-frag [n=key(32)][k=dim(64)]
        {
            int nr = tid >> 3, ds8 = (tid & 7) * 8;
            const float* kr = ks + srow + (size_t)(jt + nr) * Dd + ds8;
            float t8[8];
            *(float4*)&t8[0] = *(const float4*)kr;
            *(float4*)&t8[4] = *(const float4*)(kr + 4);
            unsigned short hh[8], ll[8];
            #pragma unroll
            for (int e = 0; e < 8; ++e) { hh[e] = f2bf(t8[e]); ll[e] = f2bf(t8[e] - bf2f(hh[e])); }
            int f = nr >> 4, rr = nr & 15, kf = ds8 >> 5, q = (ds8 >> 3) & 3;
            int u = swz(((f * 2 + kf) * 4 + q) * 16 + rr);
            *(short8*)(KH + u * 8) = *(short8*)hh;
            *(short8*)(KL + u * 8) = *(short8*)ll;
        }
        // stage V^T tile: B-frag [n=dim(64)][k=key(32)] — coalesced loads
        {
            int d = tid & 63, kg = tid >> 6;
            unsigned short hh[8], ll[8];
            #pragma unroll
            for (int e = 0; e < 8; ++e) {
                float v = vs[srow + (size_t)(jt + kg * 8 + e) * Dd + d];
                hh[e] = f2bf(v); ll[e] = f2bf(v - bf2f(hh[e]));
            }
            int f = d >> 4, rr = d & 15;
            int u = swz((f * 4 + kg) * 16 + rr);
            *(short8*)(VH + u * 8) = *(short8*)hh;
            *(short8*)(VL + u * 8) = *(short8*)ll;
        }
        __syncthreads();

        // S = Q K^T (split)
        f32x4 s[2];
        #pragma unroll
        for (int nf = 0; nf < 2; ++nf) {
            #pragma unroll
            for (int v = 0; v < 4; ++v) s[nf][v] = 0.f;
            #pragma unroll
            for (int kf = 0; kf < 2; ++kf) {
                int u = swz(((nf * 2 + kf) * 4 + lq) * 16 + l16);
                short8 kbh = *(const short8*)(KH + u * 8);
                short8 kbl = *(const short8*)(KL + u * 8);
                s[nf] = __builtin_amdgcn_mfma_f32_16x16x32_bf16(qh[kf], kbh, s[nf], 0, 0, 0);
                s[nf] = __builtin_amdgcn_mfma_f32_16x16x32_bf16(qh[kf], kbl, s[nf], 0, 0, 0);
                s[nf] = __builtin_amdgcn_mfma_f32_16x16x32_bf16(qlo[kf], kbh, s[nf], 0, 0, 0);
            }
        }
        // mask + scale (1/sqrt(64)) + online softmax
        float mt[4];
        #pragma unroll
        for (int v = 0; v < 4; ++v) {
            int i = iw + v;
            int j0c = jt + l16, j1c = jt + 16 + l16;
            s[0][v] = ((j0c <= i) && (i - j0c < WINw)) ? s[0][v] * 0.125f : -1e30f;
            s[1][v] = ((j1c <= i) && (i - j1c < WINw)) ? s[1][v] * 0.125f : -1e30f;
            mt[v] = fmaxf(s[0][v], s[1][v]);
        }
        #pragma unroll
        for (int msk = 1; msk < 16; msk <<= 1)
            #pragma unroll
            for (int v = 0; v < 4; ++v) mt[v] = fmaxf(mt[v], __shfl_xor(mt[v], msk, 64));
        float rs[4];
        #pragma unroll
        for (int v = 0; v < 4; ++v) {
            float mnew = fmaxf(mrun[v], mt[v]);
            float corr = __expf(mrun[v] - mnew);
            mrun[v] = mnew;
            float p0 = (s[0][v] > -1e29f) ? __expf(s[0][v] - mnew) : 0.f;
            float p1 = (s[1][v] > -1e29f) ? __expf(s[1][v] - mnew) : 0.f;
            s[0][v] = p0; s[1][v] = p1;
            rs[v] = p0 + p1;
            lrun[v] *= corr;
            #pragma unroll
            for (int nf = 0; nf < 4; ++nf) o[nf][v] *= corr;
        }
        #pragma unroll
        for (int msk = 1; msk < 16; msk <<= 1)
            #pragma unroll
            for (int v = 0; v < 4; ++v) rs[v] += __shfl_xor(rs[v], msk, 64);
        #pragma unroll
        for (int v = 0; v < 4; ++v) lrun[v] += rs[v];

        // P: C layout -> per-wave A-frag LDS (hi/lo), row>>2-keyed unit XOR
        #pragma unroll
        for (int nf = 0; nf < 2; ++nf)
            #pragma unroll
            for (int v = 0; v < 4; ++v) {
                float p = s[nf][v];
                unsigned short hh = f2bf(p);
                int row = lq * 4 + v;
                int cu = (nf * 2 + (l16 >> 3)) ^ (row >> 2);
                int addr = row * 32 + cu * 8 + (l16 & 7);
                PH[w][addr] = hh;
                PL[w][addr] = f2bf(p - bf2f(hh));
            }
        __syncthreads();
        int pa = l16 * 32 + (lq ^ (l16 >> 2)) * 8;
        short8 pah = *(const short8*)(&PH[w][pa]);
        short8 pal = *(const short8*)(&PL[w][pa]);
        #pragma unroll
        for (int nf = 0; nf < 4; ++nf) {
            int u = swz((nf * 4 + lq) * 16 + l16);
            short8 vth = *(const short8*)(VH + u * 8);
            short8 vtl = *(const short8*)(VL + u * 8);
            o[nf] = __builtin_amdgcn_mfma_f32_16x16x32_bf16(pah, vth, o[nf], 0, 0, 0);
            o[nf] = __builtin_amdgcn_mfma_f32_16x16x32_bf16(pah, vtl, o[nf], 0, 0, 0);
            o[nf] = __builtin_amdgcn_mfma_f32_16x16x32_bf16(pal, vth, o[nf], 0, 0, 0);
        }
    }
    float invl[4];
    #pragma unroll
    for (int v = 0; v < 4; ++v) invl[v] = 1.0f / lrun[v];
    #pragma unroll
    for (int nf = 0; nf < 4; ++nf)
        #pragma unroll
        for (int v = 0; v < 4; ++v)
            out[srow + (size_t)(iw + v) * Dd + nf * 16 + l16] = o[nf][v] * invl[v];
}

} // namespace

extern "C" void kernel_launch(void* const* d_in, const int* in_sizes, int n_in,
                              void* d_out, int out_size, void* d_ws, size_t ws_size,
                              hipStream_t stream) {
    const float* x       = (const float*)d_in[0];
    const float* meta    = (const float*)d_in[1];
    const float* mWin    = (const float*)d_in[2];
    const float* mbin    = (const float*)d_in[3];
    const float* mWh     = (const float*)d_in[4];
    const float* mbh     = (const float*)d_in[5];
    const float* mWout   = (const float*)d_in[6];
    const float* mbout   = (const float*)d_in[7];
    const float* momWin  = (const float*)d_in[8];
    const float* mombin  = (const float*)d_in[9];
    const float* momWh   = (const float*)d_in[10];
    const float* mombh   = (const float*)d_in[11];
    const float* momWout = (const float*)d_in[12];
    const float* mombout = (const float*)d_in[13];
    const float* q_w = (const float*)d_in[14]; const float* q_b = (const float*)d_in[15]; const float* q_c = (const float*)d_in[16];
    const float* k_w = (const float*)d_in[17]; const float* k_b = (const float*)d_in[18]; const float* k_c = (const float*)d_in[19];
    const float* v_w = (const float*)d_in[20]; const float* v_b = (const float*)d_in[21]; const float* v_c = (const float*)d_in[22];
    const float* lr_w = (const float*)d_in[23]; const float* lr_b = (const float*)d_in[24];
    const float* fg_w = (const float*)d_in[25]; const float* fg_b = (const float*)d_in[26];
    const float* mo_w = (const float*)d_in[27]; const float* mo_b = (const float*)d_in[28];
    const float* swa_wq = (const float*)d_in[29]; const float* swa_wk = (const float*)d_in[30];
    const float* swa_wv = (const float*)d_in[31]; const float* swa_wo = (const float*)d_in[32];
    const float* swa_bq = (const float*)d_in[33]; const float* swa_bk = (const float*)d_in[34];
    const float* swa_bv = (const float*)d_in[35]; const float* swa_bo = (const float*)d_in[36];
    (void)in_sizes; (void)n_in; (void)out_size; (void)ws_size;

    char* wsb = (char*)d_ws;
    size_t off = 0;
    auto allocB = [&](size_t bytes) { void* p = wsb + off; off = (off + bytes + 255) & ~(size_t)255; return p; };
    auto allocU = [&](size_t elems) { return (unsigned short*)allocB(elems * 2); };
    auto allocF = [&](size_t elems) { return (float*)allocB(elems * 4); };

    unsigned short *xm_h = allocU(NBD), *xm_l = allocU(NBD);     // reused as gB
    unsigned short *qb_h = allocU(NBD), *qb_l = allocU(NBD);
    unsigned short *kb_h = allocU(NBD), *kb_l = allocU(NBD);
    unsigned short *vb_h = allocU(NBD), *vb_l = allocU(NBD);     // reused as gA
    unsigned short *h0_h = allocU(NBD), *h0_l = allocU(NBD);
    unsigned short *h1_h = allocU(NBD), *h1_l = allocU(NBD);
    unsigned short *h2_h = allocU(NBD), *h2_l = allocU(NBD);
    unsigned short *g1_h = allocU(NBD), *g1_l = allocU(NBD);
    float *f0 = allocF(NBD), *f1 = allocF(NBD), *f2 = allocF(NBD), *f3 = allocF(NBD);
    float *parts = allocF((size_t)12 * 262144);
    const int WEL = 262144;
    unsigned short *wt_h[11], *wt_l[11], *wn_h[11];
    for (int i = 0; i < 11; ++i) { wt_h[i] = allocU(WEL); wt_l[i] = allocU(WEL); wn_h[i] = nullptr; }
    for (int i = 8; i < 11; ++i) wn_h[i] = allocU(WEL);          // natural hi: mWh0, mWh1, mWout
    unsigned short *nWinT_h = allocU(WEL), *nWinT_l = allocU(WEL);
    unsigned short *nWh0T_h = allocU(WEL), *nWh0T_l = allocU(WEL);
    unsigned short *nWh1T_h = allocU(WEL), *nWh1T_l = allocU(WEL);
    unsigned short *nWoutT_h = allocU(WEL), *nWoutT_l = allocU(WEL);
    float *gWin = allocF(WEL), *gWh0 = allocF(WEL), *gWh1 = allocF(WEL), *gWout = allocF(WEL);
    float *gbin = allocF(512), *gbh0 = allocF(512), *gbh1 = allocF(512), *gbout = allocF(512);
    float *nbin = allocF(512), *nbh0 = allocF(512), *nbh1 = allocF(512), *nbout = allocF(512);
    float *lr_t = allocF(Rr), *fg_t = allocF(Rr), *mo_t = allocF(Rr);
    float *scal = allocF(8);
    float *cpart = allocF(64 * 512);
    unsigned short *gA_h = vb_h, *gA_l = vb_l;
    unsigned short *gB_h = xm_h, *gB_l = xm_l;

    TriSet none{};
    const dim3 GG(66, 8);

    // ---- weight conversion ----
    WC wc{};
    const float* wlist[11] = { q_w, k_w, v_w, swa_wq, swa_wk, swa_wv, swa_wo,
                               mWin, mWh, mWh + WEL, mWout };
    for (int i = 0; i < 11; ++i) { wc.w[i] = wlist[i]; wc.th[i] = wt_h[i]; wc.tl[i] = wt_l[i]; wc.nh[i] = wn_h[i]; }
    k_wconv<<<dim3(256, 11), 256, 0, stream>>>(wc);

    // ---- Phase A ----
    k_build_xm<<<(Rr * 128 + 255) / 256, 256, 0, stream>>>(x, meta, xm_h, xm_l);
    k_gates<<<Rr / 4, 256, 0, stream>>>(xm_h, xm_l, lr_w, lr_b, fg_w, fg_b, mo_w, mo_b, lr_t, fg_t, mo_t);
    k_gate_means<<<1, 256, 0, stream>>>(lr_t, fg_t, mo_t, scal);

    TriSet qkvA{{ { wt_h[0], wt_l[0], q_b, f0 }, { wt_h[1], wt_l[1], k_b, f1 }, { wt_h[2], wt_l[2], v_b, f2 } }};
    k_mm<0, 0, false, 0, true, 3, false><<<dim3(66, 8, 3), 256, 0, stream>>>(
        xm_h, xm_l, nullptr, nullptr, nullptr, nullptr, nullptr, nullptr, nullptr, nullptr,
        nullptr, nullptr, qkvA, Rr, Dd, Dd, 0);
    k_conv3<<<dim3(Rr, 3), 256, 0, stream>>>(f0, f1, f2, q_c, k_c, v_c,
                                             qb_h, qb_l, kb_h, kb_l, vb_h, vb_l);

    // ---- Phase B: memory-MLP forward (plain bf16; theta-damped path) ----
    k_mm<0, 0, false, 5, false, 1, false><<<GG, 256, 0, stream>>>(
        kb_h, nullptr, wt_h[7], nullptr, f0, mbin, nullptr, nullptr, nullptr, nullptr,
        h0_h, h0_l, none, Rr, Dd, Dd, 0);                               // z0=f0, h0
    k_mm<0, 0, false, 6, false, 1, false><<<GG, 256, 0, stream>>>(
        h0_h, nullptr, wt_h[8], nullptr, f1, mbh, nullptr, h0_h, h0_l, nullptr,
        h1_h, h1_l, none, Rr, Dd, Dd, 0);                               // a0=f1, h1
    k_mm<0, 0, false, 6, false, 1, false><<<GG, 256, 0, stream>>>(
        h1_h, nullptr, wt_h[9], nullptr, f2, mbh + 512, nullptr, h1_h, h1_l, nullptr,
        h2_h, h2_l, none, Rr, Dd, Dd, 0);                               // a1=f2, h2
    k_mm<0, 0, false, 3, false, 1, false><<<GG, 256, 0, stream>>>(
        h2_h, nullptr, wt_h[10], nullptr, nullptr, mbout, nullptr, vb_h, vb_l, lr_t,
        g1_h, g1_l, none, Rr, Dd, Dd, 0);                               // g1 = dpred

    // ---- Phase C: backward ----
    auto GRADW = [&](const unsigned short* ah, const unsigned short* bh, float* gout) {
        k_mm<1, 1, true, 0, false, 1, false><<<dim3(8, 8, 11), 256, 0, stream>>>(
            ah, nullptr, bh, nullptr, parts, nullptr, nullptr, nullptr, nullptr, nullptr,
            nullptr, nullptr, none, Dd, Dd, Rr, 0);
        k_reduce_splitk<<<1024, 256, 0, stream>>>(parts, gout, WEL, 11, 1.0f / NCc);
    };
    auto COLSUM = [&](const unsigned short* gh, const unsigned short* gl, float* bo) {
        k_colsum<<<dim3(2, 64), 256, 0, stream>>>(gh, gl, cpart);
        k_colsum_reduce<<<2, 256, 0, stream>>>(cpart, bo, 1.0f / NCc);
    };
    GRADW(h2_h, g1_h, gWout);  COLSUM(g1_h, g1_l, gbout);
    k_mm<0, 0, false, 4, false, 1, false><<<GG, 256, 0, stream>>>(
        g1_h, nullptr, wn_h[10], nullptr, f3, nullptr, f2, nullptr, nullptr, nullptr,
        gA_h, gA_l, none, Rr, Dd, Dd, 0);                               // f3=dh2, gA=da1
    GRADW(h1_h, gA_h, gWh1);   COLSUM(gA_h, gA_l, gbh1);
    k_mm<0, 0, false, 4, false, 1, false><<<GG, 256, 0, stream>>>(
        gA_h, nullptr, wn_h[9], nullptr, f3, nullptr, f1, nullptr, nullptr, nullptr,
        gB_h, gB_l, none, Rr, Dd, Dd, 1);                               // f3=dh1, gB=da0
    GRADW(h0_h, gB_h, gWh0);   COLSUM(gB_h, gB_l, gbh0);
    k_mm<0, 0, false, 4, false, 1, false><<<GG, 256, 0, stream>>>(
        gB_h, nullptr, wn_h[8], nullptr, f3, nullptr, f0, nullptr, nullptr, nullptr,
        gA_h, gA_l, none, Rr, Dd, Dd, 1);                               // gA=dz0
    GRADW(kb_h, gA_h, gWin);   COLSUM(gA_h, gA_l, gbin);

    // ---- Phase D: updates ----
    UpdW4 uw{ { mWin, mWh, mWh + WEL, mWout },
              { momWin, momWh, momWh + WEL, momWout },
              { gWin, gWh0, gWh1, gWout },
              { nWinT_h, nWh0T_h, nWh1T_h, nWoutT_h },
              { nWinT_l, nWh0T_l, nWh1T_l, nWoutT_l } };
    k_updW<<<dim3(256, 4), 256, 0, stream>>>(uw, scal);
    UpdB4 ub{ { mbin, mbh, mbh + 512, mbout },
              { mombin, mombh, mombh + 512, mombout },
              { gbin, gbh0, gbh1, gbout },
              { nbin, nbh0, nbh1, nbout } };
    k_updB<<<8, 256, 0, stream>>>(ub, scal);

    // ---- Phase E: retrieval MLP on q (bf16x2 split) ----
    k_mm<0, 0, false, 1, false, 3, false><<<GG, 256, 0, stream>>>(
        qb_h, qb_l, nWinT_h, nWinT_l, nullptr, nbin, nullptr, nullptr, nullptr, nullptr,
        g1_h, g1_l, none, Rr, Dd, Dd, 0);                               // e0 -> g1
    k_mm<0, 0, false, 2, false, 3, false><<<GG, 256, 0, stream>>>(
        g1_h, g1_l, nWh0T_h, nWh0T_l, nullptr, nbh0, nullptr, g1_h, g1_l, nullptr,
        h0_h, h0_l, none, Rr, Dd, Dd, 0);                               // e1 -> h0
    k_mm<0, 0, false, 2, false, 3, false><<<GG, 256, 0, stream>>>(
        h0_h, h0_l, nWh1T_h, nWh1T_l, nullptr, nbh1, nullptr, h0_h, h0_l, nullptr,
        h1_h, h1_l, none, Rr, Dd, Dd, 0);                               // e2 -> h1
    k_mm<0, 0, false, 1, false, 3, false><<<GG, 256, 0, stream>>>(
        h1_h, h1_l, nWoutT_h, nWoutT_l, nullptr, nbout, nullptr, nullptr, nullptr, nullptr,
        h2_h, h2_l, none, Rr, Dd, Dd, 0);                               // retrieved -> h2

    // ---- Phase F: SWA qkv (fp32 out), fused MFMA flash SWA, out-proj+slice ----
    TriSet qkvF{{ { wt_h[3], wt_l[3], swa_bq, f0 }, { wt_h[4], wt_l[4], swa_bk, f1 },
                  { wt_h[5], wt_l[5], swa_bv, f2 } }};
    k_mm<0, 0, false, 0, true, 3, false><<<dim3(66, 8, 3), 256, 0, stream>>>(
        h2_h, h2_l, nullptr, nullptr, nullptr, nullptr, nullptr, nullptr, nullptr, nullptr,
        nullptr, nullptr, qkvF, Rr, Dd, Dd, 0);
    k_swa<<<dim3(Nn / 64, Bb * NHh), 256, 0, stream>>>(f0, f1, f2, f3);
    k_mm<0, 0, false, 7, false, 3, true><<<GG, 256, 0, stream>>>(
        f3, nullptr, wt_h[6], wt_l[6], (float*)d_out, swa_bo, nullptr, nullptr, nullptr, nullptr,
        nullptr, nullptr, none, Rr, Dd, Dd, 0);
}

// Round 8
// 512.537 us; speedup vs baseline: 5.3569x; 1.2457x over previous
//
#include <hip/hip_runtime.h>
#include <cmath>

// ---------------------------------------------------------------------------
// NeuralMemory R8: full fp16 MFMA pipeline (single-pass, no hi/lo split).
// Gradient stream scaled by S=256 to stay out of fp16 subnormals; removed at
// GRADW/COLSUM reductions. LDS-tiled transposes for wconv/updW. swz() bank
// swizzle retained everywhere.
// ---------------------------------------------------------------------------

namespace {

constexpr int Bb   = 2;
constexpr int Ss   = 2048;
constexpr int Dd   = 512;
constexpr int Mm   = 64;
constexpr int NCc  = 16;
constexpr int NHh  = 8;
constexpr int HD   = 64;
constexpr int WINw = 256;
constexpr int Nn   = Mm + Ss;    // 2112
constexpr int Rr   = Bb * Nn;    // 4224
constexpr int NBD  = Rr * Dd;
constexpr float MAXLR = 0.1f;
constexpr float GS   = 256.0f;   // gradient-stream scale (fp16 subnormal guard)

typedef __attribute__((ext_vector_type(8))) short short8;
typedef __attribute__((ext_vector_type(8))) _Float16 half8;
typedef __attribute__((ext_vector_type(4))) float f32x4;

__device__ __forceinline__ float sigf(float x)  { return 1.0f / (1.0f + __expf(-x)); }
__device__ __forceinline__ float siluf(float x) { return x * sigf(x); }
__device__ __forceinline__ float dsiluf(float x){ float s = sigf(x); return s * (1.0f + x * (1.0f - s)); }
__device__ __forceinline__ unsigned short f2h(float f) {
    _Float16 h = (_Float16)f;
    return *(unsigned short*)&h;
}
__device__ __forceinline__ float h2f(unsigned short u) {
    return (float)(*(_Float16*)&u);
}
__device__ __forceinline__ int swz(int u) { return u ^ ((u >> 4) & 7); }

// ---- build xm (fp16) ------------------------------------------------------
__global__ void k_build_xm(const float* __restrict__ x, const float* __restrict__ meta,
                           unsigned short* __restrict__ xh) {
    int i = blockIdx.x * 256 + threadIdx.x;      // float4 units
    if (i >= Rr * 128) return;
    int c = i & 127, r = i >> 7;
    int b = r / Nn, t = r - b * Nn;
    float4 v = (t < Mm) ? ((const float4*)meta)[t * 128 + c]
                        : ((const float4*)x)[(size_t)(b * Ss + (t - Mm)) * 128 + c];
    float vv[4] = { v.x, v.y, v.z, v.w };
    unsigned short h[4];
    #pragma unroll
    for (int e = 0; e < 4; ++e) h[e] = f2h(vv[e]);
    *(ushort4*)(xh + (size_t)i * 4) = *(ushort4*)h;
}

// ---- per-row scalar gates -------------------------------------------------
__global__ void k_gates(const unsigned short* __restrict__ xh,
                        const float* __restrict__ lw, const float* __restrict__ lb,
                        const float* __restrict__ fw, const float* __restrict__ fb,
                        const float* __restrict__ mw, const float* __restrict__ mb,
                        float* __restrict__ lr_t, float* __restrict__ fg_t, float* __restrict__ mo_t) {
    int r = blockIdx.x * 4 + (threadIdx.x >> 6);
    int lane = threadIdx.x & 63;
    if (r >= Rr) return;
    float s0 = 0.f, s1 = 0.f, s2 = 0.f;
    for (int j = lane; j < Dd; j += 64) {
        float v = h2f(xh[(size_t)r * Dd + j]);
        s0 += v * lw[j]; s1 += v * fw[j]; s2 += v * mw[j];
    }
    #pragma unroll
    for (int off = 32; off; off >>= 1) {
        s0 += __shfl_down(s0, off, 64);
        s1 += __shfl_down(s1, off, 64);
        s2 += __shfl_down(s2, off, 64);
    }
    if (lane == 0) {
        lr_t[r] = MAXLR * sigf(s0 + lb[0]);
        fg_t[r] = sigf(s1 + fb[0]);
        mo_t[r] = sigf(s2 + mb[0]);
    }
}

__global__ void k_gate_means(const float* __restrict__ lr_t, const float* __restrict__ fg_t,
                             const float* __restrict__ mo_t, float* __restrict__ scal) {
    __shared__ float red[256];
    const float* ptrs[3] = { fg_t, lr_t, mo_t };
    for (int w = 0; w < 3; ++w) {
        float acc = 0.f;
        for (int i = threadIdx.x; i < Rr; i += 256) acc += ptrs[w][i];
        red[threadIdx.x] = acc; __syncthreads();
        for (int off = 128; off; off >>= 1) {
            if (threadIdx.x < off) red[threadIdx.x] += red[threadIdx.x + off];
            __syncthreads();
        }
        if (threadIdx.x == 0) scal[w] = red[0] / (float)Rr;
        __syncthreads();
    }
}

// ---- weight convert via LDS transpose: W[r][c] fp32 -> WT[c][r] fp16 ------
// grid (8,8,11); block tile 64x64. Optional natural fp16 copy.
struct WC { const float* w[11]; unsigned short* th[11]; unsigned short* nh[11]; };
__global__ __launch_bounds__(256) void k_wconv(WC wc) {
    __shared__ float T[64][65];
    int seg = blockIdx.z;
    int r0 = blockIdx.y * 64, c0 = blockIdx.x * 64;
    int tr = threadIdx.x >> 2, tc = (threadIdx.x & 3) * 16;
    const float* wsrc = wc.w[seg] + (size_t)(r0 + tr) * 512 + c0 + tc;
    float vals[16];
    #pragma unroll
    for (int q = 0; q < 4; ++q) *(float4*)&vals[q * 4] = *(const float4*)(wsrc + q * 4);
    #pragma unroll
    for (int e = 0; e < 16; ++e) T[tr][tc + e] = vals[e];
    if (wc.nh[seg]) {
        unsigned short nh16[16];
        #pragma unroll
        for (int e = 0; e < 16; ++e) nh16[e] = f2h(vals[e]);
        unsigned short* np = wc.nh[seg] + (size_t)(r0 + tr) * 512 + c0 + tc;
        *(short8*)np = *(short8*)nh16; *(short8*)(np + 8) = *(short8*)(nh16 + 8);
    }
    __syncthreads();
    int c = threadIdx.x >> 2, rb = (threadIdx.x & 3) * 16;
    unsigned short o16[16];
    #pragma unroll
    for (int e = 0; e < 16; ++e) o16[e] = f2h(T[rb + e][c]);
    unsigned short* tp = wc.th[seg] + (size_t)(c0 + c) * 512 + r0 + rb;
    *(short8*)tp = *(short8*)o16; *(short8*)(tp + 8) = *(short8*)(o16 + 8);
}

// ---- MFMA GEMM: 64x64 tile, BK=64, 256 thr (4 waves, each 32x32), fp16 ----
// TA=0: A row-major (M,K) fp16 (or fp32 if AF32 — cvt on stage).
// TA=1: A stored [k][m]. TB=0: B [n][k]. TB=1: B [k][n].
// EPI: 0 fp32(+bias,+accum) | 1 silu->h | 2 ex+silu->h | 3 dpred*GS->h
//      4 accum fp32 + *dsilu(exf)->h | 5 fp32 + silu->h | 6 fp32 + ex+silu->h
//      7 bias+slice fp32 -> d_out
struct TriW { const unsigned short* bh; const float* bias; float* c; };
struct TriSet { TriW t[3]; };

template<int TA, int TB, bool SPLITK, int EPI, bool MULTI, bool AF32>
__global__ __launch_bounds__(256) void k_mm(
        const void* Ap, const unsigned short* Bh_,
        float* C, const float* bias, const float* __restrict__ exf,
        const unsigned short* __restrict__ exh,
        const float* __restrict__ lrp,
        unsigned short* oh, TriSet ts,
        int Md, int Nd, int Kd, int accum) {
    __shared__ char smem[16384];
    unsigned short* AH = (unsigned short*)smem;   // 4096 halves
    unsigned short* BH = AH + 4096;
    const int tid = threadIdx.x;
    const int m0 = blockIdx.x * 64, n0 = blockIdx.y * 64;
    if constexpr (MULTI) {
        const TriW& tw = ts.t[blockIdx.z];
        Bh_ = tw.bh; bias = tw.bias; C = tw.c;
    }
    int kbg = 0, ke = Kd;
    if constexpr (SPLITK) {
        int kc = Kd / gridDim.z;
        kbg = blockIdx.z * kc; ke = kbg + kc;
        C += (size_t)blockIdx.z * Md * Nd;
    }
    const int astr = (TA == 0) ? Kd : Md;

    f32x4 acc[2][2];
    #pragma unroll
    for (int i = 0; i < 2; ++i)
        #pragma unroll
        for (int j = 0; j < 2; ++j)
            #pragma unroll
            for (int v = 0; v < 4; ++v) acc[i][j][v] = 0.f;

    short8 pA0, pA1, pB0, pB1;
    float4 pAf[4];

    auto gload = [&](int k0) {
        if constexpr (TA == 0) {
            int r = tid >> 2, ks2 = (tid & 3) * 16;
            if constexpr (AF32) {
                const float* ap = (const float*)Ap + (size_t)(m0 + r) * astr + k0 + ks2;
                pAf[0] = *(const float4*)ap;       pAf[1] = *(const float4*)(ap + 4);
                pAf[2] = *(const float4*)(ap + 8); pAf[3] = *(const float4*)(ap + 12);
            } else {
                const unsigned short* ah = (const unsigned short*)Ap + (size_t)(m0 + r) * astr + k0 + ks2;
                pA0 = *(const short8*)ah; pA1 = *(const short8*)(ah + 8);
            }
        } else {
            int kr = tid >> 2, ms = (tid & 3) * 16;
            const unsigned short* ah = (const unsigned short*)Ap + (size_t)(k0 + kr) * astr + m0 + ms;
            pA0 = *(const short8*)ah; pA1 = *(const short8*)(ah + 8);
        }
        if constexpr (TB == 0) {
            int nr = tid >> 2, ks2 = (tid & 3) * 16;
            const unsigned short* bh = Bh_ + (size_t)(n0 + nr) * Kd + k0 + ks2;
            pB0 = *(const short8*)bh; pB1 = *(const short8*)(bh + 8);
        } else {
            int kr = tid >> 2, nseg = (tid & 3) * 16;
            const unsigned short* bh = Bh_ + (size_t)(k0 + kr) * Nd + n0 + nseg;
            pB0 = *(const short8*)bh; pB1 = *(const short8*)(bh + 8);
        }
    };
    auto lstore = [&]() {
        if constexpr (TA == 0) {
            int r = tid >> 2, ks2 = (tid & 3) * 16;
            int f = r >> 4, rr = r & 15, kf = ks2 >> 5, q = (ks2 >> 3) & 3;
            int F = (f * 2 + kf) * 4 + q;
            int u0 = swz(F * 16 + rr) * 8, u1 = swz((F + 1) * 16 + rr) * 8;
            if constexpr (AF32) {
                unsigned short hh[16];
                const float* pf = (const float*)pAf;
                #pragma unroll
                for (int e = 0; e < 16; ++e) hh[e] = f2h(pf[e]);
                *(short8*)(AH + u0) = *(short8*)hh;  *(short8*)(AH + u1) = *(short8*)(hh + 8);
            } else {
                *(short8*)(AH + u0) = pA0; *(short8*)(AH + u1) = pA1;
            }
        } else {
            int kr = tid >> 2, ms = (tid & 3) * 16;
            int f = ms >> 4, kf = kr >> 5, q = (kr >> 3) & 3, kk = kr & 7;
            int F = (f * 2 + kf) * 4 + q;
            unsigned short tmp[16];
            *(short8*)tmp = pA0; *(short8*)(tmp + 8) = pA1;
            #pragma unroll
            for (int e = 0; e < 16; ++e) AH[swz((F << 4) | e) * 8 + kk] = tmp[e];
        }
        if constexpr (TB == 0) {
            int nr = tid >> 2, ks2 = (tid & 3) * 16;
            int f = nr >> 4, rr = nr & 15, kf = ks2 >> 5, q = (ks2 >> 3) & 3;
            int F = (f * 2 + kf) * 4 + q;
            int u0 = swz(F * 16 + rr) * 8, u1 = swz((F + 1) * 16 + rr) * 8;
            *(short8*)(BH + u0) = pB0; *(short8*)(BH + u1) = pB1;
        } else {
            int kr = tid >> 2, nseg = (tid & 3) * 16;
            int f = nseg >> 4, kf = kr >> 5, q = (kr >> 3) & 3, kk = kr & 7;
            int F = (f * 2 + kf) * 4 + q;
            unsigned short tmp[16];
            *(short8*)tmp = pB0; *(short8*)(tmp + 8) = pB1;
            #pragma unroll
            for (int e = 0; e < 16; ++e) BH[swz((F << 4) | e) * 8 + kk] = tmp[e];
        }
    };

    const int wv = tid >> 6, lr16 = tid & 15, lq = (tid >> 4) & 3;
    const int wm = wv & 1, wn = wv >> 1;

    gload(kbg); lstore();
    __syncthreads();
    for (int k0 = kbg; k0 < ke; k0 += 64) {
        bool more = (k0 + 64) < ke;
        if (more) gload(k0 + 64);
        #pragma unroll
        for (int kf = 0; kf < 2; ++kf) {
            half8 fa[2], fb[2];
            #pragma unroll
            for (int i = 0; i < 2; ++i) {
                int u = swz((((wm * 2 + i) * 2 + kf) * 4 + lq) * 16 + lr16);
                fa[i] = *(const half8*)(AH + u * 8);
            }
            #pragma unroll
            for (int j = 0; j < 2; ++j) {
                int u = swz((((wn * 2 + j) * 2 + kf) * 4 + lq) * 16 + lr16);
                fb[j] = *(const half8*)(BH + u * 8);
            }
            #pragma unroll
            for (int i = 0; i < 2; ++i)
                #pragma unroll
                for (int j = 0; j < 2; ++j)
                    acc[i][j] = __builtin_amdgcn_mfma_f32_16x16x32_f16(fa[i], fb[j], acc[i][j], 0, 0, 0);
        }
        if (more) { __syncthreads(); lstore(); __syncthreads(); }
    }
    __syncthreads();

    // ---- epilogue: acc -> swizzled LDS fp32 -> row-major per-thread ----
    float* EP = (float*)smem;
    #pragma unroll
    for (int i = 0; i < 2; ++i)
        #pragma unroll
        for (int j = 0; j < 2; ++j)
            #pragma unroll
            for (int v = 0; v < 4; ++v) {
                int row = wm * 32 + i * 16 + lq * 4 + v;
                int col = wn * 32 + j * 16 + lr16;
                int u = col >> 2, up = u ^ (row & 15);
                EP[row * 64 + up * 4 + (col & 3)] = acc[i][j][v];
            }
    __syncthreads();
    int r = tid >> 2, cg = tid & 3;
    float vv[16];
    #pragma unroll
    for (int uu = 0; uu < 4; ++uu) {
        int u = cg * 4 + uu;
        *(float4*)&vv[uu * 4] = *(const float4*)&EP[r * 64 + ((u ^ (r & 15)) * 4)];
    }
    int m = m0 + r, nb = n0 + cg * 16;
    size_t idx = (size_t)m * Nd + nb;

    if constexpr (SPLITK) {
        #pragma unroll
        for (int uu = 0; uu < 4; ++uu) *(float4*)(C + idx + uu * 4) = *(float4*)&vv[uu * 4];
        return;
    }
    if (bias) {
        #pragma unroll
        for (int uu = 0; uu < 4; ++uu) {
            float4 b4 = *(const float4*)(bias + nb + uu * 4);
            vv[uu * 4 + 0] += b4.x; vv[uu * 4 + 1] += b4.y;
            vv[uu * 4 + 2] += b4.z; vv[uu * 4 + 3] += b4.w;
        }
    }
    unsigned short eh8[16];
    if constexpr (EPI == 2 || EPI == 3 || EPI == 6) {
        #pragma unroll
        for (int k4 = 0; k4 < 2; ++k4)
            *(short8*)&eh8[k4 * 8] = *(const short8*)(exh + idx + k4 * 8);
    }
    auto store_h = [&](const float* s) {
        unsigned short hb[16];
        #pragma unroll
        for (int e = 0; e < 16; ++e) hb[e] = f2h(s[e]);
        *(short8*)(oh + idx) = *(short8*)hb;
        *(short8*)(oh + idx + 8) = *(short8*)(hb + 8);
    };
    auto accum_add = [&]() {
        #pragma unroll
        for (int uu = 0; uu < 4; ++uu) {
            float4 o4 = *(const float4*)(C + idx + uu * 4);
            vv[uu * 4 + 0] += o4.x; vv[uu * 4 + 1] += o4.y;
            vv[uu * 4 + 2] += o4.z; vv[uu * 4 + 3] += o4.w;
        }
    };
    auto store_f = [&]() {
        #pragma unroll
        for (int uu = 0; uu < 4; ++uu) *(float4*)(C + idx + uu * 4) = *(float4*)&vv[uu * 4];
    };
    if constexpr (EPI == 0) {
        if (accum) accum_add();
        store_f();
    } else if constexpr (EPI == 1) {
        float s[16];
        #pragma unroll
        for (int e = 0; e < 16; ++e) s[e] = siluf(vv[e]);
        store_h(s);
    } else if constexpr (EPI == 2) {
        float s[16];
        #pragma unroll
        for (int e = 0; e < 16; ++e) s[e] = h2f(eh8[e]) + siluf(vv[e]);
        store_h(s);
    } else if constexpr (EPI == 3) {
        float sc = GS * (2.0f / 512.0f) * lrp[m];
        float s[16];
        #pragma unroll
        for (int e = 0; e < 16; ++e) s[e] = sc * (vv[e] - h2f(eh8[e]));
        store_h(s);
    } else if constexpr (EPI == 4) {
        if (accum) accum_add();
        store_f();
        float s[16];
        #pragma unroll
        for (int e = 0; e < 16; ++e) s[e] = vv[e] * dsiluf(exf[idx + e]);
        store_h(s);
    } else if constexpr (EPI == 5) {
        store_f();
        float s[16];
        #pragma unroll
        for (int e = 0; e < 16; ++e) s[e] = siluf(vv[e]);
        store_h(s);
    } else if constexpr (EPI == 6) {
        store_f();
        float s[16];
        #pragma unroll
        for (int e = 0; e < 16; ++e) s[e] = h2f(eh8[e]) + siluf(vv[e]);
        store_h(s);
    } else if constexpr (EPI == 7) {
        int b2 = m / Nn, t2 = m - b2 * Nn;
        if (t2 >= Mm) {
            float* dst = C + (size_t)(b2 * Ss + (t2 - Mm)) * Nd + nb;
            #pragma unroll
            for (int uu = 0; uu < 4; ++uu) *(float4*)(dst + uu * 4) = *(float4*)&vv[uu * 4];
        }
    }
}

__global__ void k_reduce_splitk(const float* __restrict__ part, float* __restrict__ out,
                                int n, int z, float alpha) {
    int i = blockIdx.x * 256 + threadIdx.x;
    if (i >= n) return;
    float s = 0.f;
    for (int zz = 0; zz < z; ++zz) s += part[(size_t)zz * n + i];
    out[i] = alpha * s;
}

// ---- causal depthwise conv K=4 + SiLU (+L2n for q,k); fp32 in, fp16 out ---
__global__ __launch_bounds__(256) void k_conv3(
        const float* __restrict__ yq, const float* __restrict__ yk, const float* __restrict__ yv,
        const float* __restrict__ cq, const float* __restrict__ ck, const float* __restrict__ cv,
        unsigned short* oq, unsigned short* ok, unsigned short* ov) {
    int which = blockIdx.y;
    const float* y  = which == 0 ? yq : which == 1 ? yk : yv;
    const float* cw = which == 0 ? cq : which == 1 ? ck : cv;
    unsigned short* oh = which == 0 ? oq : which == 1 ? ok : ov;
    bool norm = which < 2;
    int r = blockIdx.x;
    int b = r / Nn, t = r - b * Nn;
    const size_t rowbase = (size_t)r * Dd;
    float s[2];
    #pragma unroll
    for (int u = 0; u < 2; ++u) {
        int d = threadIdx.x + u * 256;
        float acc = 0.f;
        #pragma unroll
        for (int k = 0; k < 4; ++k) {
            int tt = t - 3 + k;
            if (tt >= 0) acc += y[(size_t)(b * Nn + tt) * Dd + d] * cw[d * 4 + k];
        }
        s[u] = siluf(acc);
    }
    float denom = 1.0f;
    if (norm) {
        __shared__ float wr[4];
        float v2 = s[0] * s[0] + s[1] * s[1];
        #pragma unroll
        for (int off = 32; off; off >>= 1) v2 += __shfl_xor(v2, off, 64);
        if ((threadIdx.x & 63) == 0) wr[threadIdx.x >> 6] = v2;
        __syncthreads();
        denom = fmaxf(sqrtf(wr[0] + wr[1] + wr[2] + wr[3]), 1e-12f);
    }
    oh[rowbase + threadIdx.x]       = f2h(s[0] / denom);
    oh[rowbase + threadIdx.x + 256] = f2h(s[1] / denom);
}

// ---- column sums for bias grads (fp16 input, ×GS) -------------------------
__global__ void k_colsum(const unsigned short* __restrict__ gh, float* __restrict__ part) {
    int col = blockIdx.x * 256 + threadIdx.x;
    int chunk = blockIdx.y;
    int r0 = chunk * (Rr / 64);
    float s = 0.f;
    for (int r = r0; r < r0 + Rr / 64; ++r) s += h2f(gh[(size_t)r * Dd + col]);
    part[chunk * Dd + col] = s;
}
__global__ void k_colsum_reduce(const float* __restrict__ part, float* __restrict__ out, float alpha) {
    int col = blockIdx.x * 256 + threadIdx.x;
    if (col >= Dd) return;
    float s = 0.f;
    for (int c = 0; c < 64; ++c) s += part[c * Dd + col];
    out[col] = alpha * s;
}

// ---- weight update + transpose to fp16 [c][r] via LDS ---------------------
struct UpdW4 { const float* p[4]; const float* mo[4]; const float* g[4]; unsigned short* th[4]; };
__global__ __launch_bounds__(256) void k_updW(UpdW4 u, const float* __restrict__ scal) {
    __shared__ float T[64][65];
    int seg = blockIdx.z;
    int r0 = blockIdx.y * 64, c0 = blockIdx.x * 64;
    float a = 1.0f - scal[0], et = scal[2], th = scal[1];
    int tr = threadIdx.x >> 2, tc = (threadIdx.x & 3) * 16;
    size_t base = (size_t)(r0 + tr) * 512 + c0 + tc;
    #pragma unroll
    for (int q = 0; q < 4; ++q) {
        float4 p4 = *(const float4*)(u.p[seg] + base + q * 4);
        float4 m4 = *(const float4*)(u.mo[seg] + base + q * 4);
        float4 g4 = *(const float4*)(u.g[seg] + base + q * 4);
        T[tr][tc + q * 4 + 0] = p4.x * a + et * m4.x - th * g4.x;
        T[tr][tc + q * 4 + 1] = p4.y * a + et * m4.y - th * g4.y;
        T[tr][tc + q * 4 + 2] = p4.z * a + et * m4.z - th * g4.z;
        T[tr][tc + q * 4 + 3] = p4.w * a + et * m4.w - th * g4.w;
    }
    __syncthreads();
    int c = threadIdx.x >> 2, rb = (threadIdx.x & 3) * 16;
    unsigned short o16[16];
    #pragma unroll
    for (int e = 0; e < 16; ++e) o16[e] = f2h(T[rb + e][c]);
    unsigned short* tp = u.th[seg] + (size_t)(c0 + c) * 512 + r0 + rb;
    *(short8*)tp = *(short8*)o16; *(short8*)(tp + 8) = *(short8*)(o16 + 8);
}
struct UpdB4 { const float* p[4]; const float* mo[4]; const float* g[4]; float* o[4]; };
__global__ void k_updB(UpdB4 u, const float* __restrict__ scal) {
    int seg = blockIdx.x >> 1;
    int i = (blockIdx.x & 1) * 256 + threadIdx.x;
    u.o[seg][i] = u.p[seg][i] * (1.0f - scal[0]) + scal[2] * u.mo[seg][i] - scal[1] * u.g[seg][i];
}

// ---- fused MFMA flash SWA (fp16 single-pass) ------------------------------
__global__ __launch_bounds__(256) void k_swa(const float* __restrict__ qs,
                                             const float* __restrict__ ks,
                                             const float* __restrict__ vs,
                                             float* __restrict__ out) {
    __shared__ unsigned short KH[2048], VH[2048];
    __shared__ unsigned short PH[4][512];
    const int tid = threadIdx.x;
    const int w = tid >> 6, lane = tid & 63;
    const int lq = lane >> 4, l16 = lane & 15;
    const int q0 = blockIdx.x * 64;
    const int bh = blockIdx.y;
    const int h = bh & 7, b = bh >> 3;
    const size_t srow = (size_t)(b * Nn) * Dd + h * HD;
    const int iq = q0 + w * 16 + l16;

    half8 qh[2];
    {
        const float* qr = qs + srow + (size_t)iq * Dd;
        #pragma unroll
        for (int kf = 0; kf < 2; ++kf) {
            float t8[8];
            *(float4*)&t8[0] = *(const float4*)(qr + kf * 32 + lq * 8);
            *(float4*)&t8[4] = *(const float4*)(qr + kf * 32 + lq * 8 + 4);
            unsigned short hh[8];
            #pragma unroll
            for (int e = 0; e < 8; ++e) hh[e] = f2h(t8[e]);
            qh[kf] = *(half8*)hh;
        }
    }

    f32x4 o[4];
    #pragma unroll
    for (int nf = 0; nf < 4; ++nf)
        #pragma unroll
        for (int v = 0; v < 4; ++v) o[nf][v] = 0.f;
    float mrun[4] = { -1e30f, -1e30f, -1e30f, -1e30f };
    float lrun[4] = { 0.f, 0.f, 0.f, 0.f };
    const int iw = q0 + w * 16 + lq * 4;

    int jlo = q0 - (WINw - 1); if (jlo < 0) jlo = 0;
    jlo &= ~31;
    for (int jt = jlo; jt < q0 + 64; jt += 32) {
        __syncthreads();
        {
            int nr = tid >> 3, ds8 = (tid & 7) * 8;
            const float* kr = ks + srow + (size_t)(jt + nr) * Dd + ds8;
            float t8[8];
            *(float4*)&t8[0] = *(const float4*)kr;
            *(float4*)&t8[4] = *(const float4*)(kr + 4);
            unsigned short hh[8];
            #pragma unroll
            for (int e = 0; e < 8; ++e) hh[e] = f2h(t8[e]);
            int f = nr >> 4, rr = nr & 15, kf = ds8 >> 5, q = (ds8 >> 3) & 3;
            int u = swz(((f * 2 + kf) * 4 + q) * 16 + rr);
            *(short8*)(KH + u * 8) = *(short8*)hh;
        }
        {
            int d = tid & 63, kg = tid >> 6;
            unsigned short hh[8];
            #pragma unroll
            for (int e = 0; e < 8; ++e)
                hh[e] = f2h(vs[srow + (size_t)(jt + kg * 8 + e) * Dd + d]);
            int f = d >> 4, rr = d & 15;
            int u = swz((f * 4 + kg) * 16 + rr);
            *(short8*)(VH + u * 8) = *(short8*)hh;
        }
        __syncthreads();

        f32x4 s[2];
        #pragma unroll
        for (int nf = 0; nf < 2; ++nf) {
            #pragma unroll
            for (int v = 0; v < 4; ++v) s[nf][v] = 0.f;
            #pragma unroll
            for (int kf = 0; kf < 2; ++kf) {
                int u = swz(((nf * 2 + kf) * 4 + lq) * 16 + l16);
                half8 kb = *(const half8*)(KH + u * 8);
                s[nf] = __builtin_amdgcn_mfma_f32_16x16x32_f16(qh[kf], kb, s[nf], 0, 0, 0);
            }
        }
        float mt[4];
        #pragma unroll
        for (int v = 0; v < 4; ++v) {
            int i = iw + v;
            int j0c = jt + l16, j1c = jt + 16 + l16;
            s[0][v] = ((j0c <= i) && (i - j0c < WINw)) ? s[0][v] * 0.125f : -1e30f;
            s[1][v] = ((j1c <= i) && (i - j1c < WINw)) ? s[1][v] * 0.125f : -1e30f;
            mt[v] = fmaxf(s[0][v], s[1][v]);
        }
        #pragma unroll
        for (int msk = 1; msk < 16; msk <<= 1)
            #pragma unroll
            for (int v = 0; v < 4; ++v) mt[v] = fmaxf(mt[v], __shfl_xor(mt[v], msk, 64));
        float rs[4];
        #pragma unroll
        for (int v = 0; v < 4; ++v) {
            float mnew = fmaxf(mrun[v], mt[v]);
            float corr = __expf(mrun[v] - mnew);
            mrun[v] = mnew;
            float p0 = (s[0][v] > -1e29f) ? __expf(s[0][v] - mnew) : 0.f;
            float p1 = (s[1][v] > -1e29f) ? __expf(s[1][v] - mnew) : 0.f;
            s[0][v] = p0; s[1][v] = p1;
            rs[v] = p0 + p1;
            lrun[v] *= corr;
            #pragma unroll
            for (int nf = 0; nf < 4; ++nf) o[nf][v] *= corr;
        }
        #pragma unroll
        for (int msk = 1; msk < 16; msk <<= 1)
            #pragma unroll
            for (int v = 0; v < 4; ++v) rs[v] += __shfl_xor(rs[v], msk, 64);
        #pragma unroll
        for (int v = 0; v < 4; ++v) lrun[v] += rs[v];

        #pragma unroll
        for (int nf = 0; nf < 2; ++nf)
            #pragma unroll
            for (int v = 0; v < 4; ++v) {
                int row = lq * 4 + v;
                int cu = (nf * 2 + (l16 >> 3)) ^ (row >> 2);
                PH[w][row * 32 + cu * 8 + (l16 & 7)] = f2h(s[nf][v]);
            }
        __syncthreads();
        int pa = l16 * 32 + (lq ^ (l16 >> 2)) * 8;
        half8 pah = *(const half8*)(&PH[w][pa]);
        #pragma unroll
        for (int nf = 0; nf < 4; ++nf) {
            int u = swz((nf * 4 + lq) * 16 + l16);
            half8 vth = *(const half8*)(VH + u * 8);
            o[nf] = __builtin_amdgcn_mfma_f32_16x16x32_f16(pah, vth, o[nf], 0, 0, 0);
        }
    }
    float invl[4];
    #pragma unroll
    for (int v = 0; v < 4; ++v) invl[v] = 1.0f / lrun[v];
    #pragma unroll
    for (int nf = 0; nf < 4; ++nf)
        #pragma unroll
        for (int v = 0; v < 4; ++v)
            out[srow + (size_t)(iw + v) * Dd + nf * 16 + l16] = o[nf][v] * invl[v];
}

} // namespace

extern "C" void kernel_launch(void* const* d_in, const int* in_sizes, int n_in,
                              void* d_out, int out_size, void* d_ws, size_t ws_size,
                              hipStream_t stream) {
    const float* x       = (const float*)d_in[0];
    const float* meta    = (const float*)d_in[1];
    const float* mWin    = (const float*)d_in[2];
    const float* mbin    = (const float*)d_in[3];
    const float* mWh     = (const float*)d_in[4];
    const float* mbh     = (const float*)d_in[5];
    const float* mWout   = (const float*)d_in[6];
    const float* mbout   = (const float*)d_in[7];
    const float* momWin  = (const float*)d_in[8];
    const float* mombin  = (const float*)d_in[9];
    const float* momWh   = (const float*)d_in[10];
    const float* mombh   = (const float*)d_in[11];
    const float* momWout = (const float*)d_in[12];
    const float* mombout = (const float*)d_in[13];
    const float* q_w = (const float*)d_in[14]; const float* q_b = (const float*)d_in[15]; const float* q_c = (const float*)d_in[16];
    const float* k_w = (const float*)d_in[17]; const float* k_b = (const float*)d_in[18]; const float* k_c = (const float*)d_in[19];
    const float* v_w = (const float*)d_in[20]; const float* v_b = (const float*)d_in[21]; const float* v_c = (const float*)d_in[22];
    const float* lr_w = (const float*)d_in[23]; const float* lr_b = (const float*)d_in[24];
    const float* fg_w = (const float*)d_in[25]; const float* fg_b = (const float*)d_in[26];
    const float* mo_w = (const float*)d_in[27]; const float* mo_b = (const float*)d_in[28];
    const float* swa_wq = (const float*)d_in[29]; const float* swa_wk = (const float*)d_in[30];
    const float* swa_wv = (const float*)d_in[31]; const float* swa_wo = (const float*)d_in[32];
    const float* swa_bq = (const float*)d_in[33]; const float* swa_bk = (const float*)d_in[34];
    const float* swa_bv = (const float*)d_in[35]; const float* swa_bo = (const float*)d_in[36];
    (void)in_sizes; (void)n_in; (void)out_size; (void)ws_size;

    char* wsb = (char*)d_ws;
    size_t off = 0;
    auto allocB = [&](size_t bytes) { void* p = wsb + off; off = (off + bytes + 255) & ~(size_t)255; return p; };
    auto allocU = [&](size_t elems) { return (unsigned short*)allocB(elems * 2); };
    auto allocF = [&](size_t elems) { return (float*)allocB(elems * 4); };

    unsigned short *xm_h = allocU(NBD);       // reused as gB
    unsigned short *qb_h = allocU(NBD);
    unsigned short *kb_h = allocU(NBD);
    unsigned short *vb_h = allocU(NBD);       // reused as gA
    unsigned short *h0_h = allocU(NBD);
    unsigned short *h1_h = allocU(NBD);
    unsigned short *h2_h = allocU(NBD);
    unsigned short *g1_h = allocU(NBD);
    float *f0 = allocF(NBD), *f1 = allocF(NBD), *f2 = allocF(NBD), *f3 = allocF(NBD);
    float *parts = allocF((size_t)12 * 262144);
    const int WEL = 262144;
    unsigned short *wt_h[11], *wn_h[11];
    for (int i = 0; i < 11; ++i) { wt_h[i] = allocU(WEL); wn_h[i] = nullptr; }
    for (int i = 8; i < 11; ++i) wn_h[i] = allocU(WEL);          // natural fp16: mWh0, mWh1, mWout
    unsigned short *nWinT_h = allocU(WEL);
    unsigned short *nWh0T_h = allocU(WEL);
    unsigned short *nWh1T_h = allocU(WEL);
    unsigned short *nWoutT_h = allocU(WEL);
    float *gWin = allocF(WEL), *gWh0 = allocF(WEL), *gWh1 = allocF(WEL), *gWout = allocF(WEL);
    float *gbin = allocF(512), *gbh0 = allocF(512), *gbh1 = allocF(512), *gbout = allocF(512);
    float *nbin = allocF(512), *nbh0 = allocF(512), *nbh1 = allocF(512), *nbout = allocF(512);
    float *lr_t = allocF(Rr), *fg_t = allocF(Rr), *mo_t = allocF(Rr);
    float *scal = allocF(8);
    float *cpart = allocF(64 * 512);
    unsigned short *gA_h = vb_h;
    unsigned short *gB_h = xm_h;

    TriSet none{};
    const dim3 GG(66, 8);
    const float GALPHA = 1.0f / (NCc * GS);

    // ---- weight conversion (LDS-tiled transpose) ----
    WC wc{};
    const float* wlist[11] = { q_w, k_w, v_w, swa_wq, swa_wk, swa_wv, swa_wo,
                               mWin, mWh, mWh + WEL, mWout };
    for (int i = 0; i < 11; ++i) { wc.w[i] = wlist[i]; wc.th[i] = wt_h[i]; wc.nh[i] = wn_h[i]; }
    k_wconv<<<dim3(8, 8, 11), 256, 0, stream>>>(wc);

    // ---- Phase A ----
    k_build_xm<<<(Rr * 128 + 255) / 256, 256, 0, stream>>>(x, meta, xm_h);
    k_gates<<<Rr / 4, 256, 0, stream>>>(xm_h, lr_w, lr_b, fg_w, fg_b, mo_w, mo_b, lr_t, fg_t, mo_t);
    k_gate_means<<<1, 256, 0, stream>>>(lr_t, fg_t, mo_t, scal);

    TriSet qkvA{{ { wt_h[0], q_b, f0 }, { wt_h[1], k_b, f1 }, { wt_h[2], v_b, f2 } }};
    k_mm<0, 0, false, 0, true, false><<<dim3(66, 8, 3), 256, 0, stream>>>(
        xm_h, nullptr, nullptr, nullptr, nullptr, nullptr, nullptr, nullptr, qkvA, Rr, Dd, Dd, 0);
    k_conv3<<<dim3(Rr, 3), 256, 0, stream>>>(f0, f1, f2, q_c, k_c, v_c, qb_h, kb_h, vb_h);

    // ---- Phase B: memory-MLP forward ----
    k_mm<0, 0, false, 5, false, false><<<GG, 256, 0, stream>>>(
        kb_h, wt_h[7], f0, mbin, nullptr, nullptr, nullptr, h0_h, none, Rr, Dd, Dd, 0);   // z0=f0, h0
    k_mm<0, 0, false, 6, false, false><<<GG, 256, 0, stream>>>(
        h0_h, wt_h[8], f1, mbh, nullptr, h0_h, nullptr, h1_h, none, Rr, Dd, Dd, 0);       // a0=f1, h1
    k_mm<0, 0, false, 6, false, false><<<GG, 256, 0, stream>>>(
        h1_h, wt_h[9], f2, mbh + 512, nullptr, h1_h, nullptr, h2_h, none, Rr, Dd, Dd, 0); // a1=f2, h2
    k_mm<0, 0, false, 3, false, false><<<GG, 256, 0, stream>>>(
        h2_h, wt_h[10], nullptr, mbout, nullptr, vb_h, lr_t, g1_h, none, Rr, Dd, Dd, 0);  // g1 = dpred*GS

    // ---- Phase C: backward (gradient stream carries ×GS) ----
    auto GRADW = [&](const unsigned short* ah, const unsigned short* bh, float* gout) {
        k_mm<1, 1, true, 0, false, false><<<dim3(8, 8, 11), 256, 0, stream>>>(
            ah, bh, parts, nullptr, nullptr, nullptr, nullptr, nullptr, none, Dd, Dd, Rr, 0);
        k_reduce_splitk<<<1024, 256, 0, stream>>>(parts, gout, WEL, 11, GALPHA);
    };
    auto COLSUM = [&](const unsigned short* gh, float* bo) {
        k_colsum<<<dim3(2, 64), 256, 0, stream>>>(gh, cpart);
        k_colsum_reduce<<<2, 256, 0, stream>>>(cpart, bo, GALPHA);
    };
    GRADW(h2_h, g1_h, gWout);  COLSUM(g1_h, gbout);
    k_mm<0, 0, false, 4, false, false><<<GG, 256, 0, stream>>>(
        g1_h, wn_h[10], f3, nullptr, f2, nullptr, nullptr, gA_h, none, Rr, Dd, Dd, 0);    // f3=dh2, gA=da1
    GRADW(h1_h, gA_h, gWh1);   COLSUM(gA_h, gbh1);
    k_mm<0, 0, false, 4, false, false><<<GG, 256, 0, stream>>>(
        gA_h, wn_h[9], f3, nullptr, f1, nullptr, nullptr, gB_h, none, Rr, Dd, Dd, 1);     // f3=dh1, gB=da0
    GRADW(h0_h, gB_h, gWh0);   COLSUM(gB_h, gbh0);
    k_mm<0, 0, false, 4, false, false><<<GG, 256, 0, stream>>>(
        gB_h, wn_h[8], f3, nullptr, f0, nullptr, nullptr, gA_h, none, Rr, Dd, Dd, 1);     // gA=dz0
    GRADW(kb_h, gA_h, gWin);   COLSUM(gA_h, gbin);

    // ---- Phase D: updates (LDS-tiled transpose to fp16 [c][r]) ----
    UpdW4 uw{ { mWin, mWh, mWh + WEL, mWout },
              { momWin, momWh, momWh + WEL, momWout },
              { gWin, gWh0, gWh1, gWout },
              { nWinT_h, nWh0T_h, nWh1T_h, nWoutT_h } };
    k_updW<<<dim3(8, 8, 4), 256, 0, stream>>>(uw, scal);
    UpdB4 ub{ { mbin, mbh, mbh + 512, mbout },
              { mombin, mombh, mombh + 512, mombout },
              { gbin, gbh0, gbh1, gbout },
              { nbin, nbh0, nbh1, nbout } };
    k_updB<<<8, 256, 0, stream>>>(ub, scal);

    // ---- Phase E: retrieval MLP on q ----
    k_mm<0, 0, false, 1, false, false><<<GG, 256, 0, stream>>>(
        qb_h, nWinT_h, nullptr, nbin, nullptr, nullptr, nullptr, g1_h, none, Rr, Dd, Dd, 0);
    k_mm<0, 0, false, 2, false, false><<<GG, 256, 0, stream>>>(
        g1_h, nWh0T_h, nullptr, nbh0, nullptr, g1_h, nullptr, h0_h, none, Rr, Dd, Dd, 0);
    k_mm<0, 0, false, 2, false, false><<<GG, 256, 0, stream>>>(
        h0_h, nWh1T_h, nullptr, nbh1, nullptr, h0_h, nullptr, h1_h, none, Rr, Dd, Dd, 0);
    k_mm<0, 0, false, 1, false, false><<<GG, 256, 0, stream>>>(
        h1_h, nWoutT_h, nullptr, nbout, nullptr, nullptr, nullptr, h2_h, none, Rr, Dd, Dd, 0); // retrieved

    // ---- Phase F: SWA qkv (fp32 out), MFMA flash SWA, out-proj+slice ----
    TriSet qkvF{{ { wt_h[3], swa_bq, f0 }, { wt_h[4], swa_bk, f1 }, { wt_h[5], swa_bv, f2 } }};
    k_mm<0, 0, false, 0, true, false><<<dim3(66, 8, 3), 256, 0, stream>>>(
        h2_h, nullptr, nullptr, nullptr, nullptr, nullptr, nullptr, nullptr, qkvF, Rr, Dd, Dd, 0);
    k_swa<<<dim3(Nn / 64, Bb * NHh), 256, 0, stream>>>(f0, f1, f2, f3);
    k_mm<0, 0, false, 7, false, true><<<GG, 256, 0, stream>>>(
        f3, wt_h[6], (float*)d_out, swa_bo, nullptr, nullptr, nullptr, nullptr, none, Rr, Dd, Dd, 0);
}